// Round 6
// baseline (832.802 us; speedup 1.0000x reference)
//
#include <hip/hip_runtime.h>
#include <hip/hip_bf16.h>

typedef __hip_bfloat16 bf16;
typedef __attribute__((ext_vector_type(8))) short bf16x8;
typedef __attribute__((ext_vector_type(4))) float floatx4;
typedef __attribute__((ext_vector_type(8))) unsigned short ushort8v;

__device__ __forceinline__ float b2f(bf16 v) { return __bfloat162float(v); }
__device__ __forceinline__ bf16 f2b(float v) { return __float2bfloat16(v); }
__device__ __forceinline__ float us2f(unsigned short u) {
  union { unsigned int i; float f; } v; v.i = ((unsigned int)u) << 16; return v.f;
}
__device__ __forceinline__ unsigned short f2us(float f) {
  bf16 h = f2b(f); return *(unsigned short*)&h;
}

// ---------------- global average pool: x (C,HW) fp32 NCHW -> gap[C] ------
__global__ __launch_bounds__(256) void gap_kernel(const float* __restrict__ x,
                                                  float* __restrict__ gap,
                                                  int HW, float inv) {
  int c = blockIdx.x;
  const float* p = x + (size_t)c * HW;
  float s = 0.f;
  for (int i = threadIdx.x; i < HW; i += 256) s += p[i];
  __shared__ float red[256];
  red[threadIdx.x] = s;
  __syncthreads();
  for (int w = 128; w > 0; w >>= 1) {
    if (threadIdx.x < w) red[threadIdx.x] += red[threadIdx.x + w];
    __syncthreads();
  }
  if (threadIdx.x == 0) gap[c] = red[0] * inv;
}

// -------- scale[o] = 1 + sigmoid( sum_i att_w[o,i] * gap[i] ) ------------
__global__ __launch_bounds__(256) void atten_kernel(const float* __restrict__ w,
                                                    const float* __restrict__ gap,
                                                    float* __restrict__ scale, int Ci) {
  int wave = threadIdx.x >> 6, lane = threadIdx.x & 63;
  int o = blockIdx.x * 4 + wave;
  const float4* wr = (const float4*)(w + (size_t)o * Ci);
  const float4* g4 = (const float4*)gap;
  int n4 = Ci >> 2;
  float s = 0.f;
  for (int i = lane; i < n4; i += 64) {
    float4 a = wr[i], b = g4[i];
    s += a.x * b.x + a.y * b.y + a.z * b.z + a.w * b.w;
  }
#pragma unroll
  for (int off = 32; off > 0; off >>= 1) s += __shfl_down(s, off);
  if (lane == 0) scale[o] = 1.f + 1.f / (1.f + expf(-s));
}

// ---- bilinear 2x upsample NHWC(256) -> NHWC(256), half-pixel, clamp -----
__global__ __launch_bounds__(256) void upsample2x_nhwc_kernel(
    const bf16* __restrict__ src, bf16* __restrict__ dst, int Hs, int Ws) {
  int p = blockIdx.x;       // output pixel
  int c = threadIdx.x;      // channel
  int W = Ws * 2;
  int y = p / W, x = p - y * W;
  float fy = y * 0.5f - 0.25f;
  float fx = x * 0.5f - 0.25f;
  int y0 = (int)floorf(fy), x0 = (int)floorf(fx);
  float wy1 = fy - (float)y0, wx1 = fx - (float)x0;
  int y0c = min(max(y0, 0), Hs - 1);
  int y1c = min(max(y0 + 1, 0), Hs - 1);
  int x0c = min(max(x0, 0), Ws - 1);
  int x1c = min(max(x0 + 1, 0), Ws - 1);
  float v00 = b2f(src[(size_t)(y0c * Ws + x0c) * 256 + c]);
  float v01 = b2f(src[(size_t)(y0c * Ws + x1c) * 256 + c]);
  float v10 = b2f(src[(size_t)(y1c * Ws + x0c) * 256 + c]);
  float v11 = b2f(src[(size_t)(y1c * Ws + x1c) * 256 + c]);
  float v = (1.f - wy1) * ((1.f - wx1) * v00 + wx1 * v01)
          + wy1 * ((1.f - wx1) * v10 + wx1 * v11);
  dst[(size_t)p * 256 + c] = f2b(v);
}

// ------- pack GEMM weights (fp32 [256][K]) -> bf16 MFMA-B layout ---------
__global__ __launch_bounds__(256) void packw1_kernel(const float* __restrict__ w,
                                                     bf16* __restrict__ BP, int K) {
  int idx = blockIdx.x * 256 + threadIdx.x;
  int j = idx & 7;
  int o = (idx >> 3) & 255;
  int kc8 = idx >> 11;
  int k = kc8 * 8 + j;
  BP[idx] = f2b(w[(size_t)o * K + k]);
}

// ------- pack dcn 3x3 weights tap-major: k = tap*256 + ci ----------------
__global__ __launch_bounds__(256) void packwd_kernel(const float* __restrict__ w,
                                                     bf16* __restrict__ BP) {
  int idx = blockIdx.x * 256 + threadIdx.x;
  int j = idx & 7;
  int o = (idx >> 3) & 255;
  int k8 = idx >> 11;
  int k = k8 * 8 + j;          // 0..2303, tap-major
  int tap = k >> 8;            // 0..8
  int ci = k & 255;
  BP[idx] = f2b(w[((size_t)o * 256 + ci) * 9 + tap]);
}

// ------- pack 3x3 conv weights (fp32 OIHW, Ci=256) -> bf16 B layout ------
__global__ __launch_bounds__(256) void packw3_kernel(const float* __restrict__ w,
                                                     bf16* __restrict__ BP,
                                                     int Ci, int Co) {
  int idx = blockIdx.x * 256 + threadIdx.x;
  int total = Ci * 9 * 256;
  if (idx >= total) return;
  int j = idx & 7;
  int t1 = idx >> 3;
  int o = t1 & 255;
  int t2 = t1 >> 8;
  int q = t2 & 3;
  int t3 = t2 >> 2;
  int tap = t3 % 9;
  int c = t3 / 9;
  int ci = c * 32 + q * 8 + j;
  float v = (o < Co) ? w[((size_t)o * Ci + ci) * 9 + tap] : 0.f;
  BP[idx] = f2b(v);
}

// ------------- 1x1 conv as MFMA GEMM -------------------------------------
template <bool NCHW1, typename TA1>
__global__ __launch_bounds__(256) void conv1x1_mfma_kernel(
    const TA1* __restrict__ A1, const float* __restrict__ scaleA,
    const bf16* __restrict__ A2, float scaleB,
    int Ci1, int Ci2, int HW,
    const bf16* __restrict__ BP, const float* __restrict__ bias,
    float* __restrict__ out1, bf16* __restrict__ out2, int ns2) {
  __shared__ __align__(16) bf16 sA[1024];   // [4 q][32 px][8]
  int p0 = blockIdx.x * 32;
  int tid = threadIdx.x;
  int pix = tid & 31, sub = tid >> 5;       // fp32-NCHW staging mapping
  int pix2 = tid >> 3, sub8 = tid & 7;      // NHWC staging mapping
  int lane = tid & 63, wave = tid >> 6;
  int pg = wave & 1, cg = wave >> 1;
  int q = lane >> 4, n = lane & 15;

  floatx4 acc[4];
#pragma unroll
  for (int nt = 0; nt < 4; ++nt) acc[nt] = (floatx4)0.f;

  int nch = (Ci1 + Ci2) >> 5;
  for (int kc = 0; kc < nch; ++kc) {
    int ci0 = kc << 5;
    if (NCHW1 && ci0 < Ci1) {
#pragma unroll
      for (int it = 0; it < 4; ++it) {
        int cil = it * 8 + sub;
        float x = (float)A1[(size_t)(ci0 + cil) * HW + p0 + pix];
        if (scaleA) x *= scaleA[ci0 + cil];
        sA[((cil >> 3) * 32 + pix) * 8 + (cil & 7)] = f2b(x);
      }
    } else {
      const bf16* src; int cb; bool scl;
      if (!NCHW1 && ci0 < Ci1) {
        src = (const bf16*)(const void*)A1; cb = ci0; scl = false;
      } else {
        src = A2; cb = ci0 - Ci1; scl = true;
      }
      ushort4 raw = *(const ushort4*)&src[(size_t)(p0 + pix2) * 256 + cb + sub8 * 4];
      if (scl) {
        raw.x = f2us(us2f(raw.x) * scaleB);
        raw.y = f2us(us2f(raw.y) * scaleB);
        raw.z = f2us(us2f(raw.z) * scaleB);
        raw.w = f2us(us2f(raw.w) * scaleB);
      }
      *(ushort4*)&sA[((sub8 >> 1) * 32 + pix2) * 8 + (sub8 & 1) * 4] = raw;
    }
    __syncthreads();
    bf16x8 a = *(const bf16x8*)&sA[(q * 32 + pg * 16 + n) * 8];
    const bf16* bp = BP + ((size_t)(kc * 4 + q) * 256 + blockIdx.y * 128 + cg * 64) * 8;
#pragma unroll
    for (int nt = 0; nt < 4; ++nt) {
      bf16x8 b = *(const bf16x8*)&bp[(nt * 16 + n) * 8];
      acc[nt] = __builtin_amdgcn_mfma_f32_16x16x32_bf16(a, b, acc[nt], 0, 0, 0);
    }
    __syncthreads();
  }

  int pbase = p0 + pg * 16 + q * 4;
#pragma unroll
  for (int nt = 0; nt < 4; ++nt) {
    int o = blockIdx.y * 128 + cg * 64 + nt * 16 + n;
    float bv = bias ? bias[o] : 0.f;
#pragma unroll
    for (int r = 0; r < 4; ++r) {
      float v = acc[nt][r] + bv;
      if (out1) out1[(size_t)o * HW + pbase + r] = v;
      if (out2) out2[(size_t)(pbase + r) * ns2 + o] = f2b(v);
    }
  }
}

// ---- K-split partial 1x1 conv (NCHW fp32 in), for tiny-HW huge-K (p5) ---
__global__ __launch_bounds__(256) void conv1x1_part_kernel(
    const float* __restrict__ A1, int HW,
    const bf16* __restrict__ BP, float* __restrict__ PART) {
  __shared__ __align__(16) bf16 sA[1024];   // [4 q][32 px][8]
  int p0 = blockIdx.x * 32;
  int tid = threadIdx.x;
  int pix = tid & 31, sub = tid >> 5;
  int lane = tid & 63, wave = tid >> 6;
  int pg = wave & 1, cg = wave >> 1;
  int q = lane >> 4, n = lane & 15;

  floatx4 acc[4];
#pragma unroll
  for (int nt = 0; nt < 4; ++nt) acc[nt] = (floatx4)0.f;

  int kc0 = blockIdx.z * 8;
  for (int kcl = 0; kcl < 8; ++kcl) {
    int kc = kc0 + kcl;
    int ci0 = kc << 5;
#pragma unroll
    for (int it = 0; it < 4; ++it) {
      int cil = it * 8 + sub;
      sA[((cil >> 3) * 32 + pix) * 8 + (cil & 7)] =
          f2b(A1[(size_t)(ci0 + cil) * HW + p0 + pix]);
    }
    __syncthreads();
    bf16x8 a = *(const bf16x8*)&sA[(q * 32 + pg * 16 + n) * 8];
    const bf16* bp = BP + ((size_t)(kc * 4 + q) * 256 + blockIdx.y * 128 + cg * 64) * 8;
#pragma unroll
    for (int nt = 0; nt < 4; ++nt) {
      bf16x8 b = *(const bf16x8*)&bp[(nt * 16 + n) * 8];
      acc[nt] = __builtin_amdgcn_mfma_f32_16x16x32_bf16(a, b, acc[nt], 0, 0, 0);
    }
    __syncthreads();
  }

  int pbase = p0 + pg * 16 + q * 4;
#pragma unroll
  for (int nt = 0; nt < 4; ++nt) {
    int o = blockIdx.y * 128 + cg * 64 + nt * 16 + n;
#pragma unroll
    for (int r = 0; r < 4; ++r)
      PART[((size_t)blockIdx.z * 256 + o) * HW + pbase + r] = acc[nt][r];
  }
}

// ---- reduce K-split partials + bias -> fp32 NCHW + bf16 NHWC ------------
__global__ __launch_bounds__(256) void reduce_p5_kernel(
    const float* __restrict__ PART, const float* __restrict__ bias,
    float* __restrict__ out1, bf16* __restrict__ out2, int HW, int KS) {
  int o = blockIdx.x;
  int p = threadIdx.x;
  float s = bias[o];
  for (int z = 0; z < KS; ++z) s += PART[((size_t)z * 256 + o) * HW + p];
  out1[(size_t)o * HW + p] = s;
  out2[(size_t)p * 256 + o] = f2b(s);
}

// ------- 3x3 conv v2: row-window staging + reg-prefetch pipeline ---------
template <int S>
__global__ __launch_bounds__(256) void conv3x3v2_kernel(
    const bf16* __restrict__ in, const bf16* __restrict__ BP,
    const float* __restrict__ bias,
    int H, int W, int Co,
    float* __restrict__ out1, bf16* __restrict__ out2, int ns2) {
  constexpr int P = 32 * S + 2;
  constexpr int TASKS = 3 * P * 8;            // ushort4 stage tasks per kc
  constexpr int ITS = (TASKS + 255) / 256;
  __shared__ __align__(16) bf16 sA[2][4 * 3 * P * 8];
  int HW = H * W;
  int segs = W / (32 * S);
  int y = blockIdx.x / segs;
  int x0 = (blockIdx.x - y * segs) * (32 * S);
  int tid = threadIdx.x;
  int lane = tid & 63, wave = tid >> 6;
  int pg = wave & 1, cg = wave >> 1;
  int q = lane >> 4, n = lane & 15;

  // --- precompute per-thread staging tasks (kc-invariant) ---
  int dstIdx[ITS], srcOff[ITS];
  bool act[ITS], val[ITS];
#pragma unroll
  for (int it = 0; it < ITS; ++it) {
    int tt = it * 256 + tid;
    act[it] = (tt < TASKS);
    int sub8 = tt & 7;
    int rp = tt >> 3;
    int row = rp / P;
    int pxl = rp - row * P;
    int yy = y + row - 1;
    int xg = x0 + pxl - 1;
    bool v = act[it] && ((unsigned)yy < (unsigned)H) && ((unsigned)xg < (unsigned)W);
    val[it] = v;
    srcOff[it] = v ? ((yy * W + xg) * 256 + sub8 * 4) : 0;
    dstIdx[it] = (((sub8 >> 1) * 3 + row) * P + pxl) * 8 + (sub8 & 1) * 4;
  }

  ushort4 pv[ITS];
  auto load_regs = [&](int kc) {
    int cb = kc << 5;
#pragma unroll
    for (int it = 0; it < ITS; ++it) {
      ushort4 z = {0, 0, 0, 0};
      pv[it] = val[it] ? *(const ushort4*)&in[(size_t)srcOff[it] + cb] : z;
    }
  };
  auto store_lds = [&](int buf) {
#pragma unroll
    for (int it = 0; it < ITS; ++it)
      if (act[it]) *(ushort4*)&sA[buf][dstIdx[it]] = pv[it];
  };

  floatx4 acc[S][4];
#pragma unroll
  for (int s = 0; s < S; ++s)
#pragma unroll
    for (int nt = 0; nt < 4; ++nt) acc[s][nt] = (floatx4)0.f;

  load_regs(0);
  store_lds(0);
  __syncthreads();
  load_regs(1);

  for (int kc = 0; kc < 8; ++kc) {
    const bf16* sv = &sA[kc & 1][0];
    const bf16* bpc = BP + (size_t)kc * 73728;   // kc*9*4*256*8
#pragma unroll
    for (int tap = 0; tap < 9; ++tap) {
      int ty = tap / 3, tx = tap % 3;            // row = dy+1, xoff = dx+1
      bf16x8 a[S];
#pragma unroll
      for (int s = 0; s < S; ++s)
        a[s] = *(const bf16x8*)&sv[((q * 3 + ty) * P + tx + s * 32 + pg * 16 + n) * 8];
      const bf16* bp = bpc + ((size_t)(tap * 4 + q) * 256 + blockIdx.y * 128 + cg * 64) * 8;
#pragma unroll
      for (int nt = 0; nt < 4; ++nt) {
        bf16x8 b = *(const bf16x8*)&bp[(nt * 16 + n) * 8];
#pragma unroll
        for (int s = 0; s < S; ++s)
          acc[s][nt] = __builtin_amdgcn_mfma_f32_16x16x32_bf16(a[s], b, acc[s][nt], 0, 0, 0);
      }
    }
    if (kc < 7) {
      store_lds((kc + 1) & 1);     // target buf last read at kc-1 (fenced)
      __syncthreads();             // publish for mfma(kc+1)
      if (kc < 6) load_regs(kc + 2);
    }
  }

#pragma unroll
  for (int s = 0; s < S; ++s) {
    int pbase = y * W + x0 + s * 32 + pg * 16 + q * 4;
#pragma unroll
    for (int nt = 0; nt < 4; ++nt) {
      int o = blockIdx.y * 128 + cg * 64 + nt * 16 + n;
      if (o < Co) {
        float bv = bias ? bias[o] : 0.f;
#pragma unroll
        for (int r = 0; r < 4; ++r) {
          float v = acc[s][nt][r] + bv;
          if (out1) out1[(size_t)o * HW + pbase + r] = v;
          if (out2) out2[(size_t)(pbase + r) * ns2 + o] = f2b(v);
        }
      }
    }
  }
}

// ---- mdcn v4: 64-px tile, thread owns (group, pixel), reg meta ----------
// Thread t: g = t>>6 (=wave), px = t&63. Per tap: meta in REGISTERS (one
// thread = one (g,px): no meta LDS, no redundancy), gather 32 ch via 4x
// dwordx4 per neighbor, bilinear in fp32 (identical math/order to v3),
// write 4x b128 rows to sval. M=64 => packed-B read once per block (halved
// L2 traffic). Double-buffered per-tap sval, one barrier per tap.
// K tap-major (k = tap*256 + ci) matching packwd_kernel.  grid = HW/64.
__global__ __launch_bounds__(512, 2) void mdcn_mfma_kernel(
    const bf16* __restrict__ UPn, const bf16* __restrict__ OM,
    const bf16* __restrict__ BP, const float* __restrict__ dcn_b,
    const bf16* __restrict__ ARM, bf16* __restrict__ F,
    int H, int W, int wshift) {
  // sval buffer: [32 R][64 px][8 ch] + 8 pad/row (stride 520) = 33,280 B
  __shared__ __align__(16) bf16 sval[2][32 * 520];
  int pb = blockIdx.x * 64;
  int tid = threadIdx.x;
  int g = tid >> 6;                 // gather: group = wave
  int px = tid & 63;
  int p = pb + px;
  int y = p >> wshift, x = p & (W - 1);
  const bf16* omp = OM + (size_t)p * 216 + g * 18;
  const bf16* omm = OM + (size_t)p * 216 + 144 + g * 9;
  int lane = tid & 63, wave = tid >> 6;
  int q = lane >> 4, n = lane & 15;

  floatx4 acc[4][2];
#pragma unroll
  for (int m = 0; m < 4; ++m)
#pragma unroll
    for (int nt = 0; nt < 2; ++nt) acc[m][nt] = (floatx4)0.f;

  auto gather = [&](int t) {
    bf16* sv = &sval[t & 1][0];
    int ky = t / 3, kx = t - ky * 3;
    float dy = b2f(omp[t]);
    float dx = b2f(omp[9 + t]);
    float mm = 1.f / (1.f + expf(-b2f(omm[t])));
    float fpy = (float)(y - 1 + ky) + dy;
    float fpx = (float)(x - 1 + kx) + dx;
    fpy = fminf(fmaxf(fpy, -1.0e4f), 1.0e4f);
    fpx = fminf(fmaxf(fpx, -1.0e4f), 1.0e4f);
    float fy0 = floorf(fpy), fx0 = floorf(fpx);
    float wy1 = fpy - fy0, wx1 = fpx - fx0;
    float wy0 = 1.f - wy1, wx0 = 1.f - wx1;
    int iy0 = (int)fy0, ix0 = (int)fx0;
    bool vy0 = (unsigned)iy0 < (unsigned)H;
    bool vy1 = (unsigned)(iy0 + 1) < (unsigned)H;
    bool vx0 = (unsigned)ix0 < (unsigned)W;
    bool vx1 = (unsigned)(ix0 + 1) < (unsigned)W;
    float w00 = (vy0 && vx0) ? mm * wy0 * wx0 : 0.f;
    float w01 = (vy0 && vx1) ? mm * wy0 * wx1 : 0.f;
    float w10 = (vy1 && vx0) ? mm * wy1 * wx0 : 0.f;
    float w11 = (vy1 && vx1) ? mm * wy1 * wx1 : 0.f;
    int iy0c = min(max(iy0, 0), H - 1);
    int iy1c = min(max(iy0 + 1, 0), H - 1);
    int ix0c = min(max(ix0, 0), W - 1);
    int ix1c = min(max(ix0 + 1, 0), W - 1);
    int dxs = (ix1c - ix0c) * 256;
    int dyW = (iy1c - iy0c) * W * 256;
    const bf16* up = UPn + (size_t)(iy0c * W + ix0c) * 256 + g * 32;
#pragma unroll
    for (int cc = 0; cc < 4; ++cc) {
      const bf16* b0 = up + cc * 8;
      ushort8v u00 = *(const ushort8v*)(b0);
      ushort8v u01 = *(const ushort8v*)(b0 + dxs);
      ushort8v u10 = *(const ushort8v*)(b0 + dyW);
      ushort8v u11 = *(const ushort8v*)(b0 + dyW + dxs);
      ushort8v o;
#pragma unroll
      for (int j = 0; j < 8; ++j) {
        float s = w00 * us2f(u00[j]) + w01 * us2f(u01[j])
                + w10 * us2f(u10[j]) + w11 * us2f(u11[j]);
        o[j] = f2us(s);
      }
      *(ushort8v*)&sv[(g * 4 + cc) * 520 + px * 8] = o;
    }
  };

  gather(0);
  for (int t = 0; t < 9; ++t) {
    __syncthreads();                 // publish sval[t&1]
    if (t < 8) gather(t + 1);        // issue next-tap loads early
    const bf16* sv = &sval[t & 1][0];
    const bf16* bpt = BP + ((size_t)(t * 32) * 256 + wave * 32) * 8;
#pragma unroll
    for (int kc = 0; kc < 8; ++kc) {
      int R = kc * 4 + q;
      const bf16* bp = bpt + (size_t)R * 2048;   // R*256*8
      bf16x8 b0 = *(const bf16x8*)&bp[n * 8];
      bf16x8 b1 = *(const bf16x8*)&bp[(16 + n) * 8];
#pragma unroll
      for (int m = 0; m < 4; ++m) {
        bf16x8 a = *(const bf16x8*)&sv[R * 520 + (m * 16 + n) * 8];
        acc[m][0] = __builtin_amdgcn_mfma_f32_16x16x32_bf16(a, b0, acc[m][0], 0, 0, 0);
        acc[m][1] = __builtin_amdgcn_mfma_f32_16x16x32_bf16(a, b1, acc[m][1], 0, 0, 0);
      }
    }
  }

#pragma unroll
  for (int m = 0; m < 4; ++m) {
#pragma unroll
    for (int nt = 0; nt < 2; ++nt) {
      int o = wave * 32 + nt * 16 + n;
      float bv = dcn_b[o];
#pragma unroll
      for (int r = 0; r < 4; ++r) {
        int pp = pb + m * 16 + q * 4 + r;
        float v = fmaxf(acc[m][nt][r] + bv, 0.f) + b2f(ARM[(size_t)pp * 256 + o]);
        F[(size_t)pp * 256 + o] = f2b(v);
      }
    }
  }
}

extern "C" void kernel_launch(void* const* d_in, const int* in_sizes, int n_in,
                              void* d_out, int out_size, void* d_ws, size_t ws_size,
                              hipStream_t stream) {
  // Inputs fp32, outputs fp32 (established rounds 3-5). Interior: bf16 NHWC.
  const float* c2 = (const float*)d_in[0];
  const float* c3 = (const float*)d_in[1];
  const float* c4 = (const float*)d_in[2];
  const float* c5 = (const float*)d_in[3];
  const float* lat_w = (const float*)d_in[31];
  const float* lat_b = (const float*)d_in[32];
  float* out = (float*)d_out;
  (void)ws_size; (void)in_sizes; (void)n_in; (void)out_size;

  const size_t p2_off = 0;
  const size_t p3_off = 4194304;
  const size_t p4_off = p3_off + 1048576;
  const size_t p5_off = p4_off + 262144;

  // ---- ws layout (~25.3MB; ws_size >= 28MB proven round 3) ----
  char* ws = (char*)d_ws;
  bf16* UPn = (bf16*)(ws);                    // 8MB NHWC
  bf16* ARM = (bf16*)(ws + 8388608);          // 8MB NHWC
  bf16* FB  = (bf16*)(ws + 16777216);         // 8MB NHWC (off_feat & F alias)
  bf16* P5N = (bf16*)(ws + 25165824);         // 128KB NHWC p5 copy
  bf16* BPB = (bf16*)(ws + 25296896);         // 1.125MB packed-B scratch
  float* GAP = (float*)(ws + 26476544);
  float* SC  = (float*)(ws + 26484736);
  // OM (NHWC stride 216, 6.75MB max) borrows the p2 output region (16.8MB);
  // p2 is written only by the final conv, after mdcn consumed OM.
  bf16* OM = (bf16*)(out + p2_off);
  // p5 K-split partials (2MB) borrow the UPn region.
  float* PART = (float*)ws;

  // ---- p5 = conv1x1(c5, lat_w, lat_b), K-split x8 + reduce --------------
  packw1_kernel<<<2048, 256, 0, stream>>>(lat_w, BPB, 2048);
  conv1x1_part_kernel<<<dim3(8, 2, 8), 256, 0, stream>>>(c5, 256, BPB, PART);
  reduce_p5_kernel<<<256, 256, 0, stream>>>(PART, lat_b, out + p5_off, P5N, 256, 8);

  struct Lv {
    const float* featl; int Ci; int H; int W; int wshift;
    float* pdst; int wbase;
  };
  Lv levels[3] = {
      {c4, 1024, 32, 32, 5, out + p4_off, 4},
      {c3, 512, 64, 64, 6, out + p3_off, 13},
      {c2, 256, 128, 128, 7, out + p2_off, 22},
  };

  for (int li = 0; li < 3; ++li) {
    const Lv& L = levels[li];
    const float* att_w = (const float*)d_in[L.wbase + 0];
    const float* fsm_w = (const float*)d_in[L.wbase + 1];
    const float* off_w = (const float*)d_in[L.wbase + 2];
    const float* om_w  = (const float*)d_in[L.wbase + 3];
    const float* om_b  = (const float*)d_in[L.wbase + 4];
    const float* dcn_w = (const float*)d_in[L.wbase + 5];
    const float* dcn_b = (const float*)d_in[L.wbase + 6];
    const float* out_w = (const float*)d_in[L.wbase + 7];
    const float* out_b = (const float*)d_in[L.wbase + 8];
    int HW = L.H * L.W;

    // 1) feat_up = bilinear 2x (NHWC -> NHWC): src = P5N or previous F(FB)
    upsample2x_nhwc_kernel<<<HW, 256, 0, stream>>>(
        (li == 0) ? P5N : FB, UPn, L.H / 2, L.W / 2);
    // 2) FSM: gap -> atten -> scaled 1x1 GEMM -> ARM (NHWC)
    gap_kernel<<<L.Ci, 256, 0, stream>>>(L.featl, GAP, HW, 1.f / (float)HW);
    atten_kernel<<<L.Ci / 4, 256, 0, stream>>>(att_w, GAP, SC, L.Ci);
    packw1_kernel<<<L.Ci, 256, 0, stream>>>(fsm_w, BPB, L.Ci);
    conv1x1_mfma_kernel<true, float><<<dim3(HW / 32, 2), 256, 0, stream>>>(
        L.featl, SC, nullptr, 0.f, L.Ci, 0, HW, BPB, nullptr,
        nullptr, ARM, 256);
    // 3) off_feat = conv1x1(concat(ARM, 2*UPn)) -> FB (NHWC)
    packw1_kernel<<<512, 256, 0, stream>>>(off_w, BPB, 512);
    conv1x1_mfma_kernel<false, bf16><<<dim3(HW / 32, 2), 256, 0, stream>>>(
        ARM, nullptr, UPn, 2.f, 256, 256, HW, BPB, nullptr,
        nullptr, FB, 256);
    // 4) om = conv3x3(FB) + om_b -> OM (NHWC stride 216, in p2 region)
    packw3_kernel<<<2304, 256, 0, stream>>>(om_w, BPB, 256, 216);
    if (li == 2)
      conv3x3v2_kernel<2><<<dim3(HW / 64, 2), 256, 0, stream>>>(
          FB, BPB, om_b, L.H, L.W, 216, nullptr, OM, 216);
    else
      conv3x3v2_kernel<1><<<dim3(HW / 32, 2), 256, 0, stream>>>(
          FB, BPB, om_b, L.H, L.W, 216, nullptr, OM, 216);
    // 5) F = relu(mdcn(UPn, OM) + dcn_b) + ARM -> FB (NHWC)
    packwd_kernel<<<2304, 256, 0, stream>>>(dcn_w, BPB);
    mdcn_mfma_kernel<<<HW / 64, 512, 0, stream>>>(
        UPn, OM, BPB, dcn_b, ARM, FB, L.H, L.W, L.wshift);
    // 6) p = conv3x3(F) + out_b -> fp32 NCHW output
    packw3_kernel<<<2304, 256, 0, stream>>>(out_w, BPB, 256, 256);
    if (li == 2)
      conv3x3v2_kernel<2><<<dim3(HW / 64, 2), 256, 0, stream>>>(
          FB, BPB, out_b, L.H, L.W, 256, L.pdst, nullptr, 256);
    else
      conv3x3v2_kernel<1><<<dim3(HW / 32, 2), 256, 0, stream>>>(
          FB, BPB, out_b, L.H, L.W, 256, L.pdst, nullptr, 256);
  }
}

// Round 7
// 723.716 us; speedup vs baseline: 1.1507x; 1.1507x over previous
//
#include <hip/hip_runtime.h>
#include <hip/hip_bf16.h>

typedef __hip_bfloat16 bf16;
typedef __attribute__((ext_vector_type(8))) short bf16x8;
typedef __attribute__((ext_vector_type(4))) float floatx4;

__device__ __forceinline__ float b2f(bf16 v) { return __bfloat162float(v); }
__device__ __forceinline__ bf16 f2b(float v) { return __float2bfloat16(v); }
__device__ __forceinline__ float us2f(unsigned short u) {
  union { unsigned int i; float f; } v; v.i = ((unsigned int)u) << 16; return v.f;
}
__device__ __forceinline__ unsigned short f2us(float f) {
  bf16 h = f2b(f); return *(unsigned short*)&h;
}

// ---------------- global average pool: x (C,HW) fp32 NCHW -> gap[C] ------
__global__ __launch_bounds__(256) void gap_kernel(const float* __restrict__ x,
                                                  float* __restrict__ gap,
                                                  int HW, float inv) {
  int c = blockIdx.x;
  const float* p = x + (size_t)c * HW;
  float s = 0.f;
  for (int i = threadIdx.x; i < HW; i += 256) s += p[i];
  __shared__ float red[256];
  red[threadIdx.x] = s;
  __syncthreads();
  for (int w = 128; w > 0; w >>= 1) {
    if (threadIdx.x < w) red[threadIdx.x] += red[threadIdx.x + w];
    __syncthreads();
  }
  if (threadIdx.x == 0) gap[c] = red[0] * inv;
}

// -------- scale[o] = 1 + sigmoid( sum_i att_w[o,i] * gap[i] ) ------------
__global__ __launch_bounds__(256) void atten_kernel(const float* __restrict__ w,
                                                    const float* __restrict__ gap,
                                                    float* __restrict__ scale, int Ci) {
  int wave = threadIdx.x >> 6, lane = threadIdx.x & 63;
  int o = blockIdx.x * 4 + wave;
  const float4* wr = (const float4*)(w + (size_t)o * Ci);
  const float4* g4 = (const float4*)gap;
  int n4 = Ci >> 2;
  float s = 0.f;
  for (int i = lane; i < n4; i += 64) {
    float4 a = wr[i], b = g4[i];
    s += a.x * b.x + a.y * b.y + a.z * b.z + a.w * b.w;
  }
#pragma unroll
  for (int off = 32; off > 0; off >>= 1) s += __shfl_down(s, off);
  if (lane == 0) scale[o] = 1.f + 1.f / (1.f + expf(-s));
}

// ---- bilinear 2x upsample NHWC(256) -> NHWC(256), half-pixel, clamp -----
__global__ __launch_bounds__(256) void upsample2x_nhwc_kernel(
    const bf16* __restrict__ src, bf16* __restrict__ dst, int Hs, int Ws) {
  int p = blockIdx.x;       // output pixel
  int c = threadIdx.x;      // channel
  int W = Ws * 2;
  int y = p / W, x = p - y * W;
  float fy = y * 0.5f - 0.25f;
  float fx = x * 0.5f - 0.25f;
  int y0 = (int)floorf(fy), x0 = (int)floorf(fx);
  float wy1 = fy - (float)y0, wx1 = fx - (float)x0;
  int y0c = min(max(y0, 0), Hs - 1);
  int y1c = min(max(y0 + 1, 0), Hs - 1);
  int x0c = min(max(x0, 0), Ws - 1);
  int x1c = min(max(x0 + 1, 0), Ws - 1);
  float v00 = b2f(src[(size_t)(y0c * Ws + x0c) * 256 + c]);
  float v01 = b2f(src[(size_t)(y0c * Ws + x1c) * 256 + c]);
  float v10 = b2f(src[(size_t)(y1c * Ws + x0c) * 256 + c]);
  float v11 = b2f(src[(size_t)(y1c * Ws + x1c) * 256 + c]);
  float v = (1.f - wy1) * ((1.f - wx1) * v00 + wx1 * v01)
          + wy1 * ((1.f - wx1) * v10 + wx1 * v11);
  dst[(size_t)p * 256 + c] = f2b(v);
}

// ------- pack GEMM weights (fp32 [256][K]) -> bf16 MFMA-B layout ---------
__global__ __launch_bounds__(256) void packw1_kernel(const float* __restrict__ w,
                                                     bf16* __restrict__ BP, int K) {
  int idx = blockIdx.x * 256 + threadIdx.x;
  int j = idx & 7;
  int o = (idx >> 3) & 255;
  int kc8 = idx >> 11;
  int k = kc8 * 8 + j;
  BP[idx] = f2b(w[(size_t)o * K + k]);
}

// ------- pack dcn 3x3 weights tap-major: k = tap*256 + ci ----------------
__global__ __launch_bounds__(256) void packwd_kernel(const float* __restrict__ w,
                                                     bf16* __restrict__ BP) {
  int idx = blockIdx.x * 256 + threadIdx.x;
  int j = idx & 7;
  int o = (idx >> 3) & 255;
  int k8 = idx >> 11;
  int k = k8 * 8 + j;          // 0..2303, tap-major
  int tap = k >> 8;            // 0..8
  int ci = k & 255;
  BP[idx] = f2b(w[((size_t)o * 256 + ci) * 9 + tap]);
}

// ------- pack 3x3 conv weights (fp32 OIHW, Ci=256) -> bf16 B layout ------
__global__ __launch_bounds__(256) void packw3_kernel(const float* __restrict__ w,
                                                     bf16* __restrict__ BP,
                                                     int Ci, int Co) {
  int idx = blockIdx.x * 256 + threadIdx.x;
  int total = Ci * 9 * 256;
  if (idx >= total) return;
  int j = idx & 7;
  int t1 = idx >> 3;
  int o = t1 & 255;
  int t2 = t1 >> 8;
  int q = t2 & 3;
  int t3 = t2 >> 2;
  int tap = t3 % 9;
  int c = t3 / 9;
  int ci = c * 32 + q * 8 + j;
  float v = (o < Co) ? w[((size_t)o * Ci + ci) * 9 + tap] : 0.f;
  BP[idx] = f2b(v);
}

// ------------- 1x1 conv as MFMA GEMM -------------------------------------
template <bool NCHW1, typename TA1>
__global__ __launch_bounds__(256) void conv1x1_mfma_kernel(
    const TA1* __restrict__ A1, const float* __restrict__ scaleA,
    const bf16* __restrict__ A2, float scaleB,
    int Ci1, int Ci2, int HW,
    const bf16* __restrict__ BP, const float* __restrict__ bias,
    float* __restrict__ out1, bf16* __restrict__ out2, int ns2) {
  __shared__ __align__(16) bf16 sA[1024];   // [4 q][32 px][8]
  int p0 = blockIdx.x * 32;
  int tid = threadIdx.x;
  int pix = tid & 31, sub = tid >> 5;       // fp32-NCHW staging mapping
  int pix2 = tid >> 3, sub8 = tid & 7;      // NHWC staging mapping
  int lane = tid & 63, wave = tid >> 6;
  int pg = wave & 1, cg = wave >> 1;
  int q = lane >> 4, n = lane & 15;

  floatx4 acc[4];
#pragma unroll
  for (int nt = 0; nt < 4; ++nt) acc[nt] = (floatx4)0.f;

  int nch = (Ci1 + Ci2) >> 5;
  for (int kc = 0; kc < nch; ++kc) {
    int ci0 = kc << 5;
    if (NCHW1 && ci0 < Ci1) {
#pragma unroll
      for (int it = 0; it < 4; ++it) {
        int cil = it * 8 + sub;
        float x = (float)A1[(size_t)(ci0 + cil) * HW + p0 + pix];
        if (scaleA) x *= scaleA[ci0 + cil];
        sA[((cil >> 3) * 32 + pix) * 8 + (cil & 7)] = f2b(x);
      }
    } else {
      const bf16* src; int cb; bool scl;
      if (!NCHW1 && ci0 < Ci1) {
        src = (const bf16*)(const void*)A1; cb = ci0; scl = false;
      } else {
        src = A2; cb = ci0 - Ci1; scl = true;
      }
      ushort4 raw = *(const ushort4*)&src[(size_t)(p0 + pix2) * 256 + cb + sub8 * 4];
      if (scl) {
        raw.x = f2us(us2f(raw.x) * scaleB);
        raw.y = f2us(us2f(raw.y) * scaleB);
        raw.z = f2us(us2f(raw.z) * scaleB);
        raw.w = f2us(us2f(raw.w) * scaleB);
      }
      *(ushort4*)&sA[((sub8 >> 1) * 32 + pix2) * 8 + (sub8 & 1) * 4] = raw;
    }
    __syncthreads();
    bf16x8 a = *(const bf16x8*)&sA[(q * 32 + pg * 16 + n) * 8];
    const bf16* bp = BP + ((size_t)(kc * 4 + q) * 256 + blockIdx.y * 128 + cg * 64) * 8;
#pragma unroll
    for (int nt = 0; nt < 4; ++nt) {
      bf16x8 b = *(const bf16x8*)&bp[(nt * 16 + n) * 8];
      acc[nt] = __builtin_amdgcn_mfma_f32_16x16x32_bf16(a, b, acc[nt], 0, 0, 0);
    }
    __syncthreads();
  }

  int pbase = p0 + pg * 16 + q * 4;
#pragma unroll
  for (int nt = 0; nt < 4; ++nt) {
    int o = blockIdx.y * 128 + cg * 64 + nt * 16 + n;
    float bv = bias ? bias[o] : 0.f;
#pragma unroll
    for (int r = 0; r < 4; ++r) {
      float v = acc[nt][r] + bv;
      if (out1) out1[(size_t)o * HW + pbase + r] = v;
      if (out2) out2[(size_t)(pbase + r) * ns2 + o] = f2b(v);
    }
  }
}

// ---- K-split partial 1x1 conv (NCHW fp32 in), for tiny-HW huge-K (p5) ---
__global__ __launch_bounds__(256) void conv1x1_part_kernel(
    const float* __restrict__ A1, int HW,
    const bf16* __restrict__ BP, float* __restrict__ PART) {
  __shared__ __align__(16) bf16 sA[1024];   // [4 q][32 px][8]
  int p0 = blockIdx.x * 32;
  int tid = threadIdx.x;
  int pix = tid & 31, sub = tid >> 5;
  int lane = tid & 63, wave = tid >> 6;
  int pg = wave & 1, cg = wave >> 1;
  int q = lane >> 4, n = lane & 15;

  floatx4 acc[4];
#pragma unroll
  for (int nt = 0; nt < 4; ++nt) acc[nt] = (floatx4)0.f;

  int kc0 = blockIdx.z * 8;
  for (int kcl = 0; kcl < 8; ++kcl) {
    int kc = kc0 + kcl;
    int ci0 = kc << 5;
#pragma unroll
    for (int it = 0; it < 4; ++it) {
      int cil = it * 8 + sub;
      sA[((cil >> 3) * 32 + pix) * 8 + (cil & 7)] =
          f2b(A1[(size_t)(ci0 + cil) * HW + p0 + pix]);
    }
    __syncthreads();
    bf16x8 a = *(const bf16x8*)&sA[(q * 32 + pg * 16 + n) * 8];
    const bf16* bp = BP + ((size_t)(kc * 4 + q) * 256 + blockIdx.y * 128 + cg * 64) * 8;
#pragma unroll
    for (int nt = 0; nt < 4; ++nt) {
      bf16x8 b = *(const bf16x8*)&bp[(nt * 16 + n) * 8];
      acc[nt] = __builtin_amdgcn_mfma_f32_16x16x32_bf16(a, b, acc[nt], 0, 0, 0);
    }
    __syncthreads();
  }

  int pbase = p0 + pg * 16 + q * 4;
#pragma unroll
  for (int nt = 0; nt < 4; ++nt) {
    int o = blockIdx.y * 128 + cg * 64 + nt * 16 + n;
#pragma unroll
    for (int r = 0; r < 4; ++r)
      PART[((size_t)blockIdx.z * 256 + o) * HW + pbase + r] = acc[nt][r];
  }
}

// ---- reduce K-split partials + bias -> fp32 NCHW + bf16 NHWC ------------
__global__ __launch_bounds__(256) void reduce_p5_kernel(
    const float* __restrict__ PART, const float* __restrict__ bias,
    float* __restrict__ out1, bf16* __restrict__ out2, int HW, int KS) {
  int o = blockIdx.x;
  int p = threadIdx.x;
  float s = bias[o];
  for (int z = 0; z < KS; ++z) s += PART[((size_t)z * 256 + o) * HW + p];
  out1[(size_t)o * HW + p] = s;
  out2[(size_t)p * 256 + o] = f2b(s);
}

// ------- 3x3 conv v2: row-window staging + reg-prefetch pipeline ---------
template <int S>
__global__ __launch_bounds__(256) void conv3x3v2_kernel(
    const bf16* __restrict__ in, const bf16* __restrict__ BP,
    const float* __restrict__ bias,
    int H, int W, int Co,
    float* __restrict__ out1, bf16* __restrict__ out2, int ns2) {
  constexpr int P = 32 * S + 2;
  constexpr int TASKS = 3 * P * 8;            // ushort4 stage tasks per kc
  constexpr int ITS = (TASKS + 255) / 256;
  __shared__ __align__(16) bf16 sA[2][4 * 3 * P * 8];
  int HW = H * W;
  int segs = W / (32 * S);
  int y = blockIdx.x / segs;
  int x0 = (blockIdx.x - y * segs) * (32 * S);
  int tid = threadIdx.x;
  int lane = tid & 63, wave = tid >> 6;
  int pg = wave & 1, cg = wave >> 1;
  int q = lane >> 4, n = lane & 15;

  // --- precompute per-thread staging tasks (kc-invariant) ---
  int dstIdx[ITS], srcOff[ITS];
  bool act[ITS], val[ITS];
#pragma unroll
  for (int it = 0; it < ITS; ++it) {
    int tt = it * 256 + tid;
    act[it] = (tt < TASKS);
    int sub8 = tt & 7;
    int rp = tt >> 3;
    int row = rp / P;
    int pxl = rp - row * P;
    int yy = y + row - 1;
    int xg = x0 + pxl - 1;
    bool v = act[it] && ((unsigned)yy < (unsigned)H) && ((unsigned)xg < (unsigned)W);
    val[it] = v;
    srcOff[it] = v ? ((yy * W + xg) * 256 + sub8 * 4) : 0;
    dstIdx[it] = (((sub8 >> 1) * 3 + row) * P + pxl) * 8 + (sub8 & 1) * 4;
  }

  ushort4 pv[ITS];
  auto load_regs = [&](int kc) {
    int cb = kc << 5;
#pragma unroll
    for (int it = 0; it < ITS; ++it) {
      ushort4 z = {0, 0, 0, 0};
      pv[it] = val[it] ? *(const ushort4*)&in[(size_t)srcOff[it] + cb] : z;
    }
  };
  auto store_lds = [&](int buf) {
#pragma unroll
    for (int it = 0; it < ITS; ++it)
      if (act[it]) *(ushort4*)&sA[buf][dstIdx[it]] = pv[it];
  };

  floatx4 acc[S][4];
#pragma unroll
  for (int s = 0; s < S; ++s)
#pragma unroll
    for (int nt = 0; nt < 4; ++nt) acc[s][nt] = (floatx4)0.f;

  load_regs(0);
  store_lds(0);
  __syncthreads();
  load_regs(1);

  for (int kc = 0; kc < 8; ++kc) {
    const bf16* sv = &sA[kc & 1][0];
    const bf16* bpc = BP + (size_t)kc * 73728;   // kc*9*4*256*8
#pragma unroll
    for (int tap = 0; tap < 9; ++tap) {
      int ty = tap / 3, tx = tap % 3;            // row = dy+1, xoff = dx+1
      bf16x8 a[S];
#pragma unroll
      for (int s = 0; s < S; ++s)
        a[s] = *(const bf16x8*)&sv[((q * 3 + ty) * P + tx + s * 32 + pg * 16 + n) * 8];
      const bf16* bp = bpc + ((size_t)(tap * 4 + q) * 256 + blockIdx.y * 128 + cg * 64) * 8;
#pragma unroll
      for (int nt = 0; nt < 4; ++nt) {
        bf16x8 b = *(const bf16x8*)&bp[(nt * 16 + n) * 8];
#pragma unroll
        for (int s = 0; s < S; ++s)
          acc[s][nt] = __builtin_amdgcn_mfma_f32_16x16x32_bf16(a[s], b, acc[s][nt], 0, 0, 0);
      }
    }
    if (kc < 7) {
      store_lds((kc + 1) & 1);     // target buf last read at kc-1 (fenced)
      __syncthreads();             // publish for mfma(kc+1)
      if (kc < 6) load_regs(kc + 2);
    }
  }

#pragma unroll
  for (int s = 0; s < S; ++s) {
    int pbase = y * W + x0 + s * 32 + pg * 16 + q * 4;
#pragma unroll
    for (int nt = 0; nt < 4; ++nt) {
      int o = blockIdx.y * 128 + cg * 64 + nt * 16 + n;
      if (o < Co) {
        float bv = bias ? bias[o] : 0.f;
#pragma unroll
        for (int r = 0; r < 4; ++r) {
          float v = acc[s][nt][r] + bv;
          if (out1) out1[(size_t)o * HW + pbase + r] = v;
          if (out2) out2[(size_t)(pbase + r) * ns2 + o] = f2b(v);
        }
      }
    }
  }
}

// ---- mdcn v3b: 32-px tile, 512 thr, tap-chunked K, dbuf; ushort4 gather --
// Identical structure/meta/numerics to v3 (R5, proven). Gather lanes widened:
// 8 lanes x 4ch per (group-half, px): halves VMEM+convert instruction count;
// coalescing preserved (8 lanes x 8B = full 64B line per neighbor).
// Thread map: l4 = tid&7 (ch quad), px = (tid>>3)&31, gh = tid>>8 (4 groups).
__global__ __launch_bounds__(512, 4) void mdcn_mfma_kernel(
    const bf16* __restrict__ UPn, const bf16* __restrict__ OM,
    const bf16* __restrict__ BP, const float* __restrict__ dcn_b,
    const bf16* __restrict__ ARM, bf16* __restrict__ F,
    int H, int W, int wshift) {
  // sval row: [32 px][8 ch] = 256 bf16 + 16 pad = 272 (stride 544 B)
  __shared__ __align__(16) bf16 sval[2][32 * 272];   // 34,816 B
  __shared__ float4 mw[2304];                        // 36,864 B
  __shared__ int mi[2304];                           //  9,216 B
  int pb = blockIdx.x * 32;
  int tid = threadIdx.x;

  // ---- meta for all 9 taps: 2304 tasks = tap*256 + g*32 + px ----
  for (int t2 = tid; t2 < 2304; t2 += 512) {
    int px_ = t2 & 31, g = (t2 >> 5) & 7, tap = t2 >> 8;
    int ky = tap / 3, kx = tap - ky * 3;
    int p = pb + px_;
    int y = p >> wshift, x = p & (W - 1);
    const bf16* omp = OM + (size_t)p * 216;
    float dy = b2f(omp[g * 18 + tap]);
    float dx = b2f(omp[g * 18 + 9 + tap]);
    float mm = 1.f / (1.f + expf(-b2f(omp[144 + g * 9 + tap])));
    float fpy = (float)(y - 1 + ky) + dy;
    float fpx = (float)(x - 1 + kx) + dx;
    fpy = fminf(fmaxf(fpy, -1.0e4f), 1.0e4f);
    fpx = fminf(fmaxf(fpx, -1.0e4f), 1.0e4f);
    float fy0 = floorf(fpy), fx0 = floorf(fpx);
    float wy1 = fpy - fy0, wx1 = fpx - fx0;
    float wy0 = 1.f - wy1, wx0 = 1.f - wx1;
    int iy0 = (int)fy0, ix0 = (int)fx0;
    bool vy0 = (unsigned)iy0 < (unsigned)H;
    bool vy1 = (unsigned)(iy0 + 1) < (unsigned)H;
    bool vx0 = (unsigned)ix0 < (unsigned)W;
    bool vx1 = (unsigned)(ix0 + 1) < (unsigned)W;
    float w00 = (vy0 && vx0) ? mm * wy0 * wx0 : 0.f;
    float w01 = (vy0 && vx1) ? mm * wy0 * wx1 : 0.f;
    float w10 = (vy1 && vx0) ? mm * wy1 * wx0 : 0.f;
    float w11 = (vy1 && vx1) ? mm * wy1 * wx1 : 0.f;
    int iy0c = min(max(iy0, 0), H - 1);
    int iy1c = min(max(iy0 + 1, 0), H - 1);
    int ix0c = min(max(ix0, 0), W - 1);
    int ix1c = min(max(ix0 + 1, 0), W - 1);
    mw[t2] = make_float4(w00, w01, w10, w11);
    mi[t2] = (iy0c * W + ix0c) | ((ix1c - ix0c) << 20) | ((iy1c - iy0c) << 21);
  }
  __syncthreads();

  int l4 = tid & 7;                   // channel quad within a 32-ch group
  int px = (tid >> 3) & 31;           // pixel
  int gh = tid >> 8;                  // group half: g = gh*4 .. gh*4+3
  int lane = tid & 63, wave = tid >> 6;
  int q = lane >> 4, n = lane & 15;
  int rowb = l4 >> 1;                 // sub-row within group's 4 rows
  int woff = px * 8 + (l4 & 1) * 4;   // bf16-elem offset within sval row

  floatx4 acc[2][2];
#pragma unroll
  for (int m = 0; m < 2; ++m)
#pragma unroll
    for (int nt = 0; nt < 2; ++nt) acc[m][nt] = (floatx4)0.f;

  auto gather = [&](int t) {
    bf16* sv = &sval[t & 1][0];
    int base = t * 256 + px + gh * 128;
#pragma unroll
    for (int gg = 0; gg < 4; ++gg) {
      int g = gh * 4 + gg;
      float4 wv = mw[base + gg * 32];
      int mv = mi[base + gg * 32];
      int idx = mv & 0x3FFFF;
      int dxs = (mv >> 20) & 1;
      int dyW = ((mv >> 21) & 1) * W;
      const bf16* up = UPn + (size_t)idx * 256 + g * 32 + l4 * 4;
      ushort4 u00 = *(const ushort4*)(up);
      ushort4 u01 = *(const ushort4*)(up + dxs * 256);
      ushort4 u10 = *(const ushort4*)(up + dyW * 256);
      ushort4 u11 = *(const ushort4*)(up + (dyW + dxs) * 256);
      ushort4 o4;
      o4.x = f2us(wv.x * us2f(u00.x) + wv.y * us2f(u01.x)
                + wv.z * us2f(u10.x) + wv.w * us2f(u11.x));
      o4.y = f2us(wv.x * us2f(u00.y) + wv.y * us2f(u01.y)
                + wv.z * us2f(u10.y) + wv.w * us2f(u11.y));
      o4.z = f2us(wv.x * us2f(u00.z) + wv.y * us2f(u01.z)
                + wv.z * us2f(u10.z) + wv.w * us2f(u11.z));
      o4.w = f2us(wv.x * us2f(u00.w) + wv.y * us2f(u01.w)
                + wv.z * us2f(u10.w) + wv.w * us2f(u11.w));
      *(ushort4*)&sv[(g * 4 + rowb) * 272 + woff] = o4;
    }
  };

  gather(0);
  for (int t = 0; t < 9; ++t) {
    __syncthreads();                 // publish sval[t&1]
    if (t < 8) gather(t + 1);        // issue next-tap loads early
    const bf16* sv = &sval[t & 1][0];
    const bf16* bpt = BP + ((size_t)(t * 32) * 256 + wave * 32) * 8;
#pragma unroll
    for (int kc = 0; kc < 8; ++kc) {
      int R = kc * 4 + q;
      bf16x8 a0 = *(const bf16x8*)&sv[R * 272 + n * 8];
      bf16x8 a1 = *(const bf16x8*)&sv[R * 272 + (16 + n) * 8];
      const bf16* bp = bpt + (size_t)R * 2048;   // R*256*8
      bf16x8 b0 = *(const bf16x8*)&bp[n * 8];
      bf16x8 b1 = *(const bf16x8*)&bp[(16 + n) * 8];
      acc[0][0] = __builtin_amdgcn_mfma_f32_16x16x32_bf16(a0, b0, acc[0][0], 0, 0, 0);
      acc[0][1] = __builtin_amdgcn_mfma_f32_16x16x32_bf16(a0, b1, acc[0][1], 0, 0, 0);
      acc[1][0] = __builtin_amdgcn_mfma_f32_16x16x32_bf16(a1, b0, acc[1][0], 0, 0, 0);
      acc[1][1] = __builtin_amdgcn_mfma_f32_16x16x32_bf16(a1, b1, acc[1][1], 0, 0, 0);
    }
  }

#pragma unroll
  for (int m = 0; m < 2; ++m) {
#pragma unroll
    for (int nt = 0; nt < 2; ++nt) {
      int o = wave * 32 + nt * 16 + n;
      float bv = dcn_b[o];
#pragma unroll
      for (int r = 0; r < 4; ++r) {
        int p = pb + m * 16 + q * 4 + r;
        float v = fmaxf(acc[m][nt][r] + bv, 0.f) + b2f(ARM[(size_t)p * 256 + o]);
        F[(size_t)p * 256 + o] = f2b(v);
      }
    }
  }
}

extern "C" void kernel_launch(void* const* d_in, const int* in_sizes, int n_in,
                              void* d_out, int out_size, void* d_ws, size_t ws_size,
                              hipStream_t stream) {
  // Inputs fp32, outputs fp32 (established rounds 3-5). Interior: bf16 NHWC.
  const float* c2 = (const float*)d_in[0];
  const float* c3 = (const float*)d_in[1];
  const float* c4 = (const float*)d_in[2];
  const float* c5 = (const float*)d_in[3];
  const float* lat_w = (const float*)d_in[31];
  const float* lat_b = (const float*)d_in[32];
  float* out = (float*)d_out;
  (void)ws_size; (void)in_sizes; (void)n_in; (void)out_size;

  const size_t p2_off = 0;
  const size_t p3_off = 4194304;
  const size_t p4_off = p3_off + 1048576;
  const size_t p5_off = p4_off + 262144;

  // ---- ws layout (~25.3MB; ws_size >= 28MB proven round 3) ----
  char* ws = (char*)d_ws;
  bf16* UPn = (bf16*)(ws);                    // 8MB NHWC
  bf16* ARM = (bf16*)(ws + 8388608);          // 8MB NHWC
  bf16* FB  = (bf16*)(ws + 16777216);         // 8MB NHWC (off_feat & F alias)
  bf16* P5N = (bf16*)(ws + 25165824);         // 128KB NHWC p5 copy
  bf16* BPB = (bf16*)(ws + 25296896);         // 1.125MB packed-B scratch
  float* GAP = (float*)(ws + 26476544);
  float* SC  = (float*)(ws + 26484736);
  // OM (NHWC stride 216, 6.75MB max) borrows the p2 output region (16.8MB);
  // p2 is written only by the final conv, after mdcn consumed OM.
  bf16* OM = (bf16*)(out + p2_off);
  // p5 K-split partials (2MB) borrow the UPn region.
  float* PART = (float*)ws;

  // ---- p5 = conv1x1(c5, lat_w, lat_b), K-split x8 + reduce --------------
  packw1_kernel<<<2048, 256, 0, stream>>>(lat_w, BPB, 2048);
  conv1x1_part_kernel<<<dim3(8, 2, 8), 256, 0, stream>>>(c5, 256, BPB, PART);
  reduce_p5_kernel<<<256, 256, 0, stream>>>(PART, lat_b, out + p5_off, P5N, 256, 8);

  struct Lv {
    const float* featl; int Ci; int H; int W; int wshift;
    float* pdst; int wbase;
  };
  Lv levels[3] = {
      {c4, 1024, 32, 32, 5, out + p4_off, 4},
      {c3, 512, 64, 64, 6, out + p3_off, 13},
      {c2, 256, 128, 128, 7, out + p2_off, 22},
  };

  for (int li = 0; li < 3; ++li) {
    const Lv& L = levels[li];
    const float* att_w = (const float*)d_in[L.wbase + 0];
    const float* fsm_w = (const float*)d_in[L.wbase + 1];
    const float* off_w = (const float*)d_in[L.wbase + 2];
    const float* om_w  = (const float*)d_in[L.wbase + 3];
    const float* om_b  = (const float*)d_in[L.wbase + 4];
    const float* dcn_w = (const float*)d_in[L.wbase + 5];
    const float* dcn_b = (const float*)d_in[L.wbase + 6];
    const float* out_w = (const float*)d_in[L.wbase + 7];
    const float* out_b = (const float*)d_in[L.wbase + 8];
    int HW = L.H * L.W;

    // 1) feat_up = bilinear 2x (NHWC -> NHWC): src = P5N or previous F(FB)
    upsample2x_nhwc_kernel<<<HW, 256, 0, stream>>>(
        (li == 0) ? P5N : FB, UPn, L.H / 2, L.W / 2);
    // 2) FSM: gap -> atten -> scaled 1x1 GEMM -> ARM (NHWC)
    gap_kernel<<<L.Ci, 256, 0, stream>>>(L.featl, GAP, HW, 1.f / (float)HW);
    atten_kernel<<<L.Ci / 4, 256, 0, stream>>>(att_w, GAP, SC, L.Ci);
    packw1_kernel<<<L.Ci, 256, 0, stream>>>(fsm_w, BPB, L.Ci);
    conv1x1_mfma_kernel<true, float><<<dim3(HW / 32, 2), 256, 0, stream>>>(
        L.featl, SC, nullptr, 0.f, L.Ci, 0, HW, BPB, nullptr,
        nullptr, ARM, 256);
    // 3) off_feat = conv1x1(concat(ARM, 2*UPn)) -> FB (NHWC)
    packw1_kernel<<<512, 256, 0, stream>>>(off_w, BPB, 512);
    conv1x1_mfma_kernel<false, bf16><<<dim3(HW / 32, 2), 256, 0, stream>>>(
        ARM, nullptr, UPn, 2.f, 256, 256, HW, BPB, nullptr,
        nullptr, FB, 256);
    // 4) om = conv3x3(FB) + om_b -> OM (NHWC stride 216, in p2 region)
    packw3_kernel<<<2304, 256, 0, stream>>>(om_w, BPB, 256, 216);
    if (li == 2)
      conv3x3v2_kernel<2><<<dim3(HW / 64, 2), 256, 0, stream>>>(
          FB, BPB, om_b, L.H, L.W, 216, nullptr, OM, 216);
    else
      conv3x3v2_kernel<1><<<dim3(HW / 32, 2), 256, 0, stream>>>(
          FB, BPB, om_b, L.H, L.W, 216, nullptr, OM, 216);
    // 5) F = relu(mdcn(UPn, OM) + dcn_b) + ARM -> FB (NHWC)
    packwd_kernel<<<2304, 256, 0, stream>>>(dcn_w, BPB);
    mdcn_mfma_kernel<<<HW / 32, 512, 0, stream>>>(
        UPn, OM, BPB, dcn_b, ARM, FB, L.H, L.W, L.wshift);
    // 6) p = conv3x3(F) + out_b -> fp32 NCHW output
    packw3_kernel<<<2304, 256, 0, stream>>>(out_w, BPB, 256, 256);
    if (li == 2)
      conv3x3v2_kernel<2><<<dim3(HW / 64, 2), 256, 0, stream>>>(
          FB, BPB, out_b, L.H, L.W, 256, L.pdst, nullptr, 256);
    else
      conv3x3v2_kernel<1><<<dim3(HW / 32, 2), 256, 0, stream>>>(
          FB, BPB, out_b, L.H, L.W, 256, L.pdst, nullptr, 256);
  }
}

// Round 8
// 696.408 us; speedup vs baseline: 1.1959x; 1.0392x over previous
//
#include <hip/hip_runtime.h>
#include <hip/hip_bf16.h>

typedef __hip_bfloat16 bf16;
typedef __attribute__((ext_vector_type(8))) short bf16x8;
typedef __attribute__((ext_vector_type(4))) float floatx4;

__device__ __forceinline__ float b2f(bf16 v) { return __bfloat162float(v); }
__device__ __forceinline__ bf16 f2b(float v) { return __float2bfloat16(v); }
__device__ __forceinline__ float us2f(unsigned short u) {
  union { unsigned int i; float f; } v; v.i = ((unsigned int)u) << 16; return v.f;
}
__device__ __forceinline__ unsigned short f2us(float f) {
  bf16 h = f2b(f); return *(unsigned short*)&h;
}

// ---------------- global average pool: x (C,HW) fp32 NCHW -> gap[C] ------
__global__ __launch_bounds__(256) void gap_kernel(const float* __restrict__ x,
                                                  float* __restrict__ gap,
                                                  int HW, float inv) {
  int c = blockIdx.x;
  const float* p = x + (size_t)c * HW;
  float s = 0.f;
  for (int i = threadIdx.x; i < HW; i += 256) s += p[i];
  __shared__ float red[256];
  red[threadIdx.x] = s;
  __syncthreads();
  for (int w = 128; w > 0; w >>= 1) {
    if (threadIdx.x < w) red[threadIdx.x] += red[threadIdx.x + w];
    __syncthreads();
  }
  if (threadIdx.x == 0) gap[c] = red[0] * inv;
}

// -------- scale[o] = 1 + sigmoid( sum_i att_w[o,i] * gap[i] ) ------------
__global__ __launch_bounds__(256) void atten_kernel(const float* __restrict__ w,
                                                    const float* __restrict__ gap,
                                                    float* __restrict__ scale, int Ci) {
  int wave = threadIdx.x >> 6, lane = threadIdx.x & 63;
  int o = blockIdx.x * 4 + wave;
  const float4* wr = (const float4*)(w + (size_t)o * Ci);
  const float4* g4 = (const float4*)gap;
  int n4 = Ci >> 2;
  float s = 0.f;
  for (int i = lane; i < n4; i += 64) {
    float4 a = wr[i], b = g4[i];
    s += a.x * b.x + a.y * b.y + a.z * b.z + a.w * b.w;
  }
#pragma unroll
  for (int off = 32; off > 0; off >>= 1) s += __shfl_down(s, off);
  if (lane == 0) scale[o] = 1.f + 1.f / (1.f + expf(-s));
}

// ---- bilinear 2x upsample NHWC(256) -> NHWC(256), half-pixel, clamp -----
__global__ __launch_bounds__(256) void upsample2x_nhwc_kernel(
    const bf16* __restrict__ src, bf16* __restrict__ dst, int Hs, int Ws) {
  int p = blockIdx.x;       // output pixel
  int c = threadIdx.x;      // channel
  int W = Ws * 2;
  int y = p / W, x = p - y * W;
  float fy = y * 0.5f - 0.25f;
  float fx = x * 0.5f - 0.25f;
  int y0 = (int)floorf(fy), x0 = (int)floorf(fx);
  float wy1 = fy - (float)y0, wx1 = fx - (float)x0;
  int y0c = min(max(y0, 0), Hs - 1);
  int y1c = min(max(y0 + 1, 0), Hs - 1);
  int x0c = min(max(x0, 0), Ws - 1);
  int x1c = min(max(x0 + 1, 0), Ws - 1);
  float v00 = b2f(src[(size_t)(y0c * Ws + x0c) * 256 + c]);
  float v01 = b2f(src[(size_t)(y0c * Ws + x1c) * 256 + c]);
  float v10 = b2f(src[(size_t)(y1c * Ws + x0c) * 256 + c]);
  float v11 = b2f(src[(size_t)(y1c * Ws + x1c) * 256 + c]);
  float v = (1.f - wy1) * ((1.f - wx1) * v00 + wx1 * v01)
          + wy1 * ((1.f - wx1) * v10 + wx1 * v11);
  dst[(size_t)p * 256 + c] = f2b(v);
}

// ------- pack GEMM weights (fp32 [256][K]) -> bf16 MFMA-B layout ---------
// BP[((k>>3)*256 + o)*8 + (k&7)] = w[o*K + k].  grid = K blocks.
__global__ __launch_bounds__(256) void packw1_kernel(const float* __restrict__ w,
                                                     bf16* __restrict__ BP, int K) {
  int idx = blockIdx.x * 256 + threadIdx.x;
  int j = idx & 7;
  int o = (idx >> 3) & 255;
  int kc8 = idx >> 11;
  int k = kc8 * 8 + j;
  BP[idx] = f2b(w[(size_t)o * K + k]);
}

// ---- fused per-level pack: fsm(w1) + off(w1) + om(w3) + dcn(wd) + out(w3)
// grid = Ci + 512 + 3*2304 blocks, block-range dispatch.
__global__ __launch_bounds__(256) void pack_level_kernel(
    const float* __restrict__ fsm_w, int Ci,
    const float* __restrict__ off_w, const float* __restrict__ om_w,
    const float* __restrict__ dcn_w, const float* __restrict__ out_w,
    bf16* __restrict__ BPfsm, bf16* __restrict__ BPoff, bf16* __restrict__ BPom,
    bf16* __restrict__ BPdcn, bf16* __restrict__ BPout) {
  int b = blockIdx.x;
  if (b < Ci) {                       // fsm: packw1, K=Ci
    int idx = b * 256 + threadIdx.x;
    int j = idx & 7, o = (idx >> 3) & 255, k = (idx >> 11) * 8 + j;
    BPfsm[idx] = f2b(fsm_w[(size_t)o * Ci + k]);
    return;
  }
  b -= Ci;
  if (b < 512) {                      // off: packw1, K=512
    int idx = b * 256 + threadIdx.x;
    int j = idx & 7, o = (idx >> 3) & 255, k = (idx >> 11) * 8 + j;
    BPoff[idx] = f2b(off_w[(size_t)o * 512 + k]);
    return;
  }
  b -= 512;
  const float* w;
  bf16* BP;
  int Co;
  if (b < 2304) { w = om_w; BP = BPom; Co = 216; }
  else if (b < 4608) {                // dcn: tap-major packwd
    int idx = (b - 2304) * 256 + threadIdx.x;
    int j = idx & 7, o = (idx >> 3) & 255;
    int k = (idx >> 11) * 8 + j;      // 0..2303 tap-major
    int tap = k >> 8, ci = k & 255;
    BPdcn[idx] = f2b(dcn_w[((size_t)o * 256 + ci) * 9 + tap]);
    return;
  } else { w = out_w; BP = BPout; Co = 256; b -= 2304; }
  // packw3 body (Ci=256)
  int idx = (b % 2304) * 256 + threadIdx.x;
  int j = idx & 7;
  int t1 = idx >> 3;
  int o = t1 & 255;
  int t2 = t1 >> 8;
  int q = t2 & 3;
  int t3 = t2 >> 2;
  int tap = t3 % 9;
  int c = t3 / 9;
  int ci = c * 32 + q * 8 + j;
  float v = (o < Co) ? w[((size_t)o * 256 + ci) * 9 + tap] : 0.f;
  BP[idx] = f2b(v);
}

// ------------- 1x1 conv as MFMA GEMM -------------------------------------
template <bool NCHW1, typename TA1>
__global__ __launch_bounds__(256) void conv1x1_mfma_kernel(
    const TA1* __restrict__ A1, const float* __restrict__ scaleA,
    const bf16* __restrict__ A2, float scaleB,
    int Ci1, int Ci2, int HW,
    const bf16* __restrict__ BP, const float* __restrict__ bias,
    float* __restrict__ out1, bf16* __restrict__ out2, int ns2) {
  __shared__ __align__(16) bf16 sA[1024];   // [4 q][32 px][8]
  int p0 = blockIdx.x * 32;
  int tid = threadIdx.x;
  int pix = tid & 31, sub = tid >> 5;       // fp32-NCHW staging mapping
  int pix2 = tid >> 3, sub8 = tid & 7;      // NHWC staging mapping
  int lane = tid & 63, wave = tid >> 6;
  int pg = wave & 1, cg = wave >> 1;
  int q = lane >> 4, n = lane & 15;

  floatx4 acc[4];
#pragma unroll
  for (int nt = 0; nt < 4; ++nt) acc[nt] = (floatx4)0.f;

  int nch = (Ci1 + Ci2) >> 5;
  for (int kc = 0; kc < nch; ++kc) {
    int ci0 = kc << 5;
    if (NCHW1 && ci0 < Ci1) {
#pragma unroll
      for (int it = 0; it < 4; ++it) {
        int cil = it * 8 + sub;
        float x = (float)A1[(size_t)(ci0 + cil) * HW + p0 + pix];
        if (scaleA) x *= scaleA[ci0 + cil];
        sA[((cil >> 3) * 32 + pix) * 8 + (cil & 7)] = f2b(x);
      }
    } else {
      const bf16* src; int cb; bool scl;
      if (!NCHW1 && ci0 < Ci1) {
        src = (const bf16*)(const void*)A1; cb = ci0; scl = false;
      } else {
        src = A2; cb = ci0 - Ci1; scl = true;
      }
      ushort4 raw = *(const ushort4*)&src[(size_t)(p0 + pix2) * 256 + cb + sub8 * 4];
      if (scl) {
        raw.x = f2us(us2f(raw.x) * scaleB);
        raw.y = f2us(us2f(raw.y) * scaleB);
        raw.z = f2us(us2f(raw.z) * scaleB);
        raw.w = f2us(us2f(raw.w) * scaleB);
      }
      *(ushort4*)&sA[((sub8 >> 1) * 32 + pix2) * 8 + (sub8 & 1) * 4] = raw;
    }
    __syncthreads();
    bf16x8 a = *(const bf16x8*)&sA[(q * 32 + pg * 16 + n) * 8];
    const bf16* bp = BP + ((size_t)(kc * 4 + q) * 256 + blockIdx.y * 128 + cg * 64) * 8;
#pragma unroll
    for (int nt = 0; nt < 4; ++nt) {
      bf16x8 b = *(const bf16x8*)&bp[(nt * 16 + n) * 8];
      acc[nt] = __builtin_amdgcn_mfma_f32_16x16x32_bf16(a, b, acc[nt], 0, 0, 0);
    }
    __syncthreads();
  }

  int pbase = p0 + pg * 16 + q * 4;
#pragma unroll
  for (int nt = 0; nt < 4; ++nt) {
    int o = blockIdx.y * 128 + cg * 64 + nt * 16 + n;
    float bv = bias ? bias[o] : 0.f;
#pragma unroll
    for (int r = 0; r < 4; ++r) {
      float v = acc[nt][r] + bv;
      if (out1) out1[(size_t)o * HW + pbase + r] = v;
      if (out2) out2[(size_t)(pbase + r) * ns2 + o] = f2b(v);
    }
  }
}

// ---- K-split partial 1x1 conv (NCHW fp32 in), for tiny-HW huge-K (p5) ---
__global__ __launch_bounds__(256) void conv1x1_part_kernel(
    const float* __restrict__ A1, int HW,
    const bf16* __restrict__ BP, float* __restrict__ PART) {
  __shared__ __align__(16) bf16 sA[1024];   // [4 q][32 px][8]
  int p0 = blockIdx.x * 32;
  int tid = threadIdx.x;
  int pix = tid & 31, sub = tid >> 5;
  int lane = tid & 63, wave = tid >> 6;
  int pg = wave & 1, cg = wave >> 1;
  int q = lane >> 4, n = lane & 15;

  floatx4 acc[4];
#pragma unroll
  for (int nt = 0; nt < 4; ++nt) acc[nt] = (floatx4)0.f;

  int kc0 = blockIdx.z * 8;
  for (int kcl = 0; kcl < 8; ++kcl) {
    int kc = kc0 + kcl;
    int ci0 = kc << 5;
#pragma unroll
    for (int it = 0; it < 4; ++it) {
      int cil = it * 8 + sub;
      sA[((cil >> 3) * 32 + pix) * 8 + (cil & 7)] =
          f2b(A1[(size_t)(ci0 + cil) * HW + p0 + pix]);
    }
    __syncthreads();
    bf16x8 a = *(const bf16x8*)&sA[(q * 32 + pg * 16 + n) * 8];
    const bf16* bp = BP + ((size_t)(kc * 4 + q) * 256 + blockIdx.y * 128 + cg * 64) * 8;
#pragma unroll
    for (int nt = 0; nt < 4; ++nt) {
      bf16x8 b = *(const bf16x8*)&bp[(nt * 16 + n) * 8];
      acc[nt] = __builtin_amdgcn_mfma_f32_16x16x32_bf16(a, b, acc[nt], 0, 0, 0);
    }
    __syncthreads();
  }

  int pbase = p0 + pg * 16 + q * 4;
#pragma unroll
  for (int nt = 0; nt < 4; ++nt) {
    int o = blockIdx.y * 128 + cg * 64 + nt * 16 + n;
#pragma unroll
    for (int r = 0; r < 4; ++r)
      PART[((size_t)blockIdx.z * 256 + o) * HW + pbase + r] = acc[nt][r];
  }
}

// ---- reduce K-split partials + bias -> fp32 NCHW + bf16 NHWC ------------
__global__ __launch_bounds__(256) void reduce_p5_kernel(
    const float* __restrict__ PART, const float* __restrict__ bias,
    float* __restrict__ out1, bf16* __restrict__ out2, int HW, int KS) {
  int o = blockIdx.x;
  int p = threadIdx.x;
  float s = bias[o];
  for (int z = 0; z < KS; ++z) s += PART[((size_t)z * 256 + o) * HW + p];
  out1[(size_t)o * HW + p] = s;
  out2[(size_t)p * 256 + o] = f2b(s);
}

// ------- 3x3 conv v2: row-window staging + reg-prefetch pipeline ---------
template <int S>
__global__ __launch_bounds__(256) void conv3x3v2_kernel(
    const bf16* __restrict__ in, const bf16* __restrict__ BP,
    const float* __restrict__ bias,
    int H, int W, int Co,
    float* __restrict__ out1, bf16* __restrict__ out2, int ns2) {
  constexpr int P = 32 * S + 2;
  constexpr int TASKS = 3 * P * 8;            // ushort4 stage tasks per kc
  constexpr int ITS = (TASKS + 255) / 256;
  __shared__ __align__(16) bf16 sA[2][4 * 3 * P * 8];
  int HW = H * W;
  int segs = W / (32 * S);
  int y = blockIdx.x / segs;
  int x0 = (blockIdx.x - y * segs) * (32 * S);
  int tid = threadIdx.x;
  int lane = tid & 63, wave = tid >> 6;
  int pg = wave & 1, cg = wave >> 1;
  int q = lane >> 4, n = lane & 15;

  // --- precompute per-thread staging tasks (kc-invariant) ---
  int dstIdx[ITS], srcOff[ITS];
  bool act[ITS], val[ITS];
#pragma unroll
  for (int it = 0; it < ITS; ++it) {
    int tt = it * 256 + tid;
    act[it] = (tt < TASKS);
    int sub8 = tt & 7;
    int rp = tt >> 3;
    int row = rp / P;
    int pxl = rp - row * P;
    int yy = y + row - 1;
    int xg = x0 + pxl - 1;
    bool v = act[it] && ((unsigned)yy < (unsigned)H) && ((unsigned)xg < (unsigned)W);
    val[it] = v;
    srcOff[it] = v ? ((yy * W + xg) * 256 + sub8 * 4) : 0;
    dstIdx[it] = (((sub8 >> 1) * 3 + row) * P + pxl) * 8 + (sub8 & 1) * 4;
  }

  ushort4 pv[ITS];
  auto load_regs = [&](int kc) {
    int cb = kc << 5;
#pragma unroll
    for (int it = 0; it < ITS; ++it) {
      ushort4 z = {0, 0, 0, 0};
      pv[it] = val[it] ? *(const ushort4*)&in[(size_t)srcOff[it] + cb] : z;
    }
  };
  auto store_lds = [&](int buf) {
#pragma unroll
    for (int it = 0; it < ITS; ++it)
      if (act[it]) *(ushort4*)&sA[buf][dstIdx[it]] = pv[it];
  };

  floatx4 acc[S][4];
#pragma unroll
  for (int s = 0; s < S; ++s)
#pragma unroll
    for (int nt = 0; nt < 4; ++nt) acc[s][nt] = (floatx4)0.f;

  load_regs(0);
  store_lds(0);
  __syncthreads();
  load_regs(1);

  for (int kc = 0; kc < 8; ++kc) {
    const bf16* sv = &sA[kc & 1][0];
    const bf16* bpc = BP + (size_t)kc * 73728;   // kc*9*4*256*8
#pragma unroll
    for (int tap = 0; tap < 9; ++tap) {
      int ty = tap / 3, tx = tap % 3;            // row = dy+1, xoff = dx+1
      bf16x8 a[S];
#pragma unroll
      for (int s = 0; s < S; ++s)
        a[s] = *(const bf16x8*)&sv[((q * 3 + ty) * P + tx + s * 32 + pg * 16 + n) * 8];
      const bf16* bp = bpc + ((size_t)(tap * 4 + q) * 256 + blockIdx.y * 128 + cg * 64) * 8;
#pragma unroll
      for (int nt = 0; nt < 4; ++nt) {
        bf16x8 b = *(const bf16x8*)&bp[(nt * 16 + n) * 8];
#pragma unroll
        for (int s = 0; s < S; ++s)
          acc[s][nt] = __builtin_amdgcn_mfma_f32_16x16x32_bf16(a[s], b, acc[s][nt], 0, 0, 0);
      }
    }
    if (kc < 7) {
      store_lds((kc + 1) & 1);     // target buf last read at kc-1 (fenced)
      __syncthreads();             // publish for mfma(kc+1)
      if (kc < 6) load_regs(kc + 2);
    }
  }

#pragma unroll
  for (int s = 0; s < S; ++s) {
    int pbase = y * W + x0 + s * 32 + pg * 16 + q * 4;
#pragma unroll
    for (int nt = 0; nt < 4; ++nt) {
      int o = blockIdx.y * 128 + cg * 64 + nt * 16 + n;
      if (o < Co) {
        float bv = bias ? bias[o] : 0.f;
#pragma unroll
        for (int r = 0; r < 4; ++r) {
          float v = acc[s][nt][r] + bv;
          if (out1) out1[(size_t)o * HW + pbase + r] = v;
          if (out2) out2[(size_t)(pbase + r) * ns2 + o] = f2b(v);
        }
      }
    }
  }
}

// ---- mdcn v3c: v3b + T14 async split (load-early / bilinear+store-late) --
// Identical meta/layout/numerics to v3b. Per tap: issue 16 ushort4 loads
// right after the barrier, run MFMA(t) (hides load latency), then bilinear
// + LDS store for tap t+1.
__global__ __launch_bounds__(512, 4) void mdcn_mfma_kernel(
    const bf16* __restrict__ UPn, const bf16* __restrict__ OM,
    const bf16* __restrict__ BP, const float* __restrict__ dcn_b,
    const bf16* __restrict__ ARM, bf16* __restrict__ F,
    int H, int W, int wshift) {
  // sval row: [32 px][8 ch] = 256 bf16 + 16 pad = 272 (stride 544 B)
  __shared__ __align__(16) bf16 sval[2][32 * 272];   // 34,816 B
  __shared__ float4 mw[2304];                        // 36,864 B
  __shared__ int mi[2304];                           //  9,216 B
  int pb = blockIdx.x * 32;
  int tid = threadIdx.x;

  // ---- meta for all 9 taps: 2304 tasks = tap*256 + g*32 + px ----
  for (int t2 = tid; t2 < 2304; t2 += 512) {
    int px_ = t2 & 31, g = (t2 >> 5) & 7, tap = t2 >> 8;
    int ky = tap / 3, kx = tap - ky * 3;
    int p = pb + px_;
    int y = p >> wshift, x = p & (W - 1);
    const bf16* omp = OM + (size_t)p * 216;
    float dy = b2f(omp[g * 18 + tap]);
    float dx = b2f(omp[g * 18 + 9 + tap]);
    float mm = 1.f / (1.f + expf(-b2f(omp[144 + g * 9 + tap])));
    float fpy = (float)(y - 1 + ky) + dy;
    float fpx = (float)(x - 1 + kx) + dx;
    fpy = fminf(fmaxf(fpy, -1.0e4f), 1.0e4f);
    fpx = fminf(fmaxf(fpx, -1.0e4f), 1.0e4f);
    float fy0 = floorf(fpy), fx0 = floorf(fpx);
    float wy1 = fpy - fy0, wx1 = fpx - fx0;
    float wy0 = 1.f - wy1, wx0 = 1.f - wx1;
    int iy0 = (int)fy0, ix0 = (int)fx0;
    bool vy0 = (unsigned)iy0 < (unsigned)H;
    bool vy1 = (unsigned)(iy0 + 1) < (unsigned)H;
    bool vx0 = (unsigned)ix0 < (unsigned)W;
    bool vx1 = (unsigned)(ix0 + 1) < (unsigned)W;
    float w00 = (vy0 && vx0) ? mm * wy0 * wx0 : 0.f;
    float w01 = (vy0 && vx1) ? mm * wy0 * wx1 : 0.f;
    float w10 = (vy1 && vx0) ? mm * wy1 * wx0 : 0.f;
    float w11 = (vy1 && vx1) ? mm * wy1 * wx1 : 0.f;
    int iy0c = min(max(iy0, 0), H - 1);
    int iy1c = min(max(iy0 + 1, 0), H - 1);
    int ix0c = min(max(ix0, 0), W - 1);
    int ix1c = min(max(ix0 + 1, 0), W - 1);
    mw[t2] = make_float4(w00, w01, w10, w11);
    mi[t2] = (iy0c * W + ix0c) | ((ix1c - ix0c) << 20) | ((iy1c - iy0c) << 21);
  }
  __syncthreads();

  int l4 = tid & 7;                   // channel quad within a 32-ch group
  int px = (tid >> 3) & 31;           // pixel
  int gh = tid >> 8;                  // group half: g = gh*4 .. gh*4+3
  int lane = tid & 63, wave = tid >> 6;
  int q = lane >> 4, n = lane & 15;
  int rowb = l4 >> 1;                 // sub-row within group's 4 rows
  int woff = px * 8 + (l4 & 1) * 4;   // bf16-elem offset within sval row

  floatx4 acc[2][2];
#pragma unroll
  for (int m = 0; m < 2; ++m)
#pragma unroll
    for (int nt = 0; nt < 2; ++nt) acc[m][nt] = (floatx4)0.f;

  ushort4 gl[4][4];                   // in-flight neighbor loads [gg][nbr]
  auto gatherLoad = [&](int t) {
    int base = t * 256 + px + gh * 128;
#pragma unroll
    for (int gg = 0; gg < 4; ++gg) {
      int g = gh * 4 + gg;
      int mv = mi[base + gg * 32];
      int idx = mv & 0x3FFFF;
      int dxs = (mv >> 20) & 1;
      int dyW = ((mv >> 21) & 1) * W;
      const bf16* up = UPn + (size_t)idx * 256 + g * 32 + l4 * 4;
      gl[gg][0] = *(const ushort4*)(up);
      gl[gg][1] = *(const ushort4*)(up + dxs * 256);
      gl[gg][2] = *(const ushort4*)(up + dyW * 256);
      gl[gg][3] = *(const ushort4*)(up + (dyW + dxs) * 256);
    }
  };
  auto gatherStore = [&](int t) {
    bf16* sv = &sval[t & 1][0];
    int base = t * 256 + px + gh * 128;
#pragma unroll
    for (int gg = 0; gg < 4; ++gg) {
      int g = gh * 4 + gg;
      float4 wv = mw[base + gg * 32];
      ushort4 u00 = gl[gg][0], u01 = gl[gg][1], u10 = gl[gg][2], u11 = gl[gg][3];
      ushort4 o4;
      o4.x = f2us(wv.x * us2f(u00.x) + wv.y * us2f(u01.x)
                + wv.z * us2f(u10.x) + wv.w * us2f(u11.x));
      o4.y = f2us(wv.x * us2f(u00.y) + wv.y * us2f(u01.y)
                + wv.z * us2f(u10.y) + wv.w * us2f(u11.y));
      o4.z = f2us(wv.x * us2f(u00.z) + wv.y * us2f(u01.z)
                + wv.z * us2f(u10.z) + wv.w * us2f(u11.z));
      o4.w = f2us(wv.x * us2f(u00.w) + wv.y * us2f(u01.w)
                + wv.z * us2f(u10.w) + wv.w * us2f(u11.w));
      *(ushort4*)&sv[(g * 4 + rowb) * 272 + woff] = o4;
    }
  };

  gatherLoad(0);
  gatherStore(0);
  for (int t = 0; t < 9; ++t) {
    __syncthreads();                 // publish sval[t&1]; other buf free
    if (t < 8) gatherLoad(t + 1);    // issue VMEM early (T14)
    const bf16* sv = &sval[t & 1][0];
    const bf16* bpt = BP + ((size_t)(t * 32) * 256 + wave * 32) * 8;
#pragma unroll
    for (int kc = 0; kc < 8; ++kc) {
      int R = kc * 4 + q;
      bf16x8 a0 = *(const bf16x8*)&sv[R * 272 + n * 8];
      bf16x8 a1 = *(const bf16x8*)&sv[R * 272 + (16 + n) * 8];
      const bf16* bp = bpt + (size_t)R * 2048;   // R*256*8
      bf16x8 b0 = *(const bf16x8*)&bp[n * 8];
      bf16x8 b1 = *(const bf16x8*)&bp[(16 + n) * 8];
      acc[0][0] = __builtin_amdgcn_mfma_f32_16x16x32_bf16(a0, b0, acc[0][0], 0, 0, 0);
      acc[0][1] = __builtin_amdgcn_mfma_f32_16x16x32_bf16(a0, b1, acc[0][1], 0, 0, 0);
      acc[1][0] = __builtin_amdgcn_mfma_f32_16x16x32_bf16(a1, b0, acc[1][0], 0, 0, 0);
      acc[1][1] = __builtin_amdgcn_mfma_f32_16x16x32_bf16(a1, b1, acc[1][1], 0, 0, 0);
    }
    if (t < 8) gatherStore(t + 1);   // bilinear + LDS write after MFMA
  }

#pragma unroll
  for (int m = 0; m < 2; ++m) {
#pragma unroll
    for (int nt = 0; nt < 2; ++nt) {
      int o = wave * 32 + nt * 16 + n;
      float bv = dcn_b[o];
#pragma unroll
      for (int r = 0; r < 4; ++r) {
        int p = pb + m * 16 + q * 4 + r;
        float v = fmaxf(acc[m][nt][r] + bv, 0.f) + b2f(ARM[(size_t)p * 256 + o]);
        F[(size_t)p * 256 + o] = f2b(v);
      }
    }
  }
}

extern "C" void kernel_launch(void* const* d_in, const int* in_sizes, int n_in,
                              void* d_out, int out_size, void* d_ws, size_t ws_size,
                              hipStream_t stream) {
  // Inputs fp32, outputs fp32 (established rounds 3-5). Interior: bf16 NHWC.
  const float* c2 = (const float*)d_in[0];
  const float* c3 = (const float*)d_in[1];
  const float* c4 = (const float*)d_in[2];
  const float* c5 = (const float*)d_in[3];
  const float* lat_w = (const float*)d_in[31];
  const float* lat_b = (const float*)d_in[32];
  float* out = (float*)d_out;
  (void)ws_size; (void)in_sizes; (void)n_in; (void)out_size;

  const size_t p2_off = 0;
  const size_t p3_off = 4194304;
  const size_t p4_off = p3_off + 1048576;
  const size_t p5_off = p4_off + 262144;

  // ---- ws layout (~27.3MB; ws_size >= 28MB proven round 3) ----
  char* ws = (char*)d_ws;
  bf16* UPn = (bf16*)(ws);                    // 8MB NHWC
  bf16* ARM = (bf16*)(ws + 8388608);          // 8MB NHWC
  bf16* FB  = (bf16*)(ws + 16777216);         // 8MB NHWC (off_feat & F alias)
  bf16* P5N = (bf16*)(ws + 25165824);         // 128KB NHWC p5 copy
  bf16* BPout = (bf16*)(ws + 25296896);       // 1.125MB (also hosts p5 lat pack)
  bf16* BPfsm = (bf16*)(ws + 26476544);       // 512KB
  bf16* BPoff = (bf16*)(ws + 27000832);       // 256KB
  float* GAP = (float*)(ws + 27262976);
  float* SC  = (float*)(ws + 27271168);
  // p2 output region (16.8MB) scratch: OM at +0 (6.75MB max), BPom at
  // +10MiB, BPdcn at +10MiB+1.125MB. All consumed before the final conv
  // (L2 step 6) overwrites p2.
  bf16* OM = (bf16*)(out + p2_off);
  bf16* BPom = (bf16*)((char*)(out + p2_off) + 10485760);
  bf16* BPdcn = (bf16*)((char*)(out + p2_off) + 11665408);
  // p5 K-split partials (2MB) borrow the UPn region.
  float* PART = (float*)ws;

  // ---- p5 = conv1x1(c5, lat_w, lat_b), K-split x8 + reduce --------------
  packw1_kernel<<<2048, 256, 0, stream>>>(lat_w, BPout, 2048);
  conv1x1_part_kernel<<<dim3(8, 2, 8), 256, 0, stream>>>(c5, 256, BPout, PART);
  reduce_p5_kernel<<<256, 256, 0, stream>>>(PART, lat_b, out + p5_off, P5N, 256, 8);

  struct Lv {
    const float* featl; int Ci; int H; int W; int wshift;
    float* pdst; int wbase;
  };
  Lv levels[3] = {
      {c4, 1024, 32, 32, 5, out + p4_off, 4},
      {c3, 512, 64, 64, 6, out + p3_off, 13},
      {c2, 256, 128, 128, 7, out + p2_off, 22},
  };

  for (int li = 0; li < 3; ++li) {
    const Lv& L = levels[li];
    const float* att_w = (const float*)d_in[L.wbase + 0];
    const float* fsm_w = (const float*)d_in[L.wbase + 1];
    const float* off_w = (const float*)d_in[L.wbase + 2];
    const float* om_w  = (const float*)d_in[L.wbase + 3];
    const float* om_b  = (const float*)d_in[L.wbase + 4];
    const float* dcn_w = (const float*)d_in[L.wbase + 5];
    const float* dcn_b = (const float*)d_in[L.wbase + 6];
    const float* out_w = (const float*)d_in[L.wbase + 7];
    const float* out_b = (const float*)d_in[L.wbase + 8];
    int HW = L.H * L.W;

    // 0) fused pack of all 5 weight tensors for this level (1 launch)
    pack_level_kernel<<<L.Ci + 512 + 3 * 2304, 256, 0, stream>>>(
        fsm_w, L.Ci, off_w, om_w, dcn_w, out_w,
        BPfsm, BPoff, BPom, BPdcn, BPout);
    // 1) feat_up = bilinear 2x (NHWC -> NHWC): src = P5N or previous F(FB)
    upsample2x_nhwc_kernel<<<HW, 256, 0, stream>>>(
        (li == 0) ? P5N : FB, UPn, L.H / 2, L.W / 2);
    // 2) FSM: gap -> atten -> scaled 1x1 GEMM -> ARM (NHWC)
    gap_kernel<<<L.Ci, 256, 0, stream>>>(L.featl, GAP, HW, 1.f / (float)HW);
    atten_kernel<<<L.Ci / 4, 256, 0, stream>>>(att_w, GAP, SC, L.Ci);
    conv1x1_mfma_kernel<true, float><<<dim3(HW / 32, 2), 256, 0, stream>>>(
        L.featl, SC, nullptr, 0.f, L.Ci, 0, HW, BPfsm, nullptr,
        nullptr, ARM, 256);
    // 3) off_feat = conv1x1(concat(ARM, 2*UPn)) -> FB (NHWC)
    conv1x1_mfma_kernel<false, bf16><<<dim3(HW / 32, 2), 256, 0, stream>>>(
        ARM, nullptr, UPn, 2.f, 256, 256, HW, BPoff, nullptr,
        nullptr, FB, 256);
    // 4) om = conv3x3(FB) + om_b -> OM (NHWC stride 216, in p2 region)
    if (li == 2)
      conv3x3v2_kernel<2><<<dim3(HW / 64, 2), 256, 0, stream>>>(
          FB, BPom, om_b, L.H, L.W, 216, nullptr, OM, 216);
    else
      conv3x3v2_kernel<1><<<dim3(HW / 32, 2), 256, 0, stream>>>(
          FB, BPom, om_b, L.H, L.W, 216, nullptr, OM, 216);
    // 5) F = relu(mdcn(UPn, OM) + dcn_b) + ARM -> FB (NHWC)
    mdcn_mfma_kernel<<<HW / 32, 512, 0, stream>>>(
        UPn, OM, BPdcn, dcn_b, ARM, FB, L.H, L.W, L.wshift);
    // 6) p = conv3x3(F) + out_b -> fp32 NCHW output
    if (li == 2)
      conv3x3v2_kernel<2><<<dim3(HW / 64, 2), 256, 0, stream>>>(
          FB, BPout, out_b, L.H, L.W, 256, L.pdst, nullptr, 256);
    else
      conv3x3v2_kernel<1><<<dim3(HW / 32, 2), 256, 0, stream>>>(
          FB, BPout, out_b, L.H, L.W, 256, L.pdst, nullptr, 256);
  }
}

// Round 9
// 694.740 us; speedup vs baseline: 1.1987x; 1.0024x over previous
//
#include <hip/hip_runtime.h>
#include <hip/hip_bf16.h>

typedef __hip_bfloat16 bf16;
typedef __attribute__((ext_vector_type(8))) short bf16x8;
typedef __attribute__((ext_vector_type(4))) float floatx4;

__device__ __forceinline__ float b2f(bf16 v) { return __bfloat162float(v); }
__device__ __forceinline__ bf16 f2b(float v) { return __float2bfloat16(v); }
__device__ __forceinline__ float us2f(unsigned short u) {
  union { unsigned int i; float f; } v; v.i = ((unsigned int)u) << 16; return v.f;
}
__device__ __forceinline__ unsigned short f2us(float f) {
  bf16 h = f2b(f); return *(unsigned short*)&h;
}

// ---------------- global average pool: x (C,HW) fp32 NCHW -> gap[C] ------
__global__ __launch_bounds__(256) void gap_kernel(const float* __restrict__ x,
                                                  float* __restrict__ gap,
                                                  int HW, float inv) {
  int c = blockIdx.x;
  const float* p = x + (size_t)c * HW;
  float s = 0.f;
  for (int i = threadIdx.x; i < HW; i += 256) s += p[i];
  __shared__ float red[256];
  red[threadIdx.x] = s;
  __syncthreads();
  for (int w = 128; w > 0; w >>= 1) {
    if (threadIdx.x < w) red[threadIdx.x] += red[threadIdx.x + w];
    __syncthreads();
  }
  if (threadIdx.x == 0) gap[c] = red[0] * inv;
}

// -------- scale[o] = 1 + sigmoid( sum_i att_w[o,i] * gap[i] ) ------------
__global__ __launch_bounds__(256) void atten_kernel(const float* __restrict__ w,
                                                    const float* __restrict__ gap,
                                                    float* __restrict__ scale, int Ci) {
  int wave = threadIdx.x >> 6, lane = threadIdx.x & 63;
  int o = blockIdx.x * 4 + wave;
  const float4* wr = (const float4*)(w + (size_t)o * Ci);
  const float4* g4 = (const float4*)gap;
  int n4 = Ci >> 2;
  float s = 0.f;
  for (int i = lane; i < n4; i += 64) {
    float4 a = wr[i], b = g4[i];
    s += a.x * b.x + a.y * b.y + a.z * b.z + a.w * b.w;
  }
#pragma unroll
  for (int off = 32; off > 0; off >>= 1) s += __shfl_down(s, off);
  if (lane == 0) scale[o] = 1.f + 1.f / (1.f + expf(-s));
}

// ---- bilinear 2x upsample NHWC(256) -> NHWC(256), half-pixel, clamp -----
__global__ __launch_bounds__(256) void upsample2x_nhwc_kernel(
    const bf16* __restrict__ src, bf16* __restrict__ dst, int Hs, int Ws) {
  int p = blockIdx.x;       // output pixel
  int c = threadIdx.x;      // channel
  int W = Ws * 2;
  int y = p / W, x = p - y * W;
  float fy = y * 0.5f - 0.25f;
  float fx = x * 0.5f - 0.25f;
  int y0 = (int)floorf(fy), x0 = (int)floorf(fx);
  float wy1 = fy - (float)y0, wx1 = fx - (float)x0;
  int y0c = min(max(y0, 0), Hs - 1);
  int y1c = min(max(y0 + 1, 0), Hs - 1);
  int x0c = min(max(x0, 0), Ws - 1);
  int x1c = min(max(x0 + 1, 0), Ws - 1);
  float v00 = b2f(src[(size_t)(y0c * Ws + x0c) * 256 + c]);
  float v01 = b2f(src[(size_t)(y0c * Ws + x1c) * 256 + c]);
  float v10 = b2f(src[(size_t)(y1c * Ws + x0c) * 256 + c]);
  float v11 = b2f(src[(size_t)(y1c * Ws + x1c) * 256 + c]);
  float v = (1.f - wy1) * ((1.f - wx1) * v00 + wx1 * v01)
          + wy1 * ((1.f - wx1) * v10 + wx1 * v11);
  dst[(size_t)p * 256 + c] = f2b(v);
}

// ------- pack GEMM weights (fp32 [256][K]) -> bf16 MFMA-B layout ---------
__global__ __launch_bounds__(256) void packw1_kernel(const float* __restrict__ w,
                                                     bf16* __restrict__ BP, int K) {
  int idx = blockIdx.x * 256 + threadIdx.x;
  int j = idx & 7;
  int o = (idx >> 3) & 255;
  int kc8 = idx >> 11;
  int k = kc8 * 8 + j;
  BP[idx] = f2b(w[(size_t)o * K + k]);
}

// ---- fused per-level pack: fsm(w1) + off(w1) + om(w3) + dcn(wd) + out(w3)
__global__ __launch_bounds__(256) void pack_level_kernel(
    const float* __restrict__ fsm_w, int Ci,
    const float* __restrict__ off_w, const float* __restrict__ om_w,
    const float* __restrict__ dcn_w, const float* __restrict__ out_w,
    bf16* __restrict__ BPfsm, bf16* __restrict__ BPoff, bf16* __restrict__ BPom,
    bf16* __restrict__ BPdcn, bf16* __restrict__ BPout) {
  int b = blockIdx.x;
  if (b < Ci) {                       // fsm: packw1, K=Ci
    int idx = b * 256 + threadIdx.x;
    int j = idx & 7, o = (idx >> 3) & 255, k = (idx >> 11) * 8 + j;
    BPfsm[idx] = f2b(fsm_w[(size_t)o * Ci + k]);
    return;
  }
  b -= Ci;
  if (b < 512) {                      // off: packw1, K=512
    int idx = b * 256 + threadIdx.x;
    int j = idx & 7, o = (idx >> 3) & 255, k = (idx >> 11) * 8 + j;
    BPoff[idx] = f2b(off_w[(size_t)o * 512 + k]);
    return;
  }
  b -= 512;
  const float* w;
  bf16* BP;
  int Co;
  if (b < 2304) { w = om_w; BP = BPom; Co = 216; }
  else if (b < 4608) {                // dcn: tap-major packwd
    int idx = (b - 2304) * 256 + threadIdx.x;
    int j = idx & 7, o = (idx >> 3) & 255;
    int k = (idx >> 11) * 8 + j;      // 0..2303 tap-major
    int tap = k >> 8, ci = k & 255;
    BPdcn[idx] = f2b(dcn_w[((size_t)o * 256 + ci) * 9 + tap]);
    return;
  } else { w = out_w; BP = BPout; Co = 256; b -= 2304; }
  // packw3 body (Ci=256)
  int idx = (b % 2304) * 256 + threadIdx.x;
  int j = idx & 7;
  int t1 = idx >> 3;
  int o = t1 & 255;
  int t2 = t1 >> 8;
  int q = t2 & 3;
  int t3 = t2 >> 2;
  int tap = t3 % 9;
  int c = t3 / 9;
  int ci = c * 32 + q * 8 + j;
  float v = (o < Co) ? w[((size_t)o * 256 + ci) * 9 + tap] : 0.f;
  BP[idx] = f2b(v);
}

// ------------- 1x1 conv as MFMA GEMM -------------------------------------
template <bool NCHW1, typename TA1>
__global__ __launch_bounds__(256) void conv1x1_mfma_kernel(
    const TA1* __restrict__ A1, const float* __restrict__ scaleA,
    const bf16* __restrict__ A2, float scaleB,
    int Ci1, int Ci2, int HW,
    const bf16* __restrict__ BP, const float* __restrict__ bias,
    float* __restrict__ out1, bf16* __restrict__ out2, int ns2) {
  __shared__ __align__(16) bf16 sA[1024];   // [4 q][32 px][8]
  int p0 = blockIdx.x * 32;
  int tid = threadIdx.x;
  int pix = tid & 31, sub = tid >> 5;       // fp32-NCHW staging mapping
  int pix2 = tid >> 3, sub8 = tid & 7;      // NHWC staging mapping
  int lane = tid & 63, wave = tid >> 6;
  int pg = wave & 1, cg = wave >> 1;
  int q = lane >> 4, n = lane & 15;

  floatx4 acc[4];
#pragma unroll
  for (int nt = 0; nt < 4; ++nt) acc[nt] = (floatx4)0.f;

  int nch = (Ci1 + Ci2) >> 5;
  for (int kc = 0; kc < nch; ++kc) {
    int ci0 = kc << 5;
    if (NCHW1 && ci0 < Ci1) {
#pragma unroll
      for (int it = 0; it < 4; ++it) {
        int cil = it * 8 + sub;
        float x = (float)A1[(size_t)(ci0 + cil) * HW + p0 + pix];
        if (scaleA) x *= scaleA[ci0 + cil];
        sA[((cil >> 3) * 32 + pix) * 8 + (cil & 7)] = f2b(x);
      }
    } else {
      const bf16* src; int cb; bool scl;
      if (!NCHW1 && ci0 < Ci1) {
        src = (const bf16*)(const void*)A1; cb = ci0; scl = false;
      } else {
        src = A2; cb = ci0 - Ci1; scl = true;
      }
      ushort4 raw = *(const ushort4*)&src[(size_t)(p0 + pix2) * 256 + cb + sub8 * 4];
      if (scl) {
        raw.x = f2us(us2f(raw.x) * scaleB);
        raw.y = f2us(us2f(raw.y) * scaleB);
        raw.z = f2us(us2f(raw.z) * scaleB);
        raw.w = f2us(us2f(raw.w) * scaleB);
      }
      *(ushort4*)&sA[((sub8 >> 1) * 32 + pix2) * 8 + (sub8 & 1) * 4] = raw;
    }
    __syncthreads();
    bf16x8 a = *(const bf16x8*)&sA[(q * 32 + pg * 16 + n) * 8];
    const bf16* bp = BP + ((size_t)(kc * 4 + q) * 256 + blockIdx.y * 128 + cg * 64) * 8;
#pragma unroll
    for (int nt = 0; nt < 4; ++nt) {
      bf16x8 b = *(const bf16x8*)&bp[(nt * 16 + n) * 8];
      acc[nt] = __builtin_amdgcn_mfma_f32_16x16x32_bf16(a, b, acc[nt], 0, 0, 0);
    }
    __syncthreads();
  }

  int pbase = p0 + pg * 16 + q * 4;
#pragma unroll
  for (int nt = 0; nt < 4; ++nt) {
    int o = blockIdx.y * 128 + cg * 64 + nt * 16 + n;
    float bv = bias ? bias[o] : 0.f;
#pragma unroll
    for (int r = 0; r < 4; ++r) {
      float v = acc[nt][r] + bv;
      if (out1) out1[(size_t)o * HW + pbase + r] = v;
      if (out2) out2[(size_t)(pbase + r) * ns2 + o] = f2b(v);
    }
  }
}

// ---- K-split partial 1x1 conv (NCHW fp32 in), for tiny-HW huge-K (p5) ---
__global__ __launch_bounds__(256) void conv1x1_part_kernel(
    const float* __restrict__ A1, int HW,
    const bf16* __restrict__ BP, float* __restrict__ PART) {
  __shared__ __align__(16) bf16 sA[1024];   // [4 q][32 px][8]
  int p0 = blockIdx.x * 32;
  int tid = threadIdx.x;
  int pix = tid & 31, sub = tid >> 5;
  int lane = tid & 63, wave = tid >> 6;
  int pg = wave & 1, cg = wave >> 1;
  int q = lane >> 4, n = lane & 15;

  floatx4 acc[4];
#pragma unroll
  for (int nt = 0; nt < 4; ++nt) acc[nt] = (floatx4)0.f;

  int kc0 = blockIdx.z * 8;
  for (int kcl = 0; kcl < 8; ++kcl) {
    int kc = kc0 + kcl;
    int ci0 = kc << 5;
#pragma unroll
    for (int it = 0; it < 4; ++it) {
      int cil = it * 8 + sub;
      sA[((cil >> 3) * 32 + pix) * 8 + (cil & 7)] =
          f2b(A1[(size_t)(ci0 + cil) * HW + p0 + pix]);
    }
    __syncthreads();
    bf16x8 a = *(const bf16x8*)&sA[(q * 32 + pg * 16 + n) * 8];
    const bf16* bp = BP + ((size_t)(kc * 4 + q) * 256 + blockIdx.y * 128 + cg * 64) * 8;
#pragma unroll
    for (int nt = 0; nt < 4; ++nt) {
      bf16x8 b = *(const bf16x8*)&bp[(nt * 16 + n) * 8];
      acc[nt] = __builtin_amdgcn_mfma_f32_16x16x32_bf16(a, b, acc[nt], 0, 0, 0);
    }
    __syncthreads();
  }

  int pbase = p0 + pg * 16 + q * 4;
#pragma unroll
  for (int nt = 0; nt < 4; ++nt) {
    int o = blockIdx.y * 128 + cg * 64 + nt * 16 + n;
#pragma unroll
    for (int r = 0; r < 4; ++r)
      PART[((size_t)blockIdx.z * 256 + o) * HW + pbase + r] = acc[nt][r];
  }
}

// ---- reduce K-split partials + bias -> fp32 NCHW + bf16 NHWC ------------
__global__ __launch_bounds__(256) void reduce_p5_kernel(
    const float* __restrict__ PART, const float* __restrict__ bias,
    float* __restrict__ out1, bf16* __restrict__ out2, int HW, int KS) {
  int o = blockIdx.x;
  int p = threadIdx.x;
  float s = bias[o];
  for (int z = 0; z < KS; ++z) s += PART[((size_t)z * 256 + o) * HW + p];
  out1[(size_t)o * HW + p] = s;
  out2[(size_t)p * 256 + o] = f2b(s);
}

// ------- 3x3 conv v2: row-window staging + reg-prefetch pipeline ---------
template <int S>
__global__ __launch_bounds__(256) void conv3x3v2_kernel(
    const bf16* __restrict__ in, const bf16* __restrict__ BP,
    const float* __restrict__ bias,
    int H, int W, int Co,
    float* __restrict__ out1, bf16* __restrict__ out2, int ns2) {
  constexpr int P = 32 * S + 2;
  constexpr int TASKS = 3 * P * 8;            // ushort4 stage tasks per kc
  constexpr int ITS = (TASKS + 255) / 256;
  __shared__ __align__(16) bf16 sA[2][4 * 3 * P * 8];
  int HW = H * W;
  int segs = W / (32 * S);
  int y = blockIdx.x / segs;
  int x0 = (blockIdx.x - y * segs) * (32 * S);
  int tid = threadIdx.x;
  int lane = tid & 63, wave = tid >> 6;
  int pg = wave & 1, cg = wave >> 1;
  int q = lane >> 4, n = lane & 15;

  // --- precompute per-thread staging tasks (kc-invariant) ---
  int dstIdx[ITS], srcOff[ITS];
  bool act[ITS], val[ITS];
#pragma unroll
  for (int it = 0; it < ITS; ++it) {
    int tt = it * 256 + tid;
    act[it] = (tt < TASKS);
    int sub8 = tt & 7;
    int rp = tt >> 3;
    int row = rp / P;
    int pxl = rp - row * P;
    int yy = y + row - 1;
    int xg = x0 + pxl - 1;
    bool v = act[it] && ((unsigned)yy < (unsigned)H) && ((unsigned)xg < (unsigned)W);
    val[it] = v;
    srcOff[it] = v ? ((yy * W + xg) * 256 + sub8 * 4) : 0;
    dstIdx[it] = (((sub8 >> 1) * 3 + row) * P + pxl) * 8 + (sub8 & 1) * 4;
  }

  ushort4 pv[ITS];
  auto load_regs = [&](int kc) {
    int cb = kc << 5;
#pragma unroll
    for (int it = 0; it < ITS; ++it) {
      ushort4 z = {0, 0, 0, 0};
      pv[it] = val[it] ? *(const ushort4*)&in[(size_t)srcOff[it] + cb] : z;
    }
  };
  auto store_lds = [&](int buf) {
#pragma unroll
    for (int it = 0; it < ITS; ++it)
      if (act[it]) *(ushort4*)&sA[buf][dstIdx[it]] = pv[it];
  };

  floatx4 acc[S][4];
#pragma unroll
  for (int s = 0; s < S; ++s)
#pragma unroll
    for (int nt = 0; nt < 4; ++nt) acc[s][nt] = (floatx4)0.f;

  load_regs(0);
  store_lds(0);
  __syncthreads();
  load_regs(1);

  for (int kc = 0; kc < 8; ++kc) {
    const bf16* sv = &sA[kc & 1][0];
    const bf16* bpc = BP + (size_t)kc * 73728;   // kc*9*4*256*8
#pragma unroll
    for (int tap = 0; tap < 9; ++tap) {
      int ty = tap / 3, tx = tap % 3;            // row = dy+1, xoff = dx+1
      bf16x8 a[S];
#pragma unroll
      for (int s = 0; s < S; ++s)
        a[s] = *(const bf16x8*)&sv[((q * 3 + ty) * P + tx + s * 32 + pg * 16 + n) * 8];
      const bf16* bp = bpc + ((size_t)(tap * 4 + q) * 256 + blockIdx.y * 128 + cg * 64) * 8;
#pragma unroll
      for (int nt = 0; nt < 4; ++nt) {
        bf16x8 b = *(const bf16x8*)&bp[(nt * 16 + n) * 8];
#pragma unroll
        for (int s = 0; s < S; ++s)
          acc[s][nt] = __builtin_amdgcn_mfma_f32_16x16x32_bf16(a[s], b, acc[s][nt], 0, 0, 0);
      }
    }
    if (kc < 7) {
      store_lds((kc + 1) & 1);     // target buf last read at kc-1 (fenced)
      __syncthreads();             // publish for mfma(kc+1)
      if (kc < 6) load_regs(kc + 2);
    }
  }

#pragma unroll
  for (int s = 0; s < S; ++s) {
    int pbase = y * W + x0 + s * 32 + pg * 16 + q * 4;
#pragma unroll
    for (int nt = 0; nt < 4; ++nt) {
      int o = blockIdx.y * 128 + cg * 64 + nt * 16 + n;
      if (o < Co) {
        float bv = bias ? bias[o] : 0.f;
#pragma unroll
        for (int r = 0; r < 4; ++r) {
          float v = acc[s][nt][r] + bv;
          if (out1) out1[(size_t)o * HW + pbase + r] = v;
          if (out2) out2[(size_t)(pbase + r) * ns2 + o] = f2b(v);
        }
      }
    }
  }
}

// ---- mdcn v3c: 32-px tile (kept for L0/L1) ------------------------------
__global__ __launch_bounds__(512, 4) void mdcn_mfma_kernel(
    const bf16* __restrict__ UPn, const bf16* __restrict__ OM,
    const bf16* __restrict__ BP, const float* __restrict__ dcn_b,
    const bf16* __restrict__ ARM, bf16* __restrict__ F,
    int H, int W, int wshift) {
  __shared__ __align__(16) bf16 sval[2][32 * 272];   // 34,816 B
  __shared__ float4 mw[2304];                        // 36,864 B
  __shared__ int mi[2304];                           //  9,216 B
  int pb = blockIdx.x * 32;
  int tid = threadIdx.x;

  for (int t2 = tid; t2 < 2304; t2 += 512) {
    int px_ = t2 & 31, g = (t2 >> 5) & 7, tap = t2 >> 8;
    int ky = tap / 3, kx = tap - ky * 3;
    int p = pb + px_;
    int y = p >> wshift, x = p & (W - 1);
    const bf16* omp = OM + (size_t)p * 216;
    float dy = b2f(omp[g * 18 + tap]);
    float dx = b2f(omp[g * 18 + 9 + tap]);
    float mm = 1.f / (1.f + expf(-b2f(omp[144 + g * 9 + tap])));
    float fpy = (float)(y - 1 + ky) + dy;
    float fpx = (float)(x - 1 + kx) + dx;
    fpy = fminf(fmaxf(fpy, -1.0e4f), 1.0e4f);
    fpx = fminf(fmaxf(fpx, -1.0e4f), 1.0e4f);
    float fy0 = floorf(fpy), fx0 = floorf(fpx);
    float wy1 = fpy - fy0, wx1 = fpx - fx0;
    float wy0 = 1.f - wy1, wx0 = 1.f - wx1;
    int iy0 = (int)fy0, ix0 = (int)fx0;
    bool vy0 = (unsigned)iy0 < (unsigned)H;
    bool vy1 = (unsigned)(iy0 + 1) < (unsigned)H;
    bool vx0 = (unsigned)ix0 < (unsigned)W;
    bool vx1 = (unsigned)(ix0 + 1) < (unsigned)W;
    float w00 = (vy0 && vx0) ? mm * wy0 * wx0 : 0.f;
    float w01 = (vy0 && vx1) ? mm * wy0 * wx1 : 0.f;
    float w10 = (vy1 && vx0) ? mm * wy1 * wx0 : 0.f;
    float w11 = (vy1 && vx1) ? mm * wy1 * wx1 : 0.f;
    int iy0c = min(max(iy0, 0), H - 1);
    int iy1c = min(max(iy0 + 1, 0), H - 1);
    int ix0c = min(max(ix0, 0), W - 1);
    int ix1c = min(max(ix0 + 1, 0), W - 1);
    mw[t2] = make_float4(w00, w01, w10, w11);
    mi[t2] = (iy0c * W + ix0c) | ((ix1c - ix0c) << 20) | ((iy1c - iy0c) << 21);
  }
  __syncthreads();

  int l4 = tid & 7;
  int px = (tid >> 3) & 31;
  int gh = tid >> 8;
  int lane = tid & 63, wave = tid >> 6;
  int q = lane >> 4, n = lane & 15;
  int rowb = l4 >> 1;
  int woff = px * 8 + (l4 & 1) * 4;

  floatx4 acc[2][2];
#pragma unroll
  for (int m = 0; m < 2; ++m)
#pragma unroll
    for (int nt = 0; nt < 2; ++nt) acc[m][nt] = (floatx4)0.f;

  ushort4 gl[4][4];
  auto gatherLoad = [&](int t) {
    int base = t * 256 + px + gh * 128;
#pragma unroll
    for (int gg = 0; gg < 4; ++gg) {
      int g = gh * 4 + gg;
      int mv = mi[base + gg * 32];
      int idx = mv & 0x3FFFF;
      int dxs = (mv >> 20) & 1;
      int dyW = ((mv >> 21) & 1) * W;
      const bf16* up = UPn + (size_t)idx * 256 + g * 32 + l4 * 4;
      gl[gg][0] = *(const ushort4*)(up);
      gl[gg][1] = *(const ushort4*)(up + dxs * 256);
      gl[gg][2] = *(const ushort4*)(up + dyW * 256);
      gl[gg][3] = *(const ushort4*)(up + (dyW + dxs) * 256);
    }
  };
  auto gatherStore = [&](int t) {
    bf16* sv = &sval[t & 1][0];
    int base = t * 256 + px + gh * 128;
#pragma unroll
    for (int gg = 0; gg < 4; ++gg) {
      int g = gh * 4 + gg;
      float4 wv = mw[base + gg * 32];
      ushort4 u00 = gl[gg][0], u01 = gl[gg][1], u10 = gl[gg][2], u11 = gl[gg][3];
      ushort4 o4;
      o4.x = f2us(wv.x * us2f(u00.x) + wv.y * us2f(u01.x)
                + wv.z * us2f(u10.x) + wv.w * us2f(u11.x));
      o4.y = f2us(wv.x * us2f(u00.y) + wv.y * us2f(u01.y)
                + wv.z * us2f(u10.y) + wv.w * us2f(u11.y));
      o4.z = f2us(wv.x * us2f(u00.z) + wv.y * us2f(u01.z)
                + wv.z * us2f(u10.z) + wv.w * us2f(u11.z));
      o4.w = f2us(wv.x * us2f(u00.w) + wv.y * us2f(u01.w)
                + wv.z * us2f(u10.w) + wv.w * us2f(u11.w));
      *(ushort4*)&sv[(g * 4 + rowb) * 272 + woff] = o4;
    }
  };

  gatherLoad(0);
  gatherStore(0);
  for (int t = 0; t < 9; ++t) {
    __syncthreads();
    if (t < 8) gatherLoad(t + 1);
    const bf16* sv = &sval[t & 1][0];
    const bf16* bpt = BP + ((size_t)(t * 32) * 256 + wave * 32) * 8;
#pragma unroll
    for (int kc = 0; kc < 8; ++kc) {
      int R = kc * 4 + q;
      bf16x8 a0 = *(const bf16x8*)&sv[R * 272 + n * 8];
      bf16x8 a1 = *(const bf16x8*)&sv[R * 272 + (16 + n) * 8];
      const bf16* bp = bpt + (size_t)R * 2048;   // R*256*8
      bf16x8 b0 = *(const bf16x8*)&bp[n * 8];
      bf16x8 b1 = *(const bf16x8*)&bp[(16 + n) * 8];
      acc[0][0] = __builtin_amdgcn_mfma_f32_16x16x32_bf16(a0, b0, acc[0][0], 0, 0, 0);
      acc[0][1] = __builtin_amdgcn_mfma_f32_16x16x32_bf16(a0, b1, acc[0][1], 0, 0, 0);
      acc[1][0] = __builtin_amdgcn_mfma_f32_16x16x32_bf16(a1, b0, acc[1][0], 0, 0, 0);
      acc[1][1] = __builtin_amdgcn_mfma_f32_16x16x32_bf16(a1, b1, acc[1][1], 0, 0, 0);
    }
    if (t < 8) gatherStore(t + 1);
  }

#pragma unroll
  for (int m = 0; m < 2; ++m) {
#pragma unroll
    for (int nt = 0; nt < 2; ++nt) {
      int o = wave * 32 + nt * 16 + n;
      float bv = dcn_b[o];
#pragma unroll
      for (int r = 0; r < 4; ++r) {
        int p = pb + m * 16 + q * 4 + r;
        float v = fmaxf(acc[m][nt][r] + bv, 0.f) + b2f(ARM[(size_t)p * 256 + o]);
        F[(size_t)p * 256 + o] = f2b(v);
      }
    }
  }
}

// ---- mdcn64: 64-px tile, same lane-contiguous gather, per-tap meta ------
// Block 512 thr, grid HW/64. M=64 => packed-B read half as often (B-L2-bound
// fix). Gather: thread (l4=tid&7 ch-quad, px=tid>>3) x 8 groups — identical
// coalescing to v3c (8 lanes x 8B = full 64B line). Meta: thread (g=tid>>6,
// pxm=tid&63) computes meta(t+2) during tap t into double-buffered LDS
// (OM lines L1-hot after tap 0). Accumulation order (t,kc) per output
// identical to v3c.
__global__ __launch_bounds__(512, 1) void mdcn64_mfma_kernel(
    const bf16* __restrict__ UPn, const bf16* __restrict__ OM,
    const bf16* __restrict__ BP, const float* __restrict__ dcn_b,
    const bf16* __restrict__ ARM, bf16* __restrict__ F,
    int H, int W, int wshift) {
  // sval row: [64 px][8 ch] = 512 bf16 + 8 pad = 520 (1040 B, +4 banks/row)
  __shared__ __align__(16) bf16 sval[2][32 * 520];   // 66,560 B
  __shared__ float4 mw2[2][512];                     // 16,384 B
  __shared__ int mi2[2][512];                        //  4,096 B
  int pb = blockIdx.x * 64;
  int tid = threadIdx.x;
  int l4 = tid & 7;                   // channel quad (4 ch) within group
  int px = tid >> 3;                  // pixel 0..63 (gather)
  int gm = tid >> 6;                  // meta group 0..7
  int pxm = tid & 63;                 // meta pixel 0..63
  int lane = tid & 63, wave = tid >> 6;
  int q = lane >> 4, n = lane & 15;
  int rowb = l4 >> 1;
  int woff = px * 8 + (l4 & 1) * 4;

  // meta precompute invariants (thread owns (gm, pxm))
  int pM = pb + pxm;
  int yM = pM >> wshift, xM = pM & (W - 1);
  const bf16* ompM = OM + (size_t)pM * 216 + gm * 18;
  const bf16* ommM = OM + (size_t)pM * 216 + 144 + gm * 9;
  int slot = gm * 64 + pxm;

  auto metaCompute = [&](int t, int buf) {
    int ky = t / 3, kx = t - ky * 3;
    float dy = b2f(ompM[t]);
    float dx = b2f(ompM[9 + t]);
    float mm = 1.f / (1.f + expf(-b2f(ommM[t])));
    float fpy = (float)(yM - 1 + ky) + dy;
    float fpx = (float)(xM - 1 + kx) + dx;
    fpy = fminf(fmaxf(fpy, -1.0e4f), 1.0e4f);
    fpx = fminf(fmaxf(fpx, -1.0e4f), 1.0e4f);
    float fy0 = floorf(fpy), fx0 = floorf(fpx);
    float wy1 = fpy - fy0, wx1 = fpx - fx0;
    float wy0 = 1.f - wy1, wx0 = 1.f - wx1;
    int iy0 = (int)fy0, ix0 = (int)fx0;
    bool vy0 = (unsigned)iy0 < (unsigned)H;
    bool vy1 = (unsigned)(iy0 + 1) < (unsigned)H;
    bool vx0 = (unsigned)ix0 < (unsigned)W;
    bool vx1 = (unsigned)(ix0 + 1) < (unsigned)W;
    float w00 = (vy0 && vx0) ? mm * wy0 * wx0 : 0.f;
    float w01 = (vy0 && vx1) ? mm * wy0 * wx1 : 0.f;
    float w10 = (vy1 && vx0) ? mm * wy1 * wx0 : 0.f;
    float w11 = (vy1 && vx1) ? mm * wy1 * wx1 : 0.f;
    int iy0c = min(max(iy0, 0), H - 1);
    int iy1c = min(max(iy0 + 1, 0), H - 1);
    int ix0c = min(max(ix0, 0), W - 1);
    int ix1c = min(max(ix0 + 1, 0), W - 1);
    mw2[buf][slot] = make_float4(w00, w01, w10, w11);
    mi2[buf][slot] = (iy0c * W + ix0c) | ((ix1c - ix0c) << 20) | ((iy1c - iy0c) << 21);
  };

  floatx4 acc[4][2];
#pragma unroll
  for (int m = 0; m < 4; ++m)
#pragma unroll
    for (int nt = 0; nt < 2; ++nt) acc[m][nt] = (floatx4)0.f;

  ushort4 gl[8][4];
  auto gatherLoad = [&](int t) {
    int bufI = t & 1;
#pragma unroll
    for (int g = 0; g < 8; ++g) {
      int mv = mi2[bufI][g * 64 + px];
      int idx = mv & 0x3FFFF;
      int dxs = (mv >> 20) & 1;
      int dyW = ((mv >> 21) & 1) * W;
      const bf16* up = UPn + (size_t)idx * 256 + g * 32 + l4 * 4;
      gl[g][0] = *(const ushort4*)(up);
      gl[g][1] = *(const ushort4*)(up + dxs * 256);
      gl[g][2] = *(const ushort4*)(up + dyW * 256);
      gl[g][3] = *(const ushort4*)(up + (dyW + dxs) * 256);
    }
  };
  auto gatherStore = [&](int t) {
    bf16* sv = &sval[t & 1][0];
    int bufI = t & 1;
#pragma unroll
    for (int g = 0; g < 8; ++g) {
      float4 wv = mw2[bufI][g * 64 + px];
      ushort4 u00 = gl[g][0], u01 = gl[g][1], u10 = gl[g][2], u11 = gl[g][3];
      ushort4 o4;
      o4.x = f2us(wv.x * us2f(u00.x) + wv.y * us2f(u01.x)
                + wv.z * us2f(u10.x) + wv.w * us2f(u11.x));
      o4.y = f2us(wv.x * us2f(u00.y) + wv.y * us2f(u01.y)
                + wv.z * us2f(u10.y) + wv.w * us2f(u11.y));
      o4.z = f2us(wv.x * us2f(u00.z) + wv.y * us2f(u01.z)
                + wv.z * us2f(u10.z) + wv.w * us2f(u11.z));
      o4.w = f2us(wv.x * us2f(u00.w) + wv.y * us2f(u01.w)
                + wv.z * us2f(u10.w) + wv.w * us2f(u11.w));
      *(ushort4*)&sv[(g * 4 + rowb) * 520 + woff] = o4;
    }
  };

  // prologue: meta(0)->buf0, meta(1)->buf1, then gather tap 0
  metaCompute(0, 0);
  metaCompute(1, 1);
  __syncthreads();
  gatherLoad(0);
  gatherStore(0);

  for (int t = 0; t < 9; ++t) {
    __syncthreads();                 // publish sval[t&1]; meta buf[t&1] free
    if (t < 8) gatherLoad(t + 1);    // VMEM issue early (buf[(t+1)&1])
    if (t < 7) metaCompute(t + 2, t & 1);   // overlaps MFMA; read next tap+1
    const bf16* sv = &sval[t & 1][0];
    const bf16* bpt = BP + ((size_t)(t * 32) * 256 + wave * 32) * 8;
#pragma unroll
    for (int kc = 0; kc < 8; ++kc) {
      int R = kc * 4 + q;
      const bf16* bp = bpt + (size_t)R * 2048;   // R*256*8
      bf16x8 b0 = *(const bf16x8*)&bp[n * 8];
      bf16x8 b1 = *(const bf16x8*)&bp[(16 + n) * 8];
#pragma unroll
      for (int m = 0; m < 4; ++m) {
        bf16x8 a = *(const bf16x8*)&sv[R * 520 + (m * 16 + n) * 8];
        acc[m][0] = __builtin_amdgcn_mfma_f32_16x16x32_bf16(a, b0, acc[m][0], 0, 0, 0);
        acc[m][1] = __builtin_amdgcn_mfma_f32_16x16x32_bf16(a, b1, acc[m][1], 0, 0, 0);
      }
    }
    if (t < 8) gatherStore(t + 1);   // bilinear + LDS write after MFMA
  }

#pragma unroll
  for (int m = 0; m < 4; ++m) {
#pragma unroll
    for (int nt = 0; nt < 2; ++nt) {
      int o = wave * 32 + nt * 16 + n;
      float bv = dcn_b[o];
#pragma unroll
      for (int r = 0; r < 4; ++r) {
        int p = pb + m * 16 + q * 4 + r;
        float v = fmaxf(acc[m][nt][r] + bv, 0.f) + b2f(ARM[(size_t)p * 256 + o]);
        F[(size_t)p * 256 + o] = f2b(v);
      }
    }
  }
}

extern "C" void kernel_launch(void* const* d_in, const int* in_sizes, int n_in,
                              void* d_out, int out_size, void* d_ws, size_t ws_size,
                              hipStream_t stream) {
  // Inputs fp32, outputs fp32 (established rounds 3-5). Interior: bf16 NHWC.
  const float* c2 = (const float*)d_in[0];
  const float* c3 = (const float*)d_in[1];
  const float* c4 = (const float*)d_in[2];
  const float* c5 = (const float*)d_in[3];
  const float* lat_w = (const float*)d_in[31];
  const float* lat_b = (const float*)d_in[32];
  float* out = (float*)d_out;
  (void)ws_size; (void)in_sizes; (void)n_in; (void)out_size;

  const size_t p2_off = 0;
  const size_t p3_off = 4194304;
  const size_t p4_off = p3_off + 1048576;
  const size_t p5_off = p4_off + 262144;

  // ---- ws layout (~27.3MB; ws_size >= 28MB proven round 3) ----
  char* ws = (char*)d_ws;
  bf16* UPn = (bf16*)(ws);                    // 8MB NHWC
  bf16* ARM = (bf16*)(ws + 8388608);          // 8MB NHWC
  bf16* FB  = (bf16*)(ws + 16777216);         // 8MB NHWC (off_feat & F alias)
  bf16* P5N = (bf16*)(ws + 25165824);         // 128KB NHWC p5 copy
  bf16* BPout = (bf16*)(ws + 25296896);       // 1.125MB (also hosts p5 lat pack)
  bf16* BPfsm = (bf16*)(ws + 26476544);       // 512KB
  bf16* BPoff = (bf16*)(ws + 27000832);       // 256KB
  float* GAP = (float*)(ws + 27262976);
  float* SC  = (float*)(ws + 27271168);
  // p2 output region scratch: OM at +0 (6.75MB max), BPom at +10MiB,
  // BPdcn at +10MiB+1.125MB. All consumed before the final conv writes p2.
  bf16* OM = (bf16*)(out + p2_off);
  bf16* BPom = (bf16*)((char*)(out + p2_off) + 10485760);
  bf16* BPdcn = (bf16*)((char*)(out + p2_off) + 11665408);
  // p5 K-split partials (2MB) borrow the UPn region.
  float* PART = (float*)ws;

  // ---- p5 = conv1x1(c5, lat_w, lat_b), K-split x8 + reduce --------------
  packw1_kernel<<<2048, 256, 0, stream>>>(lat_w, BPout, 2048);
  conv1x1_part_kernel<<<dim3(8, 2, 8), 256, 0, stream>>>(c5, 256, BPout, PART);
  reduce_p5_kernel<<<256, 256, 0, stream>>>(PART, lat_b, out + p5_off, P5N, 256, 8);

  struct Lv {
    const float* featl; int Ci; int H; int W; int wshift;
    float* pdst; int wbase;
  };
  Lv levels[3] = {
      {c4, 1024, 32, 32, 5, out + p4_off, 4},
      {c3, 512, 64, 64, 6, out + p3_off, 13},
      {c2, 256, 128, 128, 7, out + p2_off, 22},
  };

  for (int li = 0; li < 3; ++li) {
    const Lv& L = levels[li];
    const float* att_w = (const float*)d_in[L.wbase + 0];
    const float* fsm_w = (const float*)d_in[L.wbase + 1];
    const float* off_w = (const float*)d_in[L.wbase + 2];
    const float* om_w  = (const float*)d_in[L.wbase + 3];
    const float* om_b  = (const float*)d_in[L.wbase + 4];
    const float* dcn_w = (const float*)d_in[L.wbase + 5];
    const float* dcn_b = (const float*)d_in[L.wbase + 6];
    const float* out_w = (const float*)d_in[L.wbase + 7];
    const float* out_b = (const float*)d_in[L.wbase + 8];
    int HW = L.H * L.W;

    // 0) fused pack of all 5 weight tensors for this level (1 launch)
    pack_level_kernel<<<L.Ci + 512 + 3 * 2304, 256, 0, stream>>>(
        fsm_w, L.Ci, off_w, om_w, dcn_w, out_w,
        BPfsm, BPoff, BPom, BPdcn, BPout);
    // 1) feat_up = bilinear 2x (NHWC -> NHWC): src = P5N or previous F(FB)
    upsample2x_nhwc_kernel<<<HW, 256, 0, stream>>>(
        (li == 0) ? P5N : FB, UPn, L.H / 2, L.W / 2);
    // 2) FSM: gap -> atten -> scaled 1x1 GEMM -> ARM (NHWC)
    gap_kernel<<<L.Ci, 256, 0, stream>>>(L.featl, GAP, HW, 1.f / (float)HW);
    atten_kernel<<<L.Ci / 4, 256, 0, stream>>>(att_w, GAP, SC, L.Ci);
    conv1x1_mfma_kernel<true, float><<<dim3(HW / 32, 2), 256, 0, stream>>>(
        L.featl, SC, nullptr, 0.f, L.Ci, 0, HW, BPfsm, nullptr,
        nullptr, ARM, 256);
    // 3) off_feat = conv1x1(concat(ARM, 2*UPn)) -> FB (NHWC)
    conv1x1_mfma_kernel<false, bf16><<<dim3(HW / 32, 2), 256, 0, stream>>>(
        ARM, nullptr, UPn, 2.f, 256, 256, HW, BPoff, nullptr,
        nullptr, FB, 256);
    // 4) om = conv3x3(FB) + om_b -> OM (NHWC stride 216, in p2 region)
    if (li == 2)
      conv3x3v2_kernel<2><<<dim3(HW / 64, 2), 256, 0, stream>>>(
          FB, BPom, om_b, L.H, L.W, 216, nullptr, OM, 216);
    else
      conv3x3v2_kernel<1><<<dim3(HW / 32, 2), 256, 0, stream>>>(
          FB, BPom, om_b, L.H, L.W, 216, nullptr, OM, 216);
    // 5) F = relu(mdcn(UPn, OM) + dcn_b) + ARM -> FB (NHWC)
    if (li == 2)
      mdcn64_mfma_kernel<<<HW / 64, 512, 0, stream>>>(
          UPn, OM, BPdcn, dcn_b, ARM, FB, L.H, L.W, L.wshift);
    else
      mdcn_mfma_kernel<<<HW / 32, 512, 0, stream>>>(
          UPn, OM, BPdcn, dcn_b, ARM, FB, L.H, L.W, L.wshift);
    // 6) p = conv3x3(F) + out_b -> fp32 NCHW output
    if (li == 2)
      conv3x3v2_kernel<2><<<dim3(HW / 64, 2), 256, 0, stream>>>(
          FB, BPout, out_b, L.H, L.W, 256, L.pdst, nullptr, 256);
    else
      conv3x3v2_kernel<1><<<dim3(HW / 32, 2), 256, 0, stream>>>(
          FB, BPout, out_b, L.H, L.W, 256, L.pdst, nullptr, 256);
  }
}

// Round 10
// 664.181 us; speedup vs baseline: 1.2539x; 1.0460x over previous
//
#include <hip/hip_runtime.h>
#include <hip/hip_bf16.h>

typedef __hip_bfloat16 bf16;
typedef __attribute__((ext_vector_type(8))) short bf16x8;
typedef __attribute__((ext_vector_type(4))) float floatx4;

__device__ __forceinline__ float b2f(bf16 v) { return __bfloat162float(v); }
__device__ __forceinline__ bf16 f2b(float v) { return __float2bfloat16(v); }
__device__ __forceinline__ float us2f(unsigned short u) {
  union { unsigned int i; float f; } v; v.i = ((unsigned int)u) << 16; return v.f;
}
__device__ __forceinline__ unsigned short f2us(float f) {
  bf16 h = f2b(f); return *(unsigned short*)&h;
}

// ---------------- global average pool: x (C,HW) fp32 NCHW -> gap[C] ------
__global__ __launch_bounds__(256) void gap_kernel(const float* __restrict__ x,
                                                  float* __restrict__ gap,
                                                  int HW, float inv) {
  int c = blockIdx.x;
  const float* p = x + (size_t)c * HW;
  float s = 0.f;
  for (int i = threadIdx.x; i < HW; i += 256) s += p[i];
  __shared__ float red[256];
  red[threadIdx.x] = s;
  __syncthreads();
  for (int w = 128; w > 0; w >>= 1) {
    if (threadIdx.x < w) red[threadIdx.x] += red[threadIdx.x + w];
    __syncthreads();
  }
  if (threadIdx.x == 0) gap[c] = red[0] * inv;
}

// -------- scale[o] = 1 + sigmoid( sum_i att_w[o,i] * gap[i] ) ------------
__global__ __launch_bounds__(256) void atten_kernel(const float* __restrict__ w,
                                                    const float* __restrict__ gap,
                                                    float* __restrict__ scale, int Ci) {
  int wave = threadIdx.x >> 6, lane = threadIdx.x & 63;
  int o = blockIdx.x * 4 + wave;
  const float4* wr = (const float4*)(w + (size_t)o * Ci);
  const float4* g4 = (const float4*)gap;
  int n4 = Ci >> 2;
  float s = 0.f;
  for (int i = lane; i < n4; i += 64) {
    float4 a = wr[i], b = g4[i];
    s += a.x * b.x + a.y * b.y + a.z * b.z + a.w * b.w;
  }
#pragma unroll
  for (int off = 32; off > 0; off >>= 1) s += __shfl_down(s, off);
  if (lane == 0) scale[o] = 1.f + 1.f / (1.f + expf(-s));
}

// ---- bilinear 2x upsample NHWC(256) -> NHWC(256), half-pixel, clamp -----
__global__ __launch_bounds__(256) void upsample2x_nhwc_kernel(
    const bf16* __restrict__ src, bf16* __restrict__ dst, int Hs, int Ws) {
  int p = blockIdx.x;       // output pixel
  int c = threadIdx.x;      // channel
  int W = Ws * 2;
  int y = p / W, x = p - y * W;
  float fy = y * 0.5f - 0.25f;
  float fx = x * 0.5f - 0.25f;
  int y0 = (int)floorf(fy), x0 = (int)floorf(fx);
  float wy1 = fy - (float)y0, wx1 = fx - (float)x0;
  int y0c = min(max(y0, 0), Hs - 1);
  int y1c = min(max(y0 + 1, 0), Hs - 1);
  int x0c = min(max(x0, 0), Ws - 1);
  int x1c = min(max(x0 + 1, 0), Ws - 1);
  float v00 = b2f(src[(size_t)(y0c * Ws + x0c) * 256 + c]);
  float v01 = b2f(src[(size_t)(y0c * Ws + x1c) * 256 + c]);
  float v10 = b2f(src[(size_t)(y1c * Ws + x0c) * 256 + c]);
  float v11 = b2f(src[(size_t)(y1c * Ws + x1c) * 256 + c]);
  float v = (1.f - wy1) * ((1.f - wx1) * v00 + wx1 * v01)
          + wy1 * ((1.f - wx1) * v10 + wx1 * v11);
  dst[(size_t)p * 256 + c] = f2b(v);
}

// ------- pack GEMM weights (fp32 [256][K]) -> bf16 MFMA-B layout ---------
__global__ __launch_bounds__(256) void packw1_kernel(const float* __restrict__ w,
                                                     bf16* __restrict__ BP, int K) {
  int idx = blockIdx.x * 256 + threadIdx.x;
  int j = idx & 7;
  int o = (idx >> 3) & 255;
  int kc8 = idx >> 11;
  int k = kc8 * 8 + j;
  BP[idx] = f2b(w[(size_t)o * K + k]);
}

// ---- fused per-level pack: fsm(w1) + off(w1) + om(w3) + dcn(wd) + out(w3)
__global__ __launch_bounds__(256) void pack_level_kernel(
    const float* __restrict__ fsm_w, int Ci,
    const float* __restrict__ off_w, const float* __restrict__ om_w,
    const float* __restrict__ dcn_w, const float* __restrict__ out_w,
    bf16* __restrict__ BPfsm, bf16* __restrict__ BPoff, bf16* __restrict__ BPom,
    bf16* __restrict__ BPdcn, bf16* __restrict__ BPout) {
  int b = blockIdx.x;
  if (b < Ci) {                       // fsm: packw1, K=Ci
    int idx = b * 256 + threadIdx.x;
    int j = idx & 7, o = (idx >> 3) & 255, k = (idx >> 11) * 8 + j;
    BPfsm[idx] = f2b(fsm_w[(size_t)o * Ci + k]);
    return;
  }
  b -= Ci;
  if (b < 512) {                      // off: packw1, K=512
    int idx = b * 256 + threadIdx.x;
    int j = idx & 7, o = (idx >> 3) & 255, k = (idx >> 11) * 8 + j;
    BPoff[idx] = f2b(off_w[(size_t)o * 512 + k]);
    return;
  }
  b -= 512;
  const float* w;
  bf16* BP;
  int Co;
  if (b < 2304) { w = om_w; BP = BPom; Co = 216; }
  else if (b < 4608) {                // dcn: tap-major packwd
    int idx = (b - 2304) * 256 + threadIdx.x;
    int j = idx & 7, o = (idx >> 3) & 255;
    int k = (idx >> 11) * 8 + j;      // 0..2303 tap-major
    int tap = k >> 8, ci = k & 255;
    BPdcn[idx] = f2b(dcn_w[((size_t)o * 256 + ci) * 9 + tap]);
    return;
  } else { w = out_w; BP = BPout; Co = 256; b -= 2304; }
  // packw3 body (Ci=256)
  int idx = (b % 2304) * 256 + threadIdx.x;
  int j = idx & 7;
  int t1 = idx >> 3;
  int o = t1 & 255;
  int t2 = t1 >> 8;
  int q = t2 & 3;
  int t3 = t2 >> 2;
  int tap = t3 % 9;
  int c = t3 / 9;
  int ci = c * 32 + q * 8 + j;
  float v = (o < Co) ? w[((size_t)o * 256 + ci) * 9 + tap] : 0.f;
  BP[idx] = f2b(v);
}

// ------------- 1x1 conv as MFMA GEMM (fused, full-K) ---------------------
template <bool NCHW1, typename TA1>
__global__ __launch_bounds__(256) void conv1x1_mfma_kernel(
    const TA1* __restrict__ A1, const float* __restrict__ scaleA,
    const bf16* __restrict__ A2, float scaleB,
    int Ci1, int Ci2, int HW,
    const bf16* __restrict__ BP, const float* __restrict__ bias,
    float* __restrict__ out1, bf16* __restrict__ out2, int ns2) {
  __shared__ __align__(16) bf16 sA[1024];   // [4 q][32 px][8]
  int p0 = blockIdx.x * 32;
  int tid = threadIdx.x;
  int pix = tid & 31, sub = tid >> 5;       // fp32-NCHW staging mapping
  int pix2 = tid >> 3, sub8 = tid & 7;      // NHWC staging mapping
  int lane = tid & 63, wave = tid >> 6;
  int pg = wave & 1, cg = wave >> 1;
  int q = lane >> 4, n = lane & 15;

  floatx4 acc[4];
#pragma unroll
  for (int nt = 0; nt < 4; ++nt) acc[nt] = (floatx4)0.f;

  int nch = (Ci1 + Ci2) >> 5;
  for (int kc = 0; kc < nch; ++kc) {
    int ci0 = kc << 5;
    if (NCHW1 && ci0 < Ci1) {
#pragma unroll
      for (int it = 0; it < 4; ++it) {
        int cil = it * 8 + sub;
        float x = (float)A1[(size_t)(ci0 + cil) * HW + p0 + pix];
        if (scaleA) x *= scaleA[ci0 + cil];
        sA[((cil >> 3) * 32 + pix) * 8 + (cil & 7)] = f2b(x);
      }
    } else {
      const bf16* src; int cb; bool scl;
      if (!NCHW1 && ci0 < Ci1) {
        src = (const bf16*)(const void*)A1; cb = ci0; scl = false;
      } else {
        src = A2; cb = ci0 - Ci1; scl = true;
      }
      ushort4 raw = *(const ushort4*)&src[(size_t)(p0 + pix2) * 256 + cb + sub8 * 4];
      if (scl) {
        raw.x = f2us(us2f(raw.x) * scaleB);
        raw.y = f2us(us2f(raw.y) * scaleB);
        raw.z = f2us(us2f(raw.z) * scaleB);
        raw.w = f2us(us2f(raw.w) * scaleB);
      }
      *(ushort4*)&sA[((sub8 >> 1) * 32 + pix2) * 8 + (sub8 & 1) * 4] = raw;
    }
    __syncthreads();
    bf16x8 a = *(const bf16x8*)&sA[(q * 32 + pg * 16 + n) * 8];
    const bf16* bp = BP + ((size_t)(kc * 4 + q) * 256 + blockIdx.y * 128 + cg * 64) * 8;
#pragma unroll
    for (int nt = 0; nt < 4; ++nt) {
      bf16x8 b = *(const bf16x8*)&bp[(nt * 16 + n) * 8];
      acc[nt] = __builtin_amdgcn_mfma_f32_16x16x32_bf16(a, b, acc[nt], 0, 0, 0);
    }
    __syncthreads();
  }

  int pbase = p0 + pg * 16 + q * 4;
#pragma unroll
  for (int nt = 0; nt < 4; ++nt) {
    int o = blockIdx.y * 128 + cg * 64 + nt * 16 + n;
    float bv = bias ? bias[o] : 0.f;
#pragma unroll
    for (int r = 0; r < 4; ++r) {
      float v = acc[nt][r] + bv;
      if (out1) out1[(size_t)o * HW + pbase + r] = v;
      if (out2) out2[(size_t)(pbase + r) * ns2 + o] = f2b(v);
    }
  }
}

// ---- K-split 1x1 conv: blockIdx.z covers kcPerZ k-chunks; fp32 partials -
// PART[((z*256+o))*HW + p].  Used where grid would otherwise be tiny.
template <bool NCHW1, typename TA1>
__global__ __launch_bounds__(256) void conv1x1_split_kernel(
    const TA1* __restrict__ A1, const float* __restrict__ scaleA,
    const bf16* __restrict__ A2, float scaleB,
    int Ci1, int HW,
    const bf16* __restrict__ BP, float* __restrict__ PART, int kcPerZ) {
  __shared__ __align__(16) bf16 sA[1024];   // [4 q][32 px][8]
  int p0 = blockIdx.x * 32;
  int tid = threadIdx.x;
  int pix = tid & 31, sub = tid >> 5;
  int pix2 = tid >> 3, sub8 = tid & 7;
  int lane = tid & 63, wave = tid >> 6;
  int pg = wave & 1, cg = wave >> 1;
  int q = lane >> 4, n = lane & 15;

  floatx4 acc[4];
#pragma unroll
  for (int nt = 0; nt < 4; ++nt) acc[nt] = (floatx4)0.f;

  int kc0 = blockIdx.z * kcPerZ;
  for (int kcl = 0; kcl < kcPerZ; ++kcl) {
    int kc = kc0 + kcl;
    int ci0 = kc << 5;
    if (NCHW1 && ci0 < Ci1) {
#pragma unroll
      for (int it = 0; it < 4; ++it) {
        int cil = it * 8 + sub;
        float x = (float)A1[(size_t)(ci0 + cil) * HW + p0 + pix];
        if (scaleA) x *= scaleA[ci0 + cil];
        sA[((cil >> 3) * 32 + pix) * 8 + (cil & 7)] = f2b(x);
      }
    } else {
      const bf16* src; int cb; bool scl;
      if (!NCHW1 && ci0 < Ci1) {
        src = (const bf16*)(const void*)A1; cb = ci0; scl = false;
      } else {
        src = A2; cb = ci0 - Ci1; scl = true;
      }
      ushort4 raw = *(const ushort4*)&src[(size_t)(p0 + pix2) * 256 + cb + sub8 * 4];
      if (scl) {
        raw.x = f2us(us2f(raw.x) * scaleB);
        raw.y = f2us(us2f(raw.y) * scaleB);
        raw.z = f2us(us2f(raw.z) * scaleB);
        raw.w = f2us(us2f(raw.w) * scaleB);
      }
      *(ushort4*)&sA[((sub8 >> 1) * 32 + pix2) * 8 + (sub8 & 1) * 4] = raw;
    }
    __syncthreads();
    bf16x8 a = *(const bf16x8*)&sA[(q * 32 + pg * 16 + n) * 8];
    const bf16* bp = BP + ((size_t)(kc * 4 + q) * 256 + blockIdx.y * 128 + cg * 64) * 8;
#pragma unroll
    for (int nt = 0; nt < 4; ++nt) {
      bf16x8 b = *(const bf16x8*)&bp[(nt * 16 + n) * 8];
      acc[nt] = __builtin_amdgcn_mfma_f32_16x16x32_bf16(a, b, acc[nt], 0, 0, 0);
    }
    __syncthreads();
  }

  int pbase = p0 + pg * 16 + q * 4;
#pragma unroll
  for (int nt = 0; nt < 4; ++nt) {
    int o = blockIdx.y * 128 + cg * 64 + nt * 16 + n;
#pragma unroll
    for (int r = 0; r < 4; ++r)
      PART[((size_t)blockIdx.z * 256 + o) * HW + pbase + r] = acc[nt][r];
  }
}

// ---- reduce K-split partials + bias -> fp32 NCHW + bf16 NHWC (p5) -------
__global__ __launch_bounds__(256) void reduce_p5_kernel(
    const float* __restrict__ PART, const float* __restrict__ bias,
    float* __restrict__ out1, bf16* __restrict__ out2, int HW, int KS) {
  int o = blockIdx.x;
  int p = threadIdx.x;
  float s = bias[o];
  for (int z = 0; z < KS; ++z) s += PART[((size_t)z * 256 + o) * HW + p];
  out1[(size_t)o * HW + p] = s;
  out2[(size_t)p * 256 + o] = f2b(s);
}

// ---- reduce K-split partials -> bf16 NHWC (no bias) ---------------------
__global__ __launch_bounds__(256) void reduce_nhwc_kernel(
    const float* __restrict__ PART, bf16* __restrict__ out2,
    int HW, int KS, int ns2) {
  int o = blockIdx.x;
  for (int p = threadIdx.x; p < HW; p += 256) {
    float s = 0.f;
    for (int z = 0; z < KS; ++z) s += PART[((size_t)z * 256 + o) * HW + p];
    out2[(size_t)p * ns2 + o] = f2b(s);
  }
}

// ------- 3x3 conv v2: row-window staging + reg-prefetch pipeline ---------
template <int S>
__global__ __launch_bounds__(256) void conv3x3v2_kernel(
    const bf16* __restrict__ in, const bf16* __restrict__ BP,
    const float* __restrict__ bias,
    int H, int W, int Co,
    float* __restrict__ out1, bf16* __restrict__ out2, int ns2) {
  constexpr int P = 32 * S + 2;
  constexpr int TASKS = 3 * P * 8;            // ushort4 stage tasks per kc
  constexpr int ITS = (TASKS + 255) / 256;
  __shared__ __align__(16) bf16 sA[2][4 * 3 * P * 8];
  int HW = H * W;
  int segs = W / (32 * S);
  int y = blockIdx.x / segs;
  int x0 = (blockIdx.x - y * segs) * (32 * S);
  int tid = threadIdx.x;
  int lane = tid & 63, wave = tid >> 6;
  int pg = wave & 1, cg = wave >> 1;
  int q = lane >> 4, n = lane & 15;

  // --- precompute per-thread staging tasks (kc-invariant) ---
  int dstIdx[ITS], srcOff[ITS];
  bool act[ITS], val[ITS];
#pragma unroll
  for (int it = 0; it < ITS; ++it) {
    int tt = it * 256 + tid;
    act[it] = (tt < TASKS);
    int sub8 = tt & 7;
    int rp = tt >> 3;
    int row = rp / P;
    int pxl = rp - row * P;
    int yy = y + row - 1;
    int xg = x0 + pxl - 1;
    bool v = act[it] && ((unsigned)yy < (unsigned)H) && ((unsigned)xg < (unsigned)W);
    val[it] = v;
    srcOff[it] = v ? ((yy * W + xg) * 256 + sub8 * 4) : 0;
    dstIdx[it] = (((sub8 >> 1) * 3 + row) * P + pxl) * 8 + (sub8 & 1) * 4;
  }

  ushort4 pv[ITS];
  auto load_regs = [&](int kc) {
    int cb = kc << 5;
#pragma unroll
    for (int it = 0; it < ITS; ++it) {
      ushort4 z = {0, 0, 0, 0};
      pv[it] = val[it] ? *(const ushort4*)&in[(size_t)srcOff[it] + cb] : z;
    }
  };
  auto store_lds = [&](int buf) {
#pragma unroll
    for (int it = 0; it < ITS; ++it)
      if (act[it]) *(ushort4*)&sA[buf][dstIdx[it]] = pv[it];
  };

  floatx4 acc[S][4];
#pragma unroll
  for (int s = 0; s < S; ++s)
#pragma unroll
    for (int nt = 0; nt < 4; ++nt) acc[s][nt] = (floatx4)0.f;

  load_regs(0);
  store_lds(0);
  __syncthreads();
  load_regs(1);

  for (int kc = 0; kc < 8; ++kc) {
    const bf16* sv = &sA[kc & 1][0];
    const bf16* bpc = BP + (size_t)kc * 73728;   // kc*9*4*256*8
#pragma unroll
    for (int tap = 0; tap < 9; ++tap) {
      int ty = tap / 3, tx = tap % 3;            // row = dy+1, xoff = dx+1
      bf16x8 a[S];
#pragma unroll
      for (int s = 0; s < S; ++s)
        a[s] = *(const bf16x8*)&sv[((q * 3 + ty) * P + tx + s * 32 + pg * 16 + n) * 8];
      const bf16* bp = bpc + ((size_t)(tap * 4 + q) * 256 + blockIdx.y * 128 + cg * 64) * 8;
#pragma unroll
      for (int nt = 0; nt < 4; ++nt) {
        bf16x8 b = *(const bf16x8*)&bp[(nt * 16 + n) * 8];
#pragma unroll
        for (int s = 0; s < S; ++s)
          acc[s][nt] = __builtin_amdgcn_mfma_f32_16x16x32_bf16(a[s], b, acc[s][nt], 0, 0, 0);
      }
    }
    if (kc < 7) {
      store_lds((kc + 1) & 1);     // target buf last read at kc-1 (fenced)
      __syncthreads();             // publish for mfma(kc+1)
      if (kc < 6) load_regs(kc + 2);
    }
  }

#pragma unroll
  for (int s = 0; s < S; ++s) {
    int pbase = y * W + x0 + s * 32 + pg * 16 + q * 4;
#pragma unroll
    for (int nt = 0; nt < 4; ++nt) {
      int o = blockIdx.y * 128 + cg * 64 + nt * 16 + n;
      if (o < Co) {
        float bv = bias ? bias[o] : 0.f;
#pragma unroll
        for (int r = 0; r < 4; ++r) {
          float v = acc[s][nt][r] + bv;
          if (out1) out1[(size_t)o * HW + pbase + r] = v;
          if (out2) out2[(size_t)(pbase + r) * ns2 + o] = f2b(v);
        }
      }
    }
  }
}

// ---- mdcn v3c: 32-px tile (kept for L0/L1) ------------------------------
__global__ __launch_bounds__(512, 4) void mdcn_mfma_kernel(
    const bf16* __restrict__ UPn, const bf16* __restrict__ OM,
    const bf16* __restrict__ BP, const float* __restrict__ dcn_b,
    const bf16* __restrict__ ARM, bf16* __restrict__ F,
    int H, int W, int wshift) {
  __shared__ __align__(16) bf16 sval[2][32 * 272];   // 34,816 B
  __shared__ float4 mw[2304];                        // 36,864 B
  __shared__ int mi[2304];                           //  9,216 B
  int pb = blockIdx.x * 32;
  int tid = threadIdx.x;

  for (int t2 = tid; t2 < 2304; t2 += 512) {
    int px_ = t2 & 31, g = (t2 >> 5) & 7, tap = t2 >> 8;
    int ky = tap / 3, kx = tap - ky * 3;
    int p = pb + px_;
    int y = p >> wshift, x = p & (W - 1);
    const bf16* omp = OM + (size_t)p * 216;
    float dy = b2f(omp[g * 18 + tap]);
    float dx = b2f(omp[g * 18 + 9 + tap]);
    float mm = 1.f / (1.f + expf(-b2f(omp[144 + g * 9 + tap])));
    float fpy = (float)(y - 1 + ky) + dy;
    float fpx = (float)(x - 1 + kx) + dx;
    fpy = fminf(fmaxf(fpy, -1.0e4f), 1.0e4f);
    fpx = fminf(fmaxf(fpx, -1.0e4f), 1.0e4f);
    float fy0 = floorf(fpy), fx0 = floorf(fpx);
    float wy1 = fpy - fy0, wx1 = fpx - fx0;
    float wy0 = 1.f - wy1, wx0 = 1.f - wx1;
    int iy0 = (int)fy0, ix0 = (int)fx0;
    bool vy0 = (unsigned)iy0 < (unsigned)H;
    bool vy1 = (unsigned)(iy0 + 1) < (unsigned)H;
    bool vx0 = (unsigned)ix0 < (unsigned)W;
    bool vx1 = (unsigned)(ix0 + 1) < (unsigned)W;
    float w00 = (vy0 && vx0) ? mm * wy0 * wx0 : 0.f;
    float w01 = (vy0 && vx1) ? mm * wy0 * wx1 : 0.f;
    float w10 = (vy1 && vx0) ? mm * wy1 * wx0 : 0.f;
    float w11 = (vy1 && vx1) ? mm * wy1 * wx1 : 0.f;
    int iy0c = min(max(iy0, 0), H - 1);
    int iy1c = min(max(iy0 + 1, 0), H - 1);
    int ix0c = min(max(ix0, 0), W - 1);
    int ix1c = min(max(ix0 + 1, 0), W - 1);
    mw[t2] = make_float4(w00, w01, w10, w11);
    mi[t2] = (iy0c * W + ix0c) | ((ix1c - ix0c) << 20) | ((iy1c - iy0c) << 21);
  }
  __syncthreads();

  int l4 = tid & 7;
  int px = (tid >> 3) & 31;
  int gh = tid >> 8;
  int lane = tid & 63, wave = tid >> 6;
  int q = lane >> 4, n = lane & 15;
  int rowb = l4 >> 1;
  int woff = px * 8 + (l4 & 1) * 4;

  floatx4 acc[2][2];
#pragma unroll
  for (int m = 0; m < 2; ++m)
#pragma unroll
    for (int nt = 0; nt < 2; ++nt) acc[m][nt] = (floatx4)0.f;

  ushort4 gl[4][4];
  auto gatherLoad = [&](int t) {
    int base = t * 256 + px + gh * 128;
#pragma unroll
    for (int gg = 0; gg < 4; ++gg) {
      int g = gh * 4 + gg;
      int mv = mi[base + gg * 32];
      int idx = mv & 0x3FFFF;
      int dxs = (mv >> 20) & 1;
      int dyW = ((mv >> 21) & 1) * W;
      const bf16* up = UPn + (size_t)idx * 256 + g * 32 + l4 * 4;
      gl[gg][0] = *(const ushort4*)(up);
      gl[gg][1] = *(const ushort4*)(up + dxs * 256);
      gl[gg][2] = *(const ushort4*)(up + dyW * 256);
      gl[gg][3] = *(const ushort4*)(up + (dyW + dxs) * 256);
    }
  };
  auto gatherStore = [&](int t) {
    bf16* sv = &sval[t & 1][0];
    int base = t * 256 + px + gh * 128;
#pragma unroll
    for (int gg = 0; gg < 4; ++gg) {
      int g = gh * 4 + gg;
      float4 wv = mw[base + gg * 32];
      ushort4 u00 = gl[gg][0], u01 = gl[gg][1], u10 = gl[gg][2], u11 = gl[gg][3];
      ushort4 o4;
      o4.x = f2us(wv.x * us2f(u00.x) + wv.y * us2f(u01.x)
                + wv.z * us2f(u10.x) + wv.w * us2f(u11.x));
      o4.y = f2us(wv.x * us2f(u00.y) + wv.y * us2f(u01.y)
                + wv.z * us2f(u10.y) + wv.w * us2f(u11.y));
      o4.z = f2us(wv.x * us2f(u00.z) + wv.y * us2f(u01.z)
                + wv.z * us2f(u10.z) + wv.w * us2f(u11.z));
      o4.w = f2us(wv.x * us2f(u00.w) + wv.y * us2f(u01.w)
                + wv.z * us2f(u10.w) + wv.w * us2f(u11.w));
      *(ushort4*)&sv[(g * 4 + rowb) * 272 + woff] = o4;
    }
  };

  gatherLoad(0);
  gatherStore(0);
  for (int t = 0; t < 9; ++t) {
    __syncthreads();
    if (t < 8) gatherLoad(t + 1);
    const bf16* sv = &sval[t & 1][0];
    const bf16* bpt = BP + ((size_t)(t * 32) * 256 + wave * 32) * 8;
#pragma unroll
    for (int kc = 0; kc < 8; ++kc) {
      int R = kc * 4 + q;
      bf16x8 a0 = *(const bf16x8*)&sv[R * 272 + n * 8];
      bf16x8 a1 = *(const bf16x8*)&sv[R * 272 + (16 + n) * 8];
      const bf16* bp = bpt + (size_t)R * 2048;   // R*256*8
      bf16x8 b0 = *(const bf16x8*)&bp[n * 8];
      bf16x8 b1 = *(const bf16x8*)&bp[(16 + n) * 8];
      acc[0][0] = __builtin_amdgcn_mfma_f32_16x16x32_bf16(a0, b0, acc[0][0], 0, 0, 0);
      acc[0][1] = __builtin_amdgcn_mfma_f32_16x16x32_bf16(a0, b1, acc[0][1], 0, 0, 0);
      acc[1][0] = __builtin_amdgcn_mfma_f32_16x16x32_bf16(a1, b0, acc[1][0], 0, 0, 0);
      acc[1][1] = __builtin_amdgcn_mfma_f32_16x16x32_bf16(a1, b1, acc[1][1], 0, 0, 0);
    }
    if (t < 8) gatherStore(t + 1);
  }

#pragma unroll
  for (int m = 0; m < 2; ++m) {
#pragma unroll
    for (int nt = 0; nt < 2; ++nt) {
      int o = wave * 32 + nt * 16 + n;
      float bv = dcn_b[o];
#pragma unroll
      for (int r = 0; r < 4; ++r) {
        int p = pb + m * 16 + q * 4 + r;
        float v = fmaxf(acc[m][nt][r] + bv, 0.f) + b2f(ARM[(size_t)p * 256 + o]);
        F[(size_t)p * 256 + o] = f2b(v);
      }
    }
  }
}

// ---- mdcn64: 64-px tile, lane-contiguous gather, per-tap meta (L2) ------
__global__ __launch_bounds__(512, 1) void mdcn64_mfma_kernel(
    const bf16* __restrict__ UPn, const bf16* __restrict__ OM,
    const bf16* __restrict__ BP, const float* __restrict__ dcn_b,
    const bf16* __restrict__ ARM, bf16* __restrict__ F,
    int H, int W, int wshift) {
  __shared__ __align__(16) bf16 sval[2][32 * 520];   // 66,560 B
  __shared__ float4 mw2[2][512];                     // 16,384 B
  __shared__ int mi2[2][512];                        //  4,096 B
  int pb = blockIdx.x * 64;
  int tid = threadIdx.x;
  int l4 = tid & 7;
  int px = tid >> 3;
  int gm = tid >> 6;
  int pxm = tid & 63;
  int lane = tid & 63, wave = tid >> 6;
  int q = lane >> 4, n = lane & 15;
  int rowb = l4 >> 1;
  int woff = px * 8 + (l4 & 1) * 4;

  int pM = pb + pxm;
  int yM = pM >> wshift, xM = pM & (W - 1);
  const bf16* ompM = OM + (size_t)pM * 216 + gm * 18;
  const bf16* ommM = OM + (size_t)pM * 216 + 144 + gm * 9;
  int slot = gm * 64 + pxm;

  auto metaCompute = [&](int t, int buf) {
    int ky = t / 3, kx = t - ky * 3;
    float dy = b2f(ompM[t]);
    float dx = b2f(ompM[9 + t]);
    float mm = 1.f / (1.f + expf(-b2f(ommM[t])));
    float fpy = (float)(yM - 1 + ky) + dy;
    float fpx = (float)(xM - 1 + kx) + dx;
    fpy = fminf(fmaxf(fpy, -1.0e4f), 1.0e4f);
    fpx = fminf(fmaxf(fpx, -1.0e4f), 1.0e4f);
    float fy0 = floorf(fpy), fx0 = floorf(fpx);
    float wy1 = fpy - fy0, wx1 = fpx - fx0;
    float wy0 = 1.f - wy1, wx0 = 1.f - wx1;
    int iy0 = (int)fy0, ix0 = (int)fx0;
    bool vy0 = (unsigned)iy0 < (unsigned)H;
    bool vy1 = (unsigned)(iy0 + 1) < (unsigned)H;
    bool vx0 = (unsigned)ix0 < (unsigned)W;
    bool vx1 = (unsigned)(ix0 + 1) < (unsigned)W;
    float w00 = (vy0 && vx0) ? mm * wy0 * wx0 : 0.f;
    float w01 = (vy0 && vx1) ? mm * wy0 * wx1 : 0.f;
    float w10 = (vy1 && vx0) ? mm * wy1 * wx0 : 0.f;
    float w11 = (vy1 && vx1) ? mm * wy1 * wx1 : 0.f;
    int iy0c = min(max(iy0, 0), H - 1);
    int iy1c = min(max(iy0 + 1, 0), H - 1);
    int ix0c = min(max(ix0, 0), W - 1);
    int ix1c = min(max(ix0 + 1, 0), W - 1);
    mw2[buf][slot] = make_float4(w00, w01, w10, w11);
    mi2[buf][slot] = (iy0c * W + ix0c) | ((ix1c - ix0c) << 20) | ((iy1c - iy0c) << 21);
  };

  floatx4 acc[4][2];
#pragma unroll
  for (int m = 0; m < 4; ++m)
#pragma unroll
    for (int nt = 0; nt < 2; ++nt) acc[m][nt] = (floatx4)0.f;

  ushort4 gl[8][4];
  auto gatherLoad = [&](int t) {
    int bufI = t & 1;
#pragma unroll
    for (int g = 0; g < 8; ++g) {
      int mv = mi2[bufI][g * 64 + px];
      int idx = mv & 0x3FFFF;
      int dxs = (mv >> 20) & 1;
      int dyW = ((mv >> 21) & 1) * W;
      const bf16* up = UPn + (size_t)idx * 256 + g * 32 + l4 * 4;
      gl[g][0] = *(const ushort4*)(up);
      gl[g][1] = *(const ushort4*)(up + dxs * 256);
      gl[g][2] = *(const ushort4*)(up + dyW * 256);
      gl[g][3] = *(const ushort4*)(up + (dyW + dxs) * 256);
    }
  };
  auto gatherStore = [&](int t) {
    bf16* sv = &sval[t & 1][0];
    int bufI = t & 1;
#pragma unroll
    for (int g = 0; g < 8; ++g) {
      float4 wv = mw2[bufI][g * 64 + px];
      ushort4 u00 = gl[g][0], u01 = gl[g][1], u10 = gl[g][2], u11 = gl[g][3];
      ushort4 o4;
      o4.x = f2us(wv.x * us2f(u00.x) + wv.y * us2f(u01.x)
                + wv.z * us2f(u10.x) + wv.w * us2f(u11.x));
      o4.y = f2us(wv.x * us2f(u00.y) + wv.y * us2f(u01.y)
                + wv.z * us2f(u10.y) + wv.w * us2f(u11.y));
      o4.z = f2us(wv.x * us2f(u00.z) + wv.y * us2f(u01.z)
                + wv.z * us2f(u10.z) + wv.w * us2f(u11.z));
      o4.w = f2us(wv.x * us2f(u00.w) + wv.y * us2f(u01.w)
                + wv.z * us2f(u10.w) + wv.w * us2f(u11.w));
      *(ushort4*)&sv[(g * 4 + rowb) * 520 + woff] = o4;
    }
  };

  metaCompute(0, 0);
  metaCompute(1, 1);
  __syncthreads();
  gatherLoad(0);
  gatherStore(0);

  for (int t = 0; t < 9; ++t) {
    __syncthreads();
    if (t < 8) gatherLoad(t + 1);
    if (t < 7) metaCompute(t + 2, t & 1);
    const bf16* sv = &sval[t & 1][0];
    const bf16* bpt = BP + ((size_t)(t * 32) * 256 + wave * 32) * 8;
#pragma unroll
    for (int kc = 0; kc < 8; ++kc) {
      int R = kc * 4 + q;
      const bf16* bp = bpt + (size_t)R * 2048;   // R*256*8
      bf16x8 b0 = *(const bf16x8*)&bp[n * 8];
      bf16x8 b1 = *(const bf16x8*)&bp[(16 + n) * 8];
#pragma unroll
      for (int m = 0; m < 4; ++m) {
        bf16x8 a = *(const bf16x8*)&sv[R * 520 + (m * 16 + n) * 8];
        acc[m][0] = __builtin_amdgcn_mfma_f32_16x16x32_bf16(a, b0, acc[m][0], 0, 0, 0);
        acc[m][1] = __builtin_amdgcn_mfma_f32_16x16x32_bf16(a, b1, acc[m][1], 0, 0, 0);
      }
    }
    if (t < 8) gatherStore(t + 1);
  }

#pragma unroll
  for (int m = 0; m < 4; ++m) {
#pragma unroll
    for (int nt = 0; nt < 2; ++nt) {
      int o = wave * 32 + nt * 16 + n;
      float bv = dcn_b[o];
#pragma unroll
      for (int r = 0; r < 4; ++r) {
        int p = pb + m * 16 + q * 4 + r;
        float v = fmaxf(acc[m][nt][r] + bv, 0.f) + b2f(ARM[(size_t)p * 256 + o]);
        F[(size_t)p * 256 + o] = f2b(v);
      }
    }
  }
}

extern "C" void kernel_launch(void* const* d_in, const int* in_sizes, int n_in,
                              void* d_out, int out_size, void* d_ws, size_t ws_size,
                              hipStream_t stream) {
  // Inputs fp32, outputs fp32 (established rounds 3-5). Interior: bf16 NHWC.
  const float* c2 = (const float*)d_in[0];
  const float* c3 = (const float*)d_in[1];
  const float* c4 = (const float*)d_in[2];
  const float* c5 = (const float*)d_in[3];
  const float* lat_w = (const float*)d_in[31];
  const float* lat_b = (const float*)d_in[32];
  float* out = (float*)d_out;
  (void)ws_size; (void)in_sizes; (void)n_in; (void)out_size;

  const size_t p2_off = 0;
  const size_t p3_off = 4194304;
  const size_t p4_off = p3_off + 1048576;
  const size_t p5_off = p4_off + 262144;

  // ---- ws layout (~27.3MB; ws_size >= 28MB proven round 3) ----
  char* ws = (char*)d_ws;
  bf16* UPn = (bf16*)(ws);                    // 8MB NHWC
  bf16* ARM = (bf16*)(ws + 8388608);          // 8MB NHWC
  bf16* FB  = (bf16*)(ws + 16777216);         // 8MB NHWC (off_feat & F alias)
  bf16* P5N = (bf16*)(ws + 25165824);         // 128KB NHWC p5 copy
  bf16* BPout = (bf16*)(ws + 25296896);       // 1.125MB (also hosts p5 lat pack)
  bf16* BPfsm = (bf16*)(ws + 26476544);       // 512KB
  bf16* BPoff = (bf16*)(ws + 27000832);       // 256KB
  float* GAP = (float*)(ws + 27262976);
  float* SC  = (float*)(ws + 27271168);
  // p2 output region scratch: OM at +0 (6.75MB max), BPom at +10MiB,
  // BPdcn at +10MiB+1.125MB. All consumed before the final conv writes p2.
  // L0 conv1x1 K-split partials (<=4MB) also borrow p2+0 (consumed by
  // reduce_nhwc before OM is written at step 4).
  bf16* OM = (bf16*)(out + p2_off);
  bf16* BPom = (bf16*)((char*)(out + p2_off) + 10485760);
  bf16* BPdcn = (bf16*)((char*)(out + p2_off) + 11665408);
  float* PARTL = (float*)(out + p2_off);
  // p5 K-split partials (2MB) borrow the UPn region.
  float* PART = (float*)ws;

  // ---- p5 = conv1x1(c5, lat_w, lat_b), K-split x8 + reduce --------------
  packw1_kernel<<<2048, 256, 0, stream>>>(lat_w, BPout, 2048);
  conv1x1_split_kernel<true, float><<<dim3(8, 2, 8), 256, 0, stream>>>(
      c5, nullptr, nullptr, 0.f, 2048, 256, BPout, PART, 8);
  reduce_p5_kernel<<<256, 256, 0, stream>>>(PART, lat_b, out + p5_off, P5N, 256, 8);

  struct Lv {
    const float* featl; int Ci; int H; int W; int wshift;
    float* pdst; int wbase;
  };
  Lv levels[3] = {
      {c4, 1024, 32, 32, 5, out + p4_off, 4},
      {c3, 512, 64, 64, 6, out + p3_off, 13},
      {c2, 256, 128, 128, 7, out + p2_off, 22},
  };

  for (int li = 0; li < 3; ++li) {
    const Lv& L = levels[li];
    const float* att_w = (const float*)d_in[L.wbase + 0];
    const float* fsm_w = (const float*)d_in[L.wbase + 1];
    const float* off_w = (const float*)d_in[L.wbase + 2];
    const float* om_w  = (const float*)d_in[L.wbase + 3];
    const float* om_b  = (const float*)d_in[L.wbase + 4];
    const float* dcn_w = (const float*)d_in[L.wbase + 5];
    const float* dcn_b = (const float*)d_in[L.wbase + 6];
    const float* out_w = (const float*)d_in[L.wbase + 7];
    const float* out_b = (const float*)d_in[L.wbase + 8];
    int HW = L.H * L.W;

    // 0) fused pack of all 5 weight tensors for this level (1 launch)
    pack_level_kernel<<<L.Ci + 512 + 3 * 2304, 256, 0, stream>>>(
        fsm_w, L.Ci, off_w, om_w, dcn_w, out_w,
        BPfsm, BPoff, BPom, BPdcn, BPout);
    // 1) feat_up = bilinear 2x (NHWC -> NHWC): src = P5N or previous F(FB)
    upsample2x_nhwc_kernel<<<HW, 256, 0, stream>>>(
        (li == 0) ? P5N : FB, UPn, L.H / 2, L.W / 2);
    // 2) FSM: gap -> atten -> scaled 1x1 GEMM -> ARM (NHWC)
    gap_kernel<<<L.Ci, 256, 0, stream>>>(L.featl, GAP, HW, 1.f / (float)HW);
    atten_kernel<<<L.Ci / 4, 256, 0, stream>>>(att_w, GAP, SC, L.Ci);
    if (li == 0) {
      // HW=1024: K-split x4 for parallelism (64 -> 256 blocks)
      conv1x1_split_kernel<true, float><<<dim3(HW / 32, 2, 4), 256, 0, stream>>>(
          L.featl, SC, nullptr, 0.f, L.Ci, HW, BPfsm, PARTL, 8);
      reduce_nhwc_kernel<<<256, 256, 0, stream>>>(PARTL, ARM, HW, 4, 256);
    } else {
      conv1x1_mfma_kernel<true, float><<<dim3(HW / 32, 2), 256, 0, stream>>>(
          L.featl, SC, nullptr, 0.f, L.Ci, 0, HW, BPfsm, nullptr,
          nullptr, ARM, 256);
    }
    // 3) off_feat = conv1x1(concat(ARM, 2*UPn)) -> FB (NHWC)
    if (li == 0) {
      conv1x1_split_kernel<false, bf16><<<dim3(HW / 32, 2, 2), 256, 0, stream>>>(
          ARM, nullptr, UPn, 2.f, 256, HW, BPoff, PARTL, 8);
      reduce_nhwc_kernel<<<256, 256, 0, stream>>>(PARTL, FB, HW, 2, 256);
    } else {
      conv1x1_mfma_kernel<false, bf16><<<dim3(HW / 32, 2), 256, 0, stream>>>(
          ARM, nullptr, UPn, 2.f, 256, 256, HW, BPoff, nullptr,
          nullptr, FB, 256);
    }
    // 4) om = conv3x3(FB) + om_b -> OM (NHWC stride 216, in p2 region)
    if (li == 2)
      conv3x3v2_kernel<2><<<dim3(HW / 64, 2), 256, 0, stream>>>(
          FB, BPom, om_b, L.H, L.W, 216, nullptr, OM, 216);
    else
      conv3x3v2_kernel<1><<<dim3(HW / 32, 2), 256, 0, stream>>>(
          FB, BPom, om_b, L.H, L.W, 216, nullptr, OM, 216);
    // 5) F = relu(mdcn(UPn, OM) + dcn_b) + ARM -> FB (NHWC)
    if (li == 2)
      mdcn64_mfma_kernel<<<HW / 64, 512, 0, stream>>>(
          UPn, OM, BPdcn, dcn_b, ARM, FB, L.H, L.W, L.wshift);
    else
      mdcn_mfma_kernel<<<HW / 32, 512, 0, stream>>>(
          UPn, OM, BPdcn, dcn_b, ARM, FB, L.H, L.W, L.wshift);
    // 6) p = conv3x3(F) + out_b -> fp32 NCHW output
    if (li == 2)
      conv3x3v2_kernel<2><<<dim3(HW / 64, 2), 256, 0, stream>>>(
          FB, BPout, out_b, L.H, L.W, 256, L.pdst, nullptr, 256);
    else
      conv3x3v2_kernel<1><<<dim3(HW / 32, 2), 256, 0, stream>>>(
          FB, BPout, out_b, L.H, L.W, 256, L.pdst, nullptr, 256);
  }
}

// Round 11
// 663.041 us; speedup vs baseline: 1.2560x; 1.0017x over previous
//
#include <hip/hip_runtime.h>
#include <hip/hip_bf16.h>

typedef __hip_bfloat16 bf16;
typedef __attribute__((ext_vector_type(8))) short bf16x8;
typedef __attribute__((ext_vector_type(4))) float floatx4;

__device__ __forceinline__ float b2f(bf16 v) { return __bfloat162float(v); }
__device__ __forceinline__ bf16 f2b(float v) { return __float2bfloat16(v); }
__device__ __forceinline__ float us2f(unsigned short u) {
  union { unsigned int i; float f; } v; v.i = ((unsigned int)u) << 16; return v.f;
}
__device__ __forceinline__ unsigned short f2us(float f) {
  bf16 h = f2b(f); return *(unsigned short*)&h;
}
// XCD-aware bijective block swizzle (T1): contiguous logical blocks land on
// one XCD (hw ids round-robin across 8 XCDs). Requires nwg%8==0 else identity.
__device__ __forceinline__ int xcd_swz(int hw, int nwg) {
  return (nwg & 7) ? hw : ((hw & 7) * (nwg >> 3) + (hw >> 3));
}

// ---------------- global average pool: x (C,HW) fp32 NCHW -> gap[C] ------
__global__ __launch_bounds__(256) void gap_kernel(const float* __restrict__ x,
                                                  float* __restrict__ gap,
                                                  int HW, float inv) {
  int c = blockIdx.x;
  const float* p = x + (size_t)c * HW;
  float s = 0.f;
  for (int i = threadIdx.x; i < HW; i += 256) s += p[i];
  __shared__ float red[256];
  red[threadIdx.x] = s;
  __syncthreads();
  for (int w = 128; w > 0; w >>= 1) {
    if (threadIdx.x < w) red[threadIdx.x] += red[threadIdx.x + w];
    __syncthreads();
  }
  if (threadIdx.x == 0) gap[c] = red[0] * inv;
}

// -------- scale[o] = 1 + sigmoid( sum_i att_w[o,i] * gap[i] ) ------------
__global__ __launch_bounds__(256) void atten_kernel(const float* __restrict__ w,
                                                    const float* __restrict__ gap,
                                                    float* __restrict__ scale, int Ci) {
  int wave = threadIdx.x >> 6, lane = threadIdx.x & 63;
  int o = blockIdx.x * 4 + wave;
  const float4* wr = (const float4*)(w + (size_t)o * Ci);
  const float4* g4 = (const float4*)gap;
  int n4 = Ci >> 2;
  float s = 0.f;
  for (int i = lane; i < n4; i += 64) {
    float4 a = wr[i], b = g4[i];
    s += a.x * b.x + a.y * b.y + a.z * b.z + a.w * b.w;
  }
#pragma unroll
  for (int off = 32; off > 0; off >>= 1) s += __shfl_down(s, off);
  if (lane == 0) scale[o] = 1.f + 1.f / (1.f + expf(-s));
}

// ---- bilinear 2x upsample NHWC(256) -> NHWC(256), half-pixel, clamp -----
__global__ __launch_bounds__(256) void upsample2x_nhwc_kernel(
    const bf16* __restrict__ src, bf16* __restrict__ dst, int Hs, int Ws) {
  int p = blockIdx.x;       // output pixel
  int c = threadIdx.x;      // channel
  int W = Ws * 2;
  int y = p / W, x = p - y * W;
  float fy = y * 0.5f - 0.25f;
  float fx = x * 0.5f - 0.25f;
  int y0 = (int)floorf(fy), x0 = (int)floorf(fx);
  float wy1 = fy - (float)y0, wx1 = fx - (float)x0;
  int y0c = min(max(y0, 0), Hs - 1);
  int y1c = min(max(y0 + 1, 0), Hs - 1);
  int x0c = min(max(x0, 0), Ws - 1);
  int x1c = min(max(x0 + 1, 0), Ws - 1);
  float v00 = b2f(src[(size_t)(y0c * Ws + x0c) * 256 + c]);
  float v01 = b2f(src[(size_t)(y0c * Ws + x1c) * 256 + c]);
  float v10 = b2f(src[(size_t)(y1c * Ws + x0c) * 256 + c]);
  float v11 = b2f(src[(size_t)(y1c * Ws + x1c) * 256 + c]);
  float v = (1.f - wy1) * ((1.f - wx1) * v00 + wx1 * v01)
          + wy1 * ((1.f - wx1) * v10 + wx1 * v11);
  dst[(size_t)p * 256 + c] = f2b(v);
}

// ------- pack GEMM weights (fp32 [256][K]) -> bf16 MFMA-B layout ---------
__global__ __launch_bounds__(256) void packw1_kernel(const float* __restrict__ w,
                                                     bf16* __restrict__ BP, int K) {
  int idx = blockIdx.x * 256 + threadIdx.x;
  int j = idx & 7;
  int o = (idx >> 3) & 255;
  int kc8 = idx >> 11;
  int k = kc8 * 8 + j;
  BP[idx] = f2b(w[(size_t)o * K + k]);
}

// ---- fused per-level pack: fsm(w1) + off(w1) + om(w3) + dcn(wd) + out(w3)
__global__ __launch_bounds__(256) void pack_level_kernel(
    const float* __restrict__ fsm_w, int Ci,
    const float* __restrict__ off_w, const float* __restrict__ om_w,
    const float* __restrict__ dcn_w, const float* __restrict__ out_w,
    bf16* __restrict__ BPfsm, bf16* __restrict__ BPoff, bf16* __restrict__ BPom,
    bf16* __restrict__ BPdcn, bf16* __restrict__ BPout) {
  int b = blockIdx.x;
  if (b < Ci) {                       // fsm: packw1, K=Ci
    int idx = b * 256 + threadIdx.x;
    int j = idx & 7, o = (idx >> 3) & 255, k = (idx >> 11) * 8 + j;
    BPfsm[idx] = f2b(fsm_w[(size_t)o * Ci + k]);
    return;
  }
  b -= Ci;
  if (b < 512) {                      // off: packw1, K=512
    int idx = b * 256 + threadIdx.x;
    int j = idx & 7, o = (idx >> 3) & 255, k = (idx >> 11) * 8 + j;
    BPoff[idx] = f2b(off_w[(size_t)o * 512 + k]);
    return;
  }
  b -= 512;
  const float* w;
  bf16* BP;
  int Co;
  if (b < 2304) { w = om_w; BP = BPom; Co = 216; }
  else if (b < 4608) {                // dcn: tap-major packwd
    int idx = (b - 2304) * 256 + threadIdx.x;
    int j = idx & 7, o = (idx >> 3) & 255;
    int k = (idx >> 11) * 8 + j;      // 0..2303 tap-major
    int tap = k >> 8, ci = k & 255;
    BPdcn[idx] = f2b(dcn_w[((size_t)o * 256 + ci) * 9 + tap]);
    return;
  } else { w = out_w; BP = BPout; Co = 256; b -= 2304; }
  // packw3 body (Ci=256)
  int idx = (b % 2304) * 256 + threadIdx.x;
  int j = idx & 7;
  int t1 = idx >> 3;
  int o = t1 & 255;
  int t2 = t1 >> 8;
  int q = t2 & 3;
  int t3 = t2 >> 2;
  int tap = t3 % 9;
  int c = t3 / 9;
  int ci = c * 32 + q * 8 + j;
  float v = (o < Co) ? w[((size_t)o * 256 + ci) * 9 + tap] : 0.f;
  BP[idx] = f2b(v);
}

// ------------- 1x1 conv as MFMA GEMM (fused, full-K) ---------------------
template <bool NCHW1, typename TA1>
__global__ __launch_bounds__(256) void conv1x1_mfma_kernel(
    const TA1* __restrict__ A1, const float* __restrict__ scaleA,
    const bf16* __restrict__ A2, float scaleB,
    int Ci1, int Ci2, int HW,
    const bf16* __restrict__ BP, const float* __restrict__ bias,
    float* __restrict__ out1, bf16* __restrict__ out2, int ns2) {
  __shared__ __align__(16) bf16 sA[1024];   // [4 q][32 px][8]
  int p0 = blockIdx.x * 32;
  int tid = threadIdx.x;
  int pix = tid & 31, sub = tid >> 5;       // fp32-NCHW staging mapping
  int pix2 = tid >> 3, sub8 = tid & 7;      // NHWC staging mapping
  int lane = tid & 63, wave = tid >> 6;
  int pg = wave & 1, cg = wave >> 1;
  int q = lane >> 4, n = lane & 15;

  floatx4 acc[4];
#pragma unroll
  for (int nt = 0; nt < 4; ++nt) acc[nt] = (floatx4)0.f;

  int nch = (Ci1 + Ci2) >> 5;
  for (int kc = 0; kc < nch; ++kc) {
    int ci0 = kc << 5;
    if (NCHW1 && ci0 < Ci1) {
#pragma unroll
      for (int it = 0; it < 4; ++it) {
        int cil = it * 8 + sub;
        float x = (float)A1[(size_t)(ci0 + cil) * HW + p0 + pix];
        if (scaleA) x *= scaleA[ci0 + cil];
        sA[((cil >> 3) * 32 + pix) * 8 + (cil & 7)] = f2b(x);
      }
    } else {
      const bf16* src; int cb; bool scl;
      if (!NCHW1 && ci0 < Ci1) {
        src = (const bf16*)(const void*)A1; cb = ci0; scl = false;
      } else {
        src = A2; cb = ci0 - Ci1; scl = true;
      }
      ushort4 raw = *(const ushort4*)&src[(size_t)(p0 + pix2) * 256 + cb + sub8 * 4];
      if (scl) {
        raw.x = f2us(us2f(raw.x) * scaleB);
        raw.y = f2us(us2f(raw.y) * scaleB);
        raw.z = f2us(us2f(raw.z) * scaleB);
        raw.w = f2us(us2f(raw.w) * scaleB);
      }
      *(ushort4*)&sA[((sub8 >> 1) * 32 + pix2) * 8 + (sub8 & 1) * 4] = raw;
    }
    __syncthreads();
    bf16x8 a = *(const bf16x8*)&sA[(q * 32 + pg * 16 + n) * 8];
    const bf16* bp = BP + ((size_t)(kc * 4 + q) * 256 + blockIdx.y * 128 + cg * 64) * 8;
#pragma unroll
    for (int nt = 0; nt < 4; ++nt) {
      bf16x8 b = *(const bf16x8*)&bp[(nt * 16 + n) * 8];
      acc[nt] = __builtin_amdgcn_mfma_f32_16x16x32_bf16(a, b, acc[nt], 0, 0, 0);
    }
    __syncthreads();
  }

  int pbase = p0 + pg * 16 + q * 4;
#pragma unroll
  for (int nt = 0; nt < 4; ++nt) {
    int o = blockIdx.y * 128 + cg * 64 + nt * 16 + n;
    float bv = bias ? bias[o] : 0.f;
#pragma unroll
    for (int r = 0; r < 4; ++r) {
      float v = acc[nt][r] + bv;
      if (out1) out1[(size_t)o * HW + pbase + r] = v;
      if (out2) out2[(size_t)(pbase + r) * ns2 + o] = f2b(v);
    }
  }
}

// ---- K-split 1x1 conv: blockIdx.z covers kcPerZ k-chunks; fp32 partials -
template <bool NCHW1, typename TA1>
__global__ __launch_bounds__(256) void conv1x1_split_kernel(
    const TA1* __restrict__ A1, const float* __restrict__ scaleA,
    const bf16* __restrict__ A2, float scaleB,
    int Ci1, int HW,
    const bf16* __restrict__ BP, float* __restrict__ PART, int kcPerZ) {
  __shared__ __align__(16) bf16 sA[1024];   // [4 q][32 px][8]
  int p0 = blockIdx.x * 32;
  int tid = threadIdx.x;
  int pix = tid & 31, sub = tid >> 5;
  int pix2 = tid >> 3, sub8 = tid & 7;
  int lane = tid & 63, wave = tid >> 6;
  int pg = wave & 1, cg = wave >> 1;
  int q = lane >> 4, n = lane & 15;

  floatx4 acc[4];
#pragma unroll
  for (int nt = 0; nt < 4; ++nt) acc[nt] = (floatx4)0.f;

  int kc0 = blockIdx.z * kcPerZ;
  for (int kcl = 0; kcl < kcPerZ; ++kcl) {
    int kc = kc0 + kcl;
    int ci0 = kc << 5;
    if (NCHW1 && ci0 < Ci1) {
#pragma unroll
      for (int it = 0; it < 4; ++it) {
        int cil = it * 8 + sub;
        float x = (float)A1[(size_t)(ci0 + cil) * HW + p0 + pix];
        if (scaleA) x *= scaleA[ci0 + cil];
        sA[((cil >> 3) * 32 + pix) * 8 + (cil & 7)] = f2b(x);
      }
    } else {
      const bf16* src; int cb; bool scl;
      if (!NCHW1 && ci0 < Ci1) {
        src = (const bf16*)(const void*)A1; cb = ci0; scl = false;
      } else {
        src = A2; cb = ci0 - Ci1; scl = true;
      }
      ushort4 raw = *(const ushort4*)&src[(size_t)(p0 + pix2) * 256 + cb + sub8 * 4];
      if (scl) {
        raw.x = f2us(us2f(raw.x) * scaleB);
        raw.y = f2us(us2f(raw.y) * scaleB);
        raw.z = f2us(us2f(raw.z) * scaleB);
        raw.w = f2us(us2f(raw.w) * scaleB);
      }
      *(ushort4*)&sA[((sub8 >> 1) * 32 + pix2) * 8 + (sub8 & 1) * 4] = raw;
    }
    __syncthreads();
    bf16x8 a = *(const bf16x8*)&sA[(q * 32 + pg * 16 + n) * 8];
    const bf16* bp = BP + ((size_t)(kc * 4 + q) * 256 + blockIdx.y * 128 + cg * 64) * 8;
#pragma unroll
    for (int nt = 0; nt < 4; ++nt) {
      bf16x8 b = *(const bf16x8*)&bp[(nt * 16 + n) * 8];
      acc[nt] = __builtin_amdgcn_mfma_f32_16x16x32_bf16(a, b, acc[nt], 0, 0, 0);
    }
    __syncthreads();
  }

  int pbase = p0 + pg * 16 + q * 4;
#pragma unroll
  for (int nt = 0; nt < 4; ++nt) {
    int o = blockIdx.y * 128 + cg * 64 + nt * 16 + n;
#pragma unroll
    for (int r = 0; r < 4; ++r)
      PART[((size_t)blockIdx.z * 256 + o) * HW + pbase + r] = acc[nt][r];
  }
}

// ---- reduce K-split partials + bias -> fp32 NCHW + bf16 NHWC (p5) -------
__global__ __launch_bounds__(256) void reduce_p5_kernel(
    const float* __restrict__ PART, const float* __restrict__ bias,
    float* __restrict__ out1, bf16* __restrict__ out2, int HW, int KS) {
  int o = blockIdx.x;
  int p = threadIdx.x;
  float s = bias[o];
  for (int z = 0; z < KS; ++z) s += PART[((size_t)z * 256 + o) * HW + p];
  out1[(size_t)o * HW + p] = s;
  out2[(size_t)p * 256 + o] = f2b(s);
}

// ---- reduce K-split partials -> bf16 NHWC (no bias) ---------------------
__global__ __launch_bounds__(256) void reduce_nhwc_kernel(
    const float* __restrict__ PART, bf16* __restrict__ out2,
    int HW, int KS, int ns2) {
  int o = blockIdx.x;
  for (int p = threadIdx.x; p < HW; p += 256) {
    float s = 0.f;
    for (int z = 0; z < KS; ++z) s += PART[((size_t)z * 256 + o) * HW + p];
    out2[(size_t)p * ns2 + o] = f2b(s);
  }
}

// ------- 3x3 conv v2: row-window staging + reg-prefetch pipeline ---------
template <int S>
__global__ __launch_bounds__(256) void conv3x3v2_kernel(
    const bf16* __restrict__ in, const bf16* __restrict__ BP,
    const float* __restrict__ bias,
    int H, int W, int Co,
    float* __restrict__ out1, bf16* __restrict__ out2, int ns2) {
  constexpr int P = 32 * S + 2;
  constexpr int TASKS = 3 * P * 8;            // ushort4 stage tasks per kc
  constexpr int ITS = (TASKS + 255) / 256;
  __shared__ __align__(16) bf16 sA[2][4 * 3 * P * 8];
  int HW = H * W;
  int segs = W / (32 * S);
  int y = blockIdx.x / segs;
  int x0 = (blockIdx.x - y * segs) * (32 * S);
  int tid = threadIdx.x;
  int lane = tid & 63, wave = tid >> 6;
  int pg = wave & 1, cg = wave >> 1;
  int q = lane >> 4, n = lane & 15;

  // --- precompute per-thread staging tasks (kc-invariant) ---
  int dstIdx[ITS], srcOff[ITS];
  bool act[ITS], val[ITS];
#pragma unroll
  for (int it = 0; it < ITS; ++it) {
    int tt = it * 256 + tid;
    act[it] = (tt < TASKS);
    int sub8 = tt & 7;
    int rp = tt >> 3;
    int row = rp / P;
    int pxl = rp - row * P;
    int yy = y + row - 1;
    int xg = x0 + pxl - 1;
    bool v = act[it] && ((unsigned)yy < (unsigned)H) && ((unsigned)xg < (unsigned)W);
    val[it] = v;
    srcOff[it] = v ? ((yy * W + xg) * 256 + sub8 * 4) : 0;
    dstIdx[it] = (((sub8 >> 1) * 3 + row) * P + pxl) * 8 + (sub8 & 1) * 4;
  }

  ushort4 pv[ITS];
  auto load_regs = [&](int kc) {
    int cb = kc << 5;
#pragma unroll
    for (int it = 0; it < ITS; ++it) {
      ushort4 z = {0, 0, 0, 0};
      pv[it] = val[it] ? *(const ushort4*)&in[(size_t)srcOff[it] + cb] : z;
    }
  };
  auto store_lds = [&](int buf) {
#pragma unroll
    for (int it = 0; it < ITS; ++it)
      if (act[it]) *(ushort4*)&sA[buf][dstIdx[it]] = pv[it];
  };

  floatx4 acc[S][4];
#pragma unroll
  for (int s = 0; s < S; ++s)
#pragma unroll
    for (int nt = 0; nt < 4; ++nt) acc[s][nt] = (floatx4)0.f;

  load_regs(0);
  store_lds(0);
  __syncthreads();
  load_regs(1);

  for (int kc = 0; kc < 8; ++kc) {
    const bf16* sv = &sA[kc & 1][0];
    const bf16* bpc = BP + (size_t)kc * 73728;   // kc*9*4*256*8
#pragma unroll
    for (int tap = 0; tap < 9; ++tap) {
      int ty = tap / 3, tx = tap % 3;            // row = dy+1, xoff = dx+1
      bf16x8 a[S];
#pragma unroll
      for (int s = 0; s < S; ++s)
        a[s] = *(const bf16x8*)&sv[((q * 3 + ty) * P + tx + s * 32 + pg * 16 + n) * 8];
      const bf16* bp = bpc + ((size_t)(tap * 4 + q) * 256 + blockIdx.y * 128 + cg * 64) * 8;
#pragma unroll
      for (int nt = 0; nt < 4; ++nt) {
        bf16x8 b = *(const bf16x8*)&bp[(nt * 16 + n) * 8];
#pragma unroll
        for (int s = 0; s < S; ++s)
          acc[s][nt] = __builtin_amdgcn_mfma_f32_16x16x32_bf16(a[s], b, acc[s][nt], 0, 0, 0);
      }
    }
    if (kc < 7) {
      store_lds((kc + 1) & 1);     // target buf last read at kc-1 (fenced)
      __syncthreads();             // publish for mfma(kc+1)
      if (kc < 6) load_regs(kc + 2);
    }
  }

#pragma unroll
  for (int s = 0; s < S; ++s) {
    int pbase = y * W + x0 + s * 32 + pg * 16 + q * 4;
#pragma unroll
    for (int nt = 0; nt < 4; ++nt) {
      int o = blockIdx.y * 128 + cg * 64 + nt * 16 + n;
      if (o < Co) {
        float bv = bias ? bias[o] : 0.f;
#pragma unroll
        for (int r = 0; r < 4; ++r) {
          float v = acc[s][nt][r] + bv;
          if (out1) out1[(size_t)o * HW + pbase + r] = v;
          if (out2) out2[(size_t)(pbase + r) * ns2 + o] = f2b(v);
        }
      }
    }
  }
}

// ---- mdcn v3c: 32-px tile (kept for L0/L1), +XCD swizzle ----------------
__global__ __launch_bounds__(512, 4) void mdcn_mfma_kernel(
    const bf16* __restrict__ UPn, const bf16* __restrict__ OM,
    const bf16* __restrict__ BP, const float* __restrict__ dcn_b,
    const bf16* __restrict__ ARM, bf16* __restrict__ F,
    int H, int W, int wshift) {
  __shared__ __align__(16) bf16 sval[2][32 * 272];   // 34,816 B
  __shared__ float4 mw[2304];                        // 36,864 B
  __shared__ int mi[2304];                           //  9,216 B
  int pb = xcd_swz(blockIdx.x, gridDim.x) * 32;
  int tid = threadIdx.x;

  for (int t2 = tid; t2 < 2304; t2 += 512) {
    int px_ = t2 & 31, g = (t2 >> 5) & 7, tap = t2 >> 8;
    int ky = tap / 3, kx = tap - ky * 3;
    int p = pb + px_;
    int y = p >> wshift, x = p & (W - 1);
    const bf16* omp = OM + (size_t)p * 216;
    float dy = b2f(omp[g * 18 + tap]);
    float dx = b2f(omp[g * 18 + 9 + tap]);
    float mm = 1.f / (1.f + expf(-b2f(omp[144 + g * 9 + tap])));
    float fpy = (float)(y - 1 + ky) + dy;
    float fpx = (float)(x - 1 + kx) + dx;
    fpy = fminf(fmaxf(fpy, -1.0e4f), 1.0e4f);
    fpx = fminf(fmaxf(fpx, -1.0e4f), 1.0e4f);
    float fy0 = floorf(fpy), fx0 = floorf(fpx);
    float wy1 = fpy - fy0, wx1 = fpx - fx0;
    float wy0 = 1.f - wy1, wx0 = 1.f - wx1;
    int iy0 = (int)fy0, ix0 = (int)fx0;
    bool vy0 = (unsigned)iy0 < (unsigned)H;
    bool vy1 = (unsigned)(iy0 + 1) < (unsigned)H;
    bool vx0 = (unsigned)ix0 < (unsigned)W;
    bool vx1 = (unsigned)(ix0 + 1) < (unsigned)W;
    float w00 = (vy0 && vx0) ? mm * wy0 * wx0 : 0.f;
    float w01 = (vy0 && vx1) ? mm * wy0 * wx1 : 0.f;
    float w10 = (vy1 && vx0) ? mm * wy1 * wx0 : 0.f;
    float w11 = (vy1 && vx1) ? mm * wy1 * wx1 : 0.f;
    int iy0c = min(max(iy0, 0), H - 1);
    int iy1c = min(max(iy0 + 1, 0), H - 1);
    int ix0c = min(max(ix0, 0), W - 1);
    int ix1c = min(max(ix0 + 1, 0), W - 1);
    mw[t2] = make_float4(w00, w01, w10, w11);
    mi[t2] = (iy0c * W + ix0c) | ((ix1c - ix0c) << 20) | ((iy1c - iy0c) << 21);
  }
  __syncthreads();

  int l4 = tid & 7;
  int px = (tid >> 3) & 31;
  int gh = tid >> 8;
  int lane = tid & 63, wave = tid >> 6;
  int q = lane >> 4, n = lane & 15;
  int rowb = l4 >> 1;
  int woff = px * 8 + (l4 & 1) * 4;

  floatx4 acc[2][2];
#pragma unroll
  for (int m = 0; m < 2; ++m)
#pragma unroll
    for (int nt = 0; nt < 2; ++nt) acc[m][nt] = (floatx4)0.f;

  ushort4 gl[4][4];
  auto gatherLoad = [&](int t) {
    int base = t * 256 + px + gh * 128;
#pragma unroll
    for (int gg = 0; gg < 4; ++gg) {
      int g = gh * 4 + gg;
      int mv = mi[base + gg * 32];
      int idx = mv & 0x3FFFF;
      int dxs = (mv >> 20) & 1;
      int dyW = ((mv >> 21) & 1) * W;
      const bf16* up = UPn + (size_t)idx * 256 + g * 32 + l4 * 4;
      gl[gg][0] = *(const ushort4*)(up);
      gl[gg][1] = *(const ushort4*)(up + dxs * 256);
      gl[gg][2] = *(const ushort4*)(up + dyW * 256);
      gl[gg][3] = *(const ushort4*)(up + (dyW + dxs) * 256);
    }
  };
  auto gatherStore = [&](int t) {
    bf16* sv = &sval[t & 1][0];
    int base = t * 256 + px + gh * 128;
#pragma unroll
    for (int gg = 0; gg < 4; ++gg) {
      int g = gh * 4 + gg;
      float4 wv = mw[base + gg * 32];
      ushort4 u00 = gl[gg][0], u01 = gl[gg][1], u10 = gl[gg][2], u11 = gl[gg][3];
      ushort4 o4;
      o4.x = f2us(wv.x * us2f(u00.x) + wv.y * us2f(u01.x)
                + wv.z * us2f(u10.x) + wv.w * us2f(u11.x));
      o4.y = f2us(wv.x * us2f(u00.y) + wv.y * us2f(u01.y)
                + wv.z * us2f(u10.y) + wv.w * us2f(u11.y));
      o4.z = f2us(wv.x * us2f(u00.z) + wv.y * us2f(u01.z)
                + wv.z * us2f(u10.z) + wv.w * us2f(u11.z));
      o4.w = f2us(wv.x * us2f(u00.w) + wv.y * us2f(u01.w)
                + wv.z * us2f(u10.w) + wv.w * us2f(u11.w));
      *(ushort4*)&sv[(g * 4 + rowb) * 272 + woff] = o4;
    }
  };

  gatherLoad(0);
  gatherStore(0);
  for (int t = 0; t < 9; ++t) {
    __syncthreads();
    if (t < 8) gatherLoad(t + 1);
    const bf16* sv = &sval[t & 1][0];
    const bf16* bpt = BP + ((size_t)(t * 32) * 256 + wave * 32) * 8;
#pragma unroll
    for (int kc = 0; kc < 8; ++kc) {
      int R = kc * 4 + q;
      bf16x8 a0 = *(const bf16x8*)&sv[R * 272 + n * 8];
      bf16x8 a1 = *(const bf16x8*)&sv[R * 272 + (16 + n) * 8];
      const bf16* bp = bpt + (size_t)R * 2048;   // R*256*8
      bf16x8 b0 = *(const bf16x8*)&bp[n * 8];
      bf16x8 b1 = *(const bf16x8*)&bp[(16 + n) * 8];
      acc[0][0] = __builtin_amdgcn_mfma_f32_16x16x32_bf16(a0, b0, acc[0][0], 0, 0, 0);
      acc[0][1] = __builtin_amdgcn_mfma_f32_16x16x32_bf16(a0, b1, acc[0][1], 0, 0, 0);
      acc[1][0] = __builtin_amdgcn_mfma_f32_16x16x32_bf16(a1, b0, acc[1][0], 0, 0, 0);
      acc[1][1] = __builtin_amdgcn_mfma_f32_16x16x32_bf16(a1, b1, acc[1][1], 0, 0, 0);
    }
    if (t < 8) gatherStore(t + 1);
  }

#pragma unroll
  for (int m = 0; m < 2; ++m) {
#pragma unroll
    for (int nt = 0; nt < 2; ++nt) {
      int o = wave * 32 + nt * 16 + n;
      float bv = dcn_b[o];
#pragma unroll
      for (int r = 0; r < 4; ++r) {
        int p = pb + m * 16 + q * 4 + r;
        float v = fmaxf(acc[m][nt][r] + bv, 0.f) + b2f(ARM[(size_t)p * 256 + o]);
        F[(size_t)p * 256 + o] = f2b(v);
      }
    }
  }
}

// ---- mdcn64: 64-px tile, lane-contiguous gather, per-tap meta (L2) ------
// +XCD swizzle: contiguous 2048-px span per XCD keeps bilinear tap rows
// L2-resident (fix for 118MB HBM overfetch seen in R10 counters).
__global__ __launch_bounds__(512, 1) void mdcn64_mfma_kernel(
    const bf16* __restrict__ UPn, const bf16* __restrict__ OM,
    const bf16* __restrict__ BP, const float* __restrict__ dcn_b,
    const bf16* __restrict__ ARM, bf16* __restrict__ F,
    int H, int W, int wshift) {
  __shared__ __align__(16) bf16 sval[2][32 * 520];   // 66,560 B
  __shared__ float4 mw2[2][512];                     // 16,384 B
  __shared__ int mi2[2][512];                        //  4,096 B
  int pb = xcd_swz(blockIdx.x, gridDim.x) * 64;
  int tid = threadIdx.x;
  int l4 = tid & 7;
  int px = tid >> 3;
  int gm = tid >> 6;
  int pxm = tid & 63;
  int lane = tid & 63, wave = tid >> 6;
  int q = lane >> 4, n = lane & 15;
  int rowb = l4 >> 1;
  int woff = px * 8 + (l4 & 1) * 4;

  int pM = pb + pxm;
  int yM = pM >> wshift, xM = pM & (W - 1);
  const bf16* ompM = OM + (size_t)pM * 216 + gm * 18;
  const bf16* ommM = OM + (size_t)pM * 216 + 144 + gm * 9;
  int slot = gm * 64 + pxm;

  auto metaCompute = [&](int t, int buf) {
    int ky = t / 3, kx = t - ky * 3;
    float dy = b2f(ompM[t]);
    float dx = b2f(ompM[9 + t]);
    float mm = 1.f / (1.f + expf(-b2f(ommM[t])));
    float fpy = (float)(yM - 1 + ky) + dy;
    float fpx = (float)(xM - 1 + kx) + dx;
    fpy = fminf(fmaxf(fpy, -1.0e4f), 1.0e4f);
    fpx = fminf(fmaxf(fpx, -1.0e4f), 1.0e4f);
    float fy0 = floorf(fpy), fx0 = floorf(fpx);
    float wy1 = fpy - fy0, wx1 = fpx - fx0;
    float wy0 = 1.f - wy1, wx0 = 1.f - wx1;
    int iy0 = (int)fy0, ix0 = (int)fx0;
    bool vy0 = (unsigned)iy0 < (unsigned)H;
    bool vy1 = (unsigned)(iy0 + 1) < (unsigned)H;
    bool vx0 = (unsigned)ix0 < (unsigned)W;
    bool vx1 = (unsigned)(ix0 + 1) < (unsigned)W;
    float w00 = (vy0 && vx0) ? mm * wy0 * wx0 : 0.f;
    float w01 = (vy0 && vx1) ? mm * wy0 * wx1 : 0.f;
    float w10 = (vy1 && vx0) ? mm * wy1 * wx0 : 0.f;
    float w11 = (vy1 && vx1) ? mm * wy1 * wx1 : 0.f;
    int iy0c = min(max(iy0, 0), H - 1);
    int iy1c = min(max(iy0 + 1, 0), H - 1);
    int ix0c = min(max(ix0, 0), W - 1);
    int ix1c = min(max(ix0 + 1, 0), W - 1);
    mw2[buf][slot] = make_float4(w00, w01, w10, w11);
    mi2[buf][slot] = (iy0c * W + ix0c) | ((ix1c - ix0c) << 20) | ((iy1c - iy0c) << 21);
  };

  floatx4 acc[4][2];
#pragma unroll
  for (int m = 0; m < 4; ++m)
#pragma unroll
    for (int nt = 0; nt < 2; ++nt) acc[m][nt] = (floatx4)0.f;

  ushort4 gl[8][4];
  auto gatherLoad = [&](int t) {
    int bufI = t & 1;
#pragma unroll
    for (int g = 0; g < 8; ++g) {
      int mv = mi2[bufI][g * 64 + px];
      int idx = mv & 0x3FFFF;
      int dxs = (mv >> 20) & 1;
      int dyW = ((mv >> 21) & 1) * W;
      const bf16* up = UPn + (size_t)idx * 256 + g * 32 + l4 * 4;
      gl[g][0] = *(const ushort4*)(up);
      gl[g][1] = *(const ushort4*)(up + dxs * 256);
      gl[g][2] = *(const ushort4*)(up + dyW * 256);
      gl[g][3] = *(const ushort4*)(up + (dyW + dxs) * 256);
    }
  };
  auto gatherStore = [&](int t) {
    bf16* sv = &sval[t & 1][0];
    int bufI = t & 1;
#pragma unroll
    for (int g = 0; g < 8; ++g) {
      float4 wv = mw2[bufI][g * 64 + px];
      ushort4 u00 = gl[g][0], u01 = gl[g][1], u10 = gl[g][2], u11 = gl[g][3];
      ushort4 o4;
      o4.x = f2us(wv.x * us2f(u00.x) + wv.y * us2f(u01.x)
                + wv.z * us2f(u10.x) + wv.w * us2f(u11.x));
      o4.y = f2us(wv.x * us2f(u00.y) + wv.y * us2f(u01.y)
                + wv.z * us2f(u10.y) + wv.w * us2f(u11.y));
      o4.z = f2us(wv.x * us2f(u00.z) + wv.y * us2f(u01.z)
                + wv.z * us2f(u10.z) + wv.w * us2f(u11.z));
      o4.w = f2us(wv.x * us2f(u00.w) + wv.y * us2f(u01.w)
                + wv.z * us2f(u10.w) + wv.w * us2f(u11.w));
      *(ushort4*)&sv[(g * 4 + rowb) * 520 + woff] = o4;
    }
  };

  metaCompute(0, 0);
  metaCompute(1, 1);
  __syncthreads();
  gatherLoad(0);
  gatherStore(0);

  for (int t = 0; t < 9; ++t) {
    __syncthreads();
    if (t < 8) gatherLoad(t + 1);
    if (t < 7) metaCompute(t + 2, t & 1);
    const bf16* sv = &sval[t & 1][0];
    const bf16* bpt = BP + ((size_t)(t * 32) * 256 + wave * 32) * 8;
#pragma unroll
    for (int kc = 0; kc < 8; ++kc) {
      int R = kc * 4 + q;
      const bf16* bp = bpt + (size_t)R * 2048;   // R*256*8
      bf16x8 b0 = *(const bf16x8*)&bp[n * 8];
      bf16x8 b1 = *(const bf16x8*)&bp[(16 + n) * 8];
#pragma unroll
      for (int m = 0; m < 4; ++m) {
        bf16x8 a = *(const bf16x8*)&sv[R * 520 + (m * 16 + n) * 8];
        acc[m][0] = __builtin_amdgcn_mfma_f32_16x16x32_bf16(a, b0, acc[m][0], 0, 0, 0);
        acc[m][1] = __builtin_amdgcn_mfma_f32_16x16x32_bf16(a, b1, acc[m][1], 0, 0, 0);
      }
    }
    if (t < 8) gatherStore(t + 1);
  }

#pragma unroll
  for (int m = 0; m < 4; ++m) {
#pragma unroll
    for (int nt = 0; nt < 2; ++nt) {
      int o = wave * 32 + nt * 16 + n;
      float bv = dcn_b[o];
#pragma unroll
      for (int r = 0; r < 4; ++r) {
        int p = pb + m * 16 + q * 4 + r;
        float v = fmaxf(acc[m][nt][r] + bv, 0.f) + b2f(ARM[(size_t)p * 256 + o]);
        F[(size_t)p * 256 + o] = f2b(v);
      }
    }
  }
}

extern "C" void kernel_launch(void* const* d_in, const int* in_sizes, int n_in,
                              void* d_out, int out_size, void* d_ws, size_t ws_size,
                              hipStream_t stream) {
  // Inputs fp32, outputs fp32 (established rounds 3-5). Interior: bf16 NHWC.
  const float* c2 = (const float*)d_in[0];
  const float* c3 = (const float*)d_in[1];
  const float* c4 = (const float*)d_in[2];
  const float* c5 = (const float*)d_in[3];
  const float* lat_w = (const float*)d_in[31];
  const float* lat_b = (const float*)d_in[32];
  float* out = (float*)d_out;
  (void)ws_size; (void)in_sizes; (void)n_in; (void)out_size;

  const size_t p2_off = 0;
  const size_t p3_off = 4194304;
  const size_t p4_off = p3_off + 1048576;
  const size_t p5_off = p4_off + 262144;

  // ---- ws layout (~27.3MB; ws_size >= 28MB proven round 3) ----
  char* ws = (char*)d_ws;
  bf16* UPn = (bf16*)(ws);                    // 8MB NHWC
  bf16* ARM = (bf16*)(ws + 8388608);          // 8MB NHWC
  bf16* FB  = (bf16*)(ws + 16777216);         // 8MB NHWC (off_feat & F alias)
  bf16* P5N = (bf16*)(ws + 25165824);         // 128KB NHWC p5 copy
  bf16* BPout = (bf16*)(ws + 25296896);       // 1.125MB (also hosts p5 lat pack)
  bf16* BPfsm = (bf16*)(ws + 26476544);       // 512KB
  bf16* BPoff = (bf16*)(ws + 27000832);       // 256KB
  float* GAP = (float*)(ws + 27262976);
  float* SC  = (float*)(ws + 27271168);
  // p2 output region scratch: OM at +0 (6.75MB max), BPom at +10MiB,
  // BPdcn at +10MiB+1.125MB. All consumed before the final conv writes p2.
  // L0 conv1x1 K-split partials (<=4MB) also borrow p2+0 (consumed by
  // reduce_nhwc before OM is written at step 4).
  bf16* OM = (bf16*)(out + p2_off);
  bf16* BPom = (bf16*)((char*)(out + p2_off) + 10485760);
  bf16* BPdcn = (bf16*)((char*)(out + p2_off) + 11665408);
  float* PARTL = (float*)(out + p2_off);
  // p5 K-split partials (2MB) borrow the UPn region.
  float* PART = (float*)ws;

  // ---- p5 = conv1x1(c5, lat_w, lat_b), K-split x8 + reduce --------------
  packw1_kernel<<<2048, 256, 0, stream>>>(lat_w, BPout, 2048);
  conv1x1_split_kernel<true, float><<<dim3(8, 2, 8), 256, 0, stream>>>(
      c5, nullptr, nullptr, 0.f, 2048, 256, BPout, PART, 8);
  reduce_p5_kernel<<<256, 256, 0, stream>>>(PART, lat_b, out + p5_off, P5N, 256, 8);

  struct Lv {
    const float* featl; int Ci; int H; int W; int wshift;
    float* pdst; int wbase;
  };
  Lv levels[3] = {
      {c4, 1024, 32, 32, 5, out + p4_off, 4},
      {c3, 512, 64, 64, 6, out + p3_off, 13},
      {c2, 256, 128, 128, 7, out + p2_off, 22},
  };

  for (int li = 0; li < 3; ++li) {
    const Lv& L = levels[li];
    const float* att_w = (const float*)d_in[L.wbase + 0];
    const float* fsm_w = (const float*)d_in[L.wbase + 1];
    const float* off_w = (const float*)d_in[L.wbase + 2];
    const float* om_w  = (const float*)d_in[L.wbase + 3];
    const float* om_b  = (const float*)d_in[L.wbase + 4];
    const float* dcn_w = (const float*)d_in[L.wbase + 5];
    const float* dcn_b = (const float*)d_in[L.wbase + 6];
    const float* out_w = (const float*)d_in[L.wbase + 7];
    const float* out_b = (const float*)d_in[L.wbase + 8];
    int HW = L.H * L.W;

    // 0) fused pack of all 5 weight tensors for this level (1 launch)
    pack_level_kernel<<<L.Ci + 512 + 3 * 2304, 256, 0, stream>>>(
        fsm_w, L.Ci, off_w, om_w, dcn_w, out_w,
        BPfsm, BPoff, BPom, BPdcn, BPout);
    // 1) feat_up = bilinear 2x (NHWC -> NHWC): src = P5N or previous F(FB)
    upsample2x_nhwc_kernel<<<HW, 256, 0, stream>>>(
        (li == 0) ? P5N : FB, UPn, L.H / 2, L.W / 2);
    // 2) FSM: gap -> atten -> scaled 1x1 GEMM -> ARM (NHWC)
    gap_kernel<<<L.Ci, 256, 0, stream>>>(L.featl, GAP, HW, 1.f / (float)HW);
    atten_kernel<<<L.Ci / 4, 256, 0, stream>>>(att_w, GAP, SC, L.Ci);
    if (li == 0) {
      // HW=1024: K-split x4 for parallelism (64 -> 256 blocks)
      conv1x1_split_kernel<true, float><<<dim3(HW / 32, 2, 4), 256, 0, stream>>>(
          L.featl, SC, nullptr, 0.f, L.Ci, HW, BPfsm, PARTL, 8);
      reduce_nhwc_kernel<<<256, 256, 0, stream>>>(PARTL, ARM, HW, 4, 256);
    } else {
      conv1x1_mfma_kernel<true, float><<<dim3(HW / 32, 2), 256, 0, stream>>>(
          L.featl, SC, nullptr, 0.f, L.Ci, 0, HW, BPfsm, nullptr,
          nullptr, ARM, 256);
    }
    // 3) off_feat = conv1x1(concat(ARM, 2*UPn)) -> FB (NHWC)
    if (li == 0) {
      conv1x1_split_kernel<false, bf16><<<dim3(HW / 32, 2, 2), 256, 0, stream>>>(
          ARM, nullptr, UPn, 2.f, 256, HW, BPoff, PARTL, 8);
      reduce_nhwc_kernel<<<256, 256, 0, stream>>>(PARTL, FB, HW, 2, 256);
    } else {
      conv1x1_mfma_kernel<false, bf16><<<dim3(HW / 32, 2), 256, 0, stream>>>(
          ARM, nullptr, UPn, 2.f, 256, 256, HW, BPoff, nullptr,
          nullptr, FB, 256);
    }
    // 4) om = conv3x3(FB) + om_b -> OM (NHWC stride 216, in p2 region)
    if (li == 2)
      conv3x3v2_kernel<2><<<dim3(HW / 64, 2), 256, 0, stream>>>(
          FB, BPom, om_b, L.H, L.W, 216, nullptr, OM, 216);
    else
      conv3x3v2_kernel<1><<<dim3(HW / 32, 2), 256, 0, stream>>>(
          FB, BPom, om_b, L.H, L.W, 216, nullptr, OM, 216);
    // 5) F = relu(mdcn(UPn, OM) + dcn_b) + ARM -> FB (NHWC)
    if (li == 2)
      mdcn64_mfma_kernel<<<HW / 64, 512, 0, stream>>>(
          UPn, OM, BPdcn, dcn_b, ARM, FB, L.H, L.W, L.wshift);
    else
      mdcn_mfma_kernel<<<HW / 32, 512, 0, stream>>>(
          UPn, OM, BPdcn, dcn_b, ARM, FB, L.H, L.W, L.wshift);
    // 6) p = conv3x3(F) + out_b -> fp32 NCHW output
    if (li == 2)
      conv3x3v2_kernel<2><<<dim3(HW / 64, 2), 256, 0, stream>>>(
          FB, BPout, out_b, L.H, L.W, 256, L.pdst, nullptr, 256);
    else
      conv3x3v2_kernel<1><<<dim3(HW / 32, 2), 256, 0, stream>>>(
          FB, BPout, out_b, L.H, L.W, 256, L.pdst, nullptr, 256);
  }
}

// Round 12
// 639.725 us; speedup vs baseline: 1.3018x; 1.0364x over previous
//
#include <hip/hip_runtime.h>
#include <hip/hip_bf16.h>

typedef __hip_bfloat16 bf16;
typedef __attribute__((ext_vector_type(8))) short bf16x8;
typedef __attribute__((ext_vector_type(4))) float floatx4;

__device__ __forceinline__ float b2f(bf16 v) { return __bfloat162float(v); }
__device__ __forceinline__ bf16 f2b(float v) { return __float2bfloat16(v); }
__device__ __forceinline__ float us2f(unsigned short u) {
  union { unsigned int i; float f; } v; v.i = ((unsigned int)u) << 16; return v.f;
}
__device__ __forceinline__ unsigned short f2us(float f) {
  bf16 h = f2b(f); return *(unsigned short*)&h;
}
// XCD-aware bijective block swizzle (T1): contiguous logical blocks land on
// one XCD (hw ids round-robin across 8 XCDs). Requires nwg%8==0 else identity.
__device__ __forceinline__ int xcd_swz(int hw, int nwg) {
  return (nwg & 7) ? hw : ((hw & 7) * (nwg >> 3) + (hw >> 3));
}

// ---------------- global average pool: x (C,HW) fp32 NCHW -> gap[C] ------
__global__ __launch_bounds__(256) void gap_kernel(const float* __restrict__ x,
                                                  float* __restrict__ gap,
                                                  int HW, float inv) {
  int c = blockIdx.x;
  const float* p = x + (size_t)c * HW;
  float s = 0.f;
  for (int i = threadIdx.x; i < HW; i += 256) s += p[i];
  __shared__ float red[256];
  red[threadIdx.x] = s;
  __syncthreads();
  for (int w = 128; w > 0; w >>= 1) {
    if (threadIdx.x < w) red[threadIdx.x] += red[threadIdx.x + w];
    __syncthreads();
  }
  if (threadIdx.x == 0) gap[c] = red[0] * inv;
}

// -------- scale[o] = 1 + sigmoid( sum_i att_w[o,i] * gap[i] ) ------------
__global__ __launch_bounds__(256) void atten_kernel(const float* __restrict__ w,
                                                    const float* __restrict__ gap,
                                                    float* __restrict__ scale, int Ci) {
  int wave = threadIdx.x >> 6, lane = threadIdx.x & 63;
  int o = blockIdx.x * 4 + wave;
  const float4* wr = (const float4*)(w + (size_t)o * Ci);
  const float4* g4 = (const float4*)gap;
  int n4 = Ci >> 2;
  float s = 0.f;
  for (int i = lane; i < n4; i += 64) {
    float4 a = wr[i], b = g4[i];
    s += a.x * b.x + a.y * b.y + a.z * b.z + a.w * b.w;
  }
#pragma unroll
  for (int off = 32; off > 0; off >>= 1) s += __shfl_down(s, off);
  if (lane == 0) scale[o] = 1.f + 1.f / (1.f + expf(-s));
}

// ---- bilinear 2x upsample NHWC(256) -> NHWC(256), half-pixel, clamp -----
__global__ __launch_bounds__(256) void upsample2x_nhwc_kernel(
    const bf16* __restrict__ src, bf16* __restrict__ dst, int Hs, int Ws) {
  int p = blockIdx.x;       // output pixel
  int c = threadIdx.x;      // channel
  int W = Ws * 2;
  int y = p / W, x = p - y * W;
  float fy = y * 0.5f - 0.25f;
  float fx = x * 0.5f - 0.25f;
  int y0 = (int)floorf(fy), x0 = (int)floorf(fx);
  float wy1 = fy - (float)y0, wx1 = fx - (float)x0;
  int y0c = min(max(y0, 0), Hs - 1);
  int y1c = min(max(y0 + 1, 0), Hs - 1);
  int x0c = min(max(x0, 0), Ws - 1);
  int x1c = min(max(x0 + 1, 0), Ws - 1);
  float v00 = b2f(src[(size_t)(y0c * Ws + x0c) * 256 + c]);
  float v01 = b2f(src[(size_t)(y0c * Ws + x1c) * 256 + c]);
  float v10 = b2f(src[(size_t)(y1c * Ws + x0c) * 256 + c]);
  float v11 = b2f(src[(size_t)(y1c * Ws + x1c) * 256 + c]);
  float v = (1.f - wy1) * ((1.f - wx1) * v00 + wx1 * v01)
          + wy1 * ((1.f - wx1) * v10 + wx1 * v11);
  dst[(size_t)p * 256 + c] = f2b(v);
}

// ------- pack GEMM weights (fp32 [256][K]) -> bf16 MFMA-B layout ---------
__global__ __launch_bounds__(256) void packw1_kernel(const float* __restrict__ w,
                                                     bf16* __restrict__ BP, int K) {
  int idx = blockIdx.x * 256 + threadIdx.x;
  int j = idx & 7;
  int o = (idx >> 3) & 255;
  int kc8 = idx >> 11;
  int k = kc8 * 8 + j;
  BP[idx] = f2b(w[(size_t)o * K + k]);
}

// ---- fused per-level pack: fsm(w1) + off(w1) + om(w3) + dcn(wd) + out(w3)
__global__ __launch_bounds__(256) void pack_level_kernel(
    const float* __restrict__ fsm_w, int Ci,
    const float* __restrict__ off_w, const float* __restrict__ om_w,
    const float* __restrict__ dcn_w, const float* __restrict__ out_w,
    bf16* __restrict__ BPfsm, bf16* __restrict__ BPoff, bf16* __restrict__ BPom,
    bf16* __restrict__ BPdcn, bf16* __restrict__ BPout) {
  int b = blockIdx.x;
  if (b < Ci) {                       // fsm: packw1, K=Ci
    int idx = b * 256 + threadIdx.x;
    int j = idx & 7, o = (idx >> 3) & 255, k = (idx >> 11) * 8 + j;
    BPfsm[idx] = f2b(fsm_w[(size_t)o * Ci + k]);
    return;
  }
  b -= Ci;
  if (b < 512) {                      // off: packw1, K=512
    int idx = b * 256 + threadIdx.x;
    int j = idx & 7, o = (idx >> 3) & 255, k = (idx >> 11) * 8 + j;
    BPoff[idx] = f2b(off_w[(size_t)o * 512 + k]);
    return;
  }
  b -= 512;
  const float* w;
  bf16* BP;
  int Co;
  if (b < 2304) { w = om_w; BP = BPom; Co = 216; }
  else if (b < 4608) {                // dcn: tap-major packwd
    int idx = (b - 2304) * 256 + threadIdx.x;
    int j = idx & 7, o = (idx >> 3) & 255;
    int k = (idx >> 11) * 8 + j;      // 0..2303 tap-major
    int tap = k >> 8, ci = k & 255;
    BPdcn[idx] = f2b(dcn_w[((size_t)o * 256 + ci) * 9 + tap]);
    return;
  } else { w = out_w; BP = BPout; Co = 256; b -= 2304; }
  // packw3 body (Ci=256)
  int idx = (b % 2304) * 256 + threadIdx.x;
  int j = idx & 7;
  int t1 = idx >> 3;
  int o = t1 & 255;
  int t2 = t1 >> 8;
  int q = t2 & 3;
  int t3 = t2 >> 2;
  int tap = t3 % 9;
  int c = t3 / 9;
  int ci = c * 32 + q * 8 + j;
  float v = (o < Co) ? w[((size_t)o * 256 + ci) * 9 + tap] : 0.f;
  BP[idx] = f2b(v);
}

// ------------- 1x1 conv as MFMA GEMM (fused, full-K) ---------------------
template <bool NCHW1, typename TA1>
__global__ __launch_bounds__(256) void conv1x1_mfma_kernel(
    const TA1* __restrict__ A1, const float* __restrict__ scaleA,
    const bf16* __restrict__ A2, float scaleB,
    int Ci1, int Ci2, int HW,
    const bf16* __restrict__ BP, const float* __restrict__ bias,
    float* __restrict__ out1, bf16* __restrict__ out2, int ns2) {
  __shared__ __align__(16) bf16 sA[1024];   // [4 q][32 px][8]
  int p0 = blockIdx.x * 32;
  int tid = threadIdx.x;
  int pix = tid & 31, sub = tid >> 5;       // fp32-NCHW staging mapping
  int pix2 = tid >> 3, sub8 = tid & 7;      // NHWC staging mapping
  int lane = tid & 63, wave = tid >> 6;
  int pg = wave & 1, cg = wave >> 1;
  int q = lane >> 4, n = lane & 15;

  floatx4 acc[4];
#pragma unroll
  for (int nt = 0; nt < 4; ++nt) acc[nt] = (floatx4)0.f;

  int nch = (Ci1 + Ci2) >> 5;
  for (int kc = 0; kc < nch; ++kc) {
    int ci0 = kc << 5;
    if (NCHW1 && ci0 < Ci1) {
#pragma unroll
      for (int it = 0; it < 4; ++it) {
        int cil = it * 8 + sub;
        float x = (float)A1[(size_t)(ci0 + cil) * HW + p0 + pix];
        if (scaleA) x *= scaleA[ci0 + cil];
        sA[((cil >> 3) * 32 + pix) * 8 + (cil & 7)] = f2b(x);
      }
    } else {
      const bf16* src; int cb; bool scl;
      if (!NCHW1 && ci0 < Ci1) {
        src = (const bf16*)(const void*)A1; cb = ci0; scl = false;
      } else {
        src = A2; cb = ci0 - Ci1; scl = true;
      }
      ushort4 raw = *(const ushort4*)&src[(size_t)(p0 + pix2) * 256 + cb + sub8 * 4];
      if (scl) {
        raw.x = f2us(us2f(raw.x) * scaleB);
        raw.y = f2us(us2f(raw.y) * scaleB);
        raw.z = f2us(us2f(raw.z) * scaleB);
        raw.w = f2us(us2f(raw.w) * scaleB);
      }
      *(ushort4*)&sA[((sub8 >> 1) * 32 + pix2) * 8 + (sub8 & 1) * 4] = raw;
    }
    __syncthreads();
    bf16x8 a = *(const bf16x8*)&sA[(q * 32 + pg * 16 + n) * 8];
    const bf16* bp = BP + ((size_t)(kc * 4 + q) * 256 + blockIdx.y * 128 + cg * 64) * 8;
#pragma unroll
    for (int nt = 0; nt < 4; ++nt) {
      bf16x8 b = *(const bf16x8*)&bp[(nt * 16 + n) * 8];
      acc[nt] = __builtin_amdgcn_mfma_f32_16x16x32_bf16(a, b, acc[nt], 0, 0, 0);
    }
    __syncthreads();
  }

  int pbase = p0 + pg * 16 + q * 4;
#pragma unroll
  for (int nt = 0; nt < 4; ++nt) {
    int o = blockIdx.y * 128 + cg * 64 + nt * 16 + n;
    float bv = bias ? bias[o] : 0.f;
#pragma unroll
    for (int r = 0; r < 4; ++r) {
      float v = acc[nt][r] + bv;
      if (out1) out1[(size_t)o * HW + pbase + r] = v;
      if (out2) out2[(size_t)(pbase + r) * ns2 + o] = f2b(v);
    }
  }
}

// ---- K-split 1x1 conv: blockIdx.z covers kcPerZ k-chunks; fp32 partials -
template <bool NCHW1, typename TA1>
__global__ __launch_bounds__(256) void conv1x1_split_kernel(
    const TA1* __restrict__ A1, const float* __restrict__ scaleA,
    const bf16* __restrict__ A2, float scaleB,
    int Ci1, int HW,
    const bf16* __restrict__ BP, float* __restrict__ PART, int kcPerZ) {
  __shared__ __align__(16) bf16 sA[1024];   // [4 q][32 px][8]
  int p0 = blockIdx.x * 32;
  int tid = threadIdx.x;
  int pix = tid & 31, sub = tid >> 5;
  int pix2 = tid >> 3, sub8 = tid & 7;
  int lane = tid & 63, wave = tid >> 6;
  int pg = wave & 1, cg = wave >> 1;
  int q = lane >> 4, n = lane & 15;

  floatx4 acc[4];
#pragma unroll
  for (int nt = 0; nt < 4; ++nt) acc[nt] = (floatx4)0.f;

  int kc0 = blockIdx.z * kcPerZ;
  for (int kcl = 0; kcl < kcPerZ; ++kcl) {
    int kc = kc0 + kcl;
    int ci0 = kc << 5;
    if (NCHW1 && ci0 < Ci1) {
#pragma unroll
      for (int it = 0; it < 4; ++it) {
        int cil = it * 8 + sub;
        float x = (float)A1[(size_t)(ci0 + cil) * HW + p0 + pix];
        if (scaleA) x *= scaleA[ci0 + cil];
        sA[((cil >> 3) * 32 + pix) * 8 + (cil & 7)] = f2b(x);
      }
    } else {
      const bf16* src; int cb; bool scl;
      if (!NCHW1 && ci0 < Ci1) {
        src = (const bf16*)(const void*)A1; cb = ci0; scl = false;
      } else {
        src = A2; cb = ci0 - Ci1; scl = true;
      }
      ushort4 raw = *(const ushort4*)&src[(size_t)(p0 + pix2) * 256 + cb + sub8 * 4];
      if (scl) {
        raw.x = f2us(us2f(raw.x) * scaleB);
        raw.y = f2us(us2f(raw.y) * scaleB);
        raw.z = f2us(us2f(raw.z) * scaleB);
        raw.w = f2us(us2f(raw.w) * scaleB);
      }
      *(ushort4*)&sA[((sub8 >> 1) * 32 + pix2) * 8 + (sub8 & 1) * 4] = raw;
    }
    __syncthreads();
    bf16x8 a = *(const bf16x8*)&sA[(q * 32 + pg * 16 + n) * 8];
    const bf16* bp = BP + ((size_t)(kc * 4 + q) * 256 + blockIdx.y * 128 + cg * 64) * 8;
#pragma unroll
    for (int nt = 0; nt < 4; ++nt) {
      bf16x8 b = *(const bf16x8*)&bp[(nt * 16 + n) * 8];
      acc[nt] = __builtin_amdgcn_mfma_f32_16x16x32_bf16(a, b, acc[nt], 0, 0, 0);
    }
    __syncthreads();
  }

  int pbase = p0 + pg * 16 + q * 4;
#pragma unroll
  for (int nt = 0; nt < 4; ++nt) {
    int o = blockIdx.y * 128 + cg * 64 + nt * 16 + n;
#pragma unroll
    for (int r = 0; r < 4; ++r)
      PART[((size_t)blockIdx.z * 256 + o) * HW + pbase + r] = acc[nt][r];
  }
}

// ---- reduce K-split partials + bias -> fp32 NCHW + bf16 NHWC (p5) -------
__global__ __launch_bounds__(256) void reduce_p5_kernel(
    const float* __restrict__ PART, const float* __restrict__ bias,
    float* __restrict__ out1, bf16* __restrict__ out2, int HW, int KS) {
  int o = blockIdx.x;
  int p = threadIdx.x;
  float s = bias[o];
  for (int z = 0; z < KS; ++z) s += PART[((size_t)z * 256 + o) * HW + p];
  out1[(size_t)o * HW + p] = s;
  out2[(size_t)p * 256 + o] = f2b(s);
}

// ---- reduce K-split partials -> bf16 NHWC (no bias) ---------------------
__global__ __launch_bounds__(256) void reduce_nhwc_kernel(
    const float* __restrict__ PART, bf16* __restrict__ out2,
    int HW, int KS, int ns2) {
  int o = blockIdx.x;
  for (int p = threadIdx.x; p < HW; p += 256) {
    float s = 0.f;
    for (int z = 0; z < KS; ++z) s += PART[((size_t)z * 256 + o) * HW + p];
    out2[(size_t)p * ns2 + o] = f2b(s);
  }
}

// ------- 3x3 conv v3: row-window staging + reg-prefetch, 64-o blocks -----
// Block: 32*S px x 64 o (grid (HW/(32S), 4)), 256 thr, 4 waves = 2 pg x 2 cg
// (cg covers 32 o each). 4x O-split doubles blocks/CU vs v2 (16 waves/CU)
// to hide B-load L2 latency (R11 counters: occupancy 19%, all pipes idle).
template <int S>
__global__ __launch_bounds__(256) void conv3x3v2_kernel(
    const bf16* __restrict__ in, const bf16* __restrict__ BP,
    const float* __restrict__ bias,
    int H, int W, int Co,
    float* __restrict__ out1, bf16* __restrict__ out2, int ns2) {
  constexpr int P = 32 * S + 2;
  constexpr int TASKS = 3 * P * 8;            // ushort4 stage tasks per kc
  constexpr int ITS = (TASKS + 255) / 256;
  __shared__ __align__(16) bf16 sA[2][4 * 3 * P * 8];
  int HW = H * W;
  int segs = W / (32 * S);
  int y = blockIdx.x / segs;
  int x0 = (blockIdx.x - y * segs) * (32 * S);
  int tid = threadIdx.x;
  int lane = tid & 63, wave = tid >> 6;
  int pg = wave & 1, cg = wave >> 1;
  int q = lane >> 4, n = lane & 15;
  int ob = blockIdx.y * 64 + cg * 32;         // 32-o slice per cg-wave

  // --- precompute per-thread staging tasks (kc-invariant) ---
  int dstIdx[ITS], srcOff[ITS];
  bool act[ITS], val[ITS];
#pragma unroll
  for (int it = 0; it < ITS; ++it) {
    int tt = it * 256 + tid;
    act[it] = (tt < TASKS);
    int sub8 = tt & 7;
    int rp = tt >> 3;
    int row = rp / P;
    int pxl = rp - row * P;
    int yy = y + row - 1;
    int xg = x0 + pxl - 1;
    bool v = act[it] && ((unsigned)yy < (unsigned)H) && ((unsigned)xg < (unsigned)W);
    val[it] = v;
    srcOff[it] = v ? ((yy * W + xg) * 256 + sub8 * 4) : 0;
    dstIdx[it] = (((sub8 >> 1) * 3 + row) * P + pxl) * 8 + (sub8 & 1) * 4;
  }

  ushort4 pv[ITS];
  auto load_regs = [&](int kc) {
    int cb = kc << 5;
#pragma unroll
    for (int it = 0; it < ITS; ++it) {
      ushort4 z = {0, 0, 0, 0};
      pv[it] = val[it] ? *(const ushort4*)&in[(size_t)srcOff[it] + cb] : z;
    }
  };
  auto store_lds = [&](int buf) {
#pragma unroll
    for (int it = 0; it < ITS; ++it)
      if (act[it]) *(ushort4*)&sA[buf][dstIdx[it]] = pv[it];
  };

  floatx4 acc[S][2];
#pragma unroll
  for (int s = 0; s < S; ++s)
#pragma unroll
    for (int nt = 0; nt < 2; ++nt) acc[s][nt] = (floatx4)0.f;

  load_regs(0);
  store_lds(0);
  __syncthreads();
  load_regs(1);

  for (int kc = 0; kc < 8; ++kc) {
    const bf16* sv = &sA[kc & 1][0];
    const bf16* bpc = BP + (size_t)kc * 73728;   // kc*9*4*256*8
#pragma unroll
    for (int tap = 0; tap < 9; ++tap) {
      int ty = tap / 3, tx = tap % 3;            // row = dy+1, xoff = dx+1
      bf16x8 a[S];
#pragma unroll
      for (int s = 0; s < S; ++s)
        a[s] = *(const bf16x8*)&sv[((q * 3 + ty) * P + tx + s * 32 + pg * 16 + n) * 8];
      const bf16* bp = bpc + ((size_t)(tap * 4 + q) * 256 + ob) * 8;
#pragma unroll
      for (int nt = 0; nt < 2; ++nt) {
        bf16x8 b = *(const bf16x8*)&bp[(nt * 16 + n) * 8];
#pragma unroll
        for (int s = 0; s < S; ++s)
          acc[s][nt] = __builtin_amdgcn_mfma_f32_16x16x32_bf16(a[s], b, acc[s][nt], 0, 0, 0);
      }
    }
    if (kc < 7) {
      store_lds((kc + 1) & 1);     // target buf last read at kc-1 (fenced)
      __syncthreads();             // publish for mfma(kc+1)
      if (kc < 6) load_regs(kc + 2);
    }
  }

#pragma unroll
  for (int s = 0; s < S; ++s) {
    int pbase = y * W + x0 + s * 32 + pg * 16 + q * 4;
#pragma unroll
    for (int nt = 0; nt < 2; ++nt) {
      int o = ob + nt * 16 + n;
      if (o < Co) {
        float bv = bias ? bias[o] : 0.f;
#pragma unroll
        for (int r = 0; r < 4; ++r) {
          float v = acc[s][nt][r] + bv;
          if (out1) out1[(size_t)o * HW + pbase + r] = v;
          if (out2) out2[(size_t)(pbase + r) * ns2 + o] = f2b(v);
        }
      }
    }
  }
}

// ---- mdcn v3c: 32-px tile (kept for L0/L1), +XCD swizzle ----------------
__global__ __launch_bounds__(512, 4) void mdcn_mfma_kernel(
    const bf16* __restrict__ UPn, const bf16* __restrict__ OM,
    const bf16* __restrict__ BP, const float* __restrict__ dcn_b,
    const bf16* __restrict__ ARM, bf16* __restrict__ F,
    int H, int W, int wshift) {
  __shared__ __align__(16) bf16 sval[2][32 * 272];   // 34,816 B
  __shared__ float4 mw[2304];                        // 36,864 B
  __shared__ int mi[2304];                           //  9,216 B
  int pb = xcd_swz(blockIdx.x, gridDim.x) * 32;
  int tid = threadIdx.x;

  for (int t2 = tid; t2 < 2304; t2 += 512) {
    int px_ = t2 & 31, g = (t2 >> 5) & 7, tap = t2 >> 8;
    int ky = tap / 3, kx = tap - ky * 3;
    int p = pb + px_;
    int y = p >> wshift, x = p & (W - 1);
    const bf16* omp = OM + (size_t)p * 216;
    float dy = b2f(omp[g * 18 + tap]);
    float dx = b2f(omp[g * 18 + 9 + tap]);
    float mm = 1.f / (1.f + expf(-b2f(omp[144 + g * 9 + tap])));
    float fpy = (float)(y - 1 + ky) + dy;
    float fpx = (float)(x - 1 + kx) + dx;
    fpy = fminf(fmaxf(fpy, -1.0e4f), 1.0e4f);
    fpx = fminf(fmaxf(fpx, -1.0e4f), 1.0e4f);
    float fy0 = floorf(fpy), fx0 = floorf(fpx);
    float wy1 = fpy - fy0, wx1 = fpx - fx0;
    float wy0 = 1.f - wy1, wx0 = 1.f - wx1;
    int iy0 = (int)fy0, ix0 = (int)fx0;
    bool vy0 = (unsigned)iy0 < (unsigned)H;
    bool vy1 = (unsigned)(iy0 + 1) < (unsigned)H;
    bool vx0 = (unsigned)ix0 < (unsigned)W;
    bool vx1 = (unsigned)(ix0 + 1) < (unsigned)W;
    float w00 = (vy0 && vx0) ? mm * wy0 * wx0 : 0.f;
    float w01 = (vy0 && vx1) ? mm * wy0 * wx1 : 0.f;
    float w10 = (vy1 && vx0) ? mm * wy1 * wx0 : 0.f;
    float w11 = (vy1 && vx1) ? mm * wy1 * wx1 : 0.f;
    int iy0c = min(max(iy0, 0), H - 1);
    int iy1c = min(max(iy0 + 1, 0), H - 1);
    int ix0c = min(max(ix0, 0), W - 1);
    int ix1c = min(max(ix0 + 1, 0), W - 1);
    mw[t2] = make_float4(w00, w01, w10, w11);
    mi[t2] = (iy0c * W + ix0c) | ((ix1c - ix0c) << 20) | ((iy1c - iy0c) << 21);
  }
  __syncthreads();

  int l4 = tid & 7;
  int px = (tid >> 3) & 31;
  int gh = tid >> 8;
  int lane = tid & 63, wave = tid >> 6;
  int q = lane >> 4, n = lane & 15;
  int rowb = l4 >> 1;
  int woff = px * 8 + (l4 & 1) * 4;

  floatx4 acc[2][2];
#pragma unroll
  for (int m = 0; m < 2; ++m)
#pragma unroll
    for (int nt = 0; nt < 2; ++nt) acc[m][nt] = (floatx4)0.f;

  ushort4 gl[4][4];
  auto gatherLoad = [&](int t) {
    int base = t * 256 + px + gh * 128;
#pragma unroll
    for (int gg = 0; gg < 4; ++gg) {
      int g = gh * 4 + gg;
      int mv = mi[base + gg * 32];
      int idx = mv & 0x3FFFF;
      int dxs = (mv >> 20) & 1;
      int dyW = ((mv >> 21) & 1) * W;
      const bf16* up = UPn + (size_t)idx * 256 + g * 32 + l4 * 4;
      gl[gg][0] = *(const ushort4*)(up);
      gl[gg][1] = *(const ushort4*)(up + dxs * 256);
      gl[gg][2] = *(const ushort4*)(up + dyW * 256);
      gl[gg][3] = *(const ushort4*)(up + (dyW + dxs) * 256);
    }
  };
  auto gatherStore = [&](int t) {
    bf16* sv = &sval[t & 1][0];
    int base = t * 256 + px + gh * 128;
#pragma unroll
    for (int gg = 0; gg < 4; ++gg) {
      int g = gh * 4 + gg;
      float4 wv = mw[base + gg * 32];
      ushort4 u00 = gl[gg][0], u01 = gl[gg][1], u10 = gl[gg][2], u11 = gl[gg][3];
      ushort4 o4;
      o4.x = f2us(wv.x * us2f(u00.x) + wv.y * us2f(u01.x)
                + wv.z * us2f(u10.x) + wv.w * us2f(u11.x));
      o4.y = f2us(wv.x * us2f(u00.y) + wv.y * us2f(u01.y)
                + wv.z * us2f(u10.y) + wv.w * us2f(u11.y));
      o4.z = f2us(wv.x * us2f(u00.z) + wv.y * us2f(u01.z)
                + wv.z * us2f(u10.z) + wv.w * us2f(u11.z));
      o4.w = f2us(wv.x * us2f(u00.w) + wv.y * us2f(u01.w)
                + wv.z * us2f(u10.w) + wv.w * us2f(u11.w));
      *(ushort4*)&sv[(g * 4 + rowb) * 272 + woff] = o4;
    }
  };

  gatherLoad(0);
  gatherStore(0);
  for (int t = 0; t < 9; ++t) {
    __syncthreads();
    if (t < 8) gatherLoad(t + 1);
    const bf16* sv = &sval[t & 1][0];
    const bf16* bpt = BP + ((size_t)(t * 32) * 256 + wave * 32) * 8;
#pragma unroll
    for (int kc = 0; kc < 8; ++kc) {
      int R = kc * 4 + q;
      bf16x8 a0 = *(const bf16x8*)&sv[R * 272 + n * 8];
      bf16x8 a1 = *(const bf16x8*)&sv[R * 272 + (16 + n) * 8];
      const bf16* bp = bpt + (size_t)R * 2048;   // R*256*8
      bf16x8 b0 = *(const bf16x8*)&bp[n * 8];
      bf16x8 b1 = *(const bf16x8*)&bp[(16 + n) * 8];
      acc[0][0] = __builtin_amdgcn_mfma_f32_16x16x32_bf16(a0, b0, acc[0][0], 0, 0, 0);
      acc[0][1] = __builtin_amdgcn_mfma_f32_16x16x32_bf16(a0, b1, acc[0][1], 0, 0, 0);
      acc[1][0] = __builtin_amdgcn_mfma_f32_16x16x32_bf16(a1, b0, acc[1][0], 0, 0, 0);
      acc[1][1] = __builtin_amdgcn_mfma_f32_16x16x32_bf16(a1, b1, acc[1][1], 0, 0, 0);
    }
    if (t < 8) gatherStore(t + 1);
  }

#pragma unroll
  for (int m = 0; m < 2; ++m) {
#pragma unroll
    for (int nt = 0; nt < 2; ++nt) {
      int o = wave * 32 + nt * 16 + n;
      float bv = dcn_b[o];
#pragma unroll
      for (int r = 0; r < 4; ++r) {
        int p = pb + m * 16 + q * 4 + r;
        float v = fmaxf(acc[m][nt][r] + bv, 0.f) + b2f(ARM[(size_t)p * 256 + o]);
        F[(size_t)p * 256 + o] = f2b(v);
      }
    }
  }
}

// ---- mdcn64: 64-px tile, lane-contiguous gather, per-tap meta (L2) ------
__global__ __launch_bounds__(512, 1) void mdcn64_mfma_kernel(
    const bf16* __restrict__ UPn, const bf16* __restrict__ OM,
    const bf16* __restrict__ BP, const float* __restrict__ dcn_b,
    const bf16* __restrict__ ARM, bf16* __restrict__ F,
    int H, int W, int wshift) {
  __shared__ __align__(16) bf16 sval[2][32 * 520];   // 66,560 B
  __shared__ float4 mw2[2][512];                     // 16,384 B
  __shared__ int mi2[2][512];                        //  4,096 B
  int pb = xcd_swz(blockIdx.x, gridDim.x) * 64;
  int tid = threadIdx.x;
  int l4 = tid & 7;
  int px = tid >> 3;
  int gm = tid >> 6;
  int pxm = tid & 63;
  int lane = tid & 63, wave = tid >> 6;
  int q = lane >> 4, n = lane & 15;
  int rowb = l4 >> 1;
  int woff = px * 8 + (l4 & 1) * 4;

  int pM = pb + pxm;
  int yM = pM >> wshift, xM = pM & (W - 1);
  const bf16* ompM = OM + (size_t)pM * 216 + gm * 18;
  const bf16* ommM = OM + (size_t)pM * 216 + 144 + gm * 9;
  int slot = gm * 64 + pxm;

  auto metaCompute = [&](int t, int buf) {
    int ky = t / 3, kx = t - ky * 3;
    float dy = b2f(ompM[t]);
    float dx = b2f(ompM[9 + t]);
    float mm = 1.f / (1.f + expf(-b2f(ommM[t])));
    float fpy = (float)(yM - 1 + ky) + dy;
    float fpx = (float)(xM - 1 + kx) + dx;
    fpy = fminf(fmaxf(fpy, -1.0e4f), 1.0e4f);
    fpx = fminf(fmaxf(fpx, -1.0e4f), 1.0e4f);
    float fy0 = floorf(fpy), fx0 = floorf(fpx);
    float wy1 = fpy - fy0, wx1 = fpx - fx0;
    float wy0 = 1.f - wy1, wx0 = 1.f - wx1;
    int iy0 = (int)fy0, ix0 = (int)fx0;
    bool vy0 = (unsigned)iy0 < (unsigned)H;
    bool vy1 = (unsigned)(iy0 + 1) < (unsigned)H;
    bool vx0 = (unsigned)ix0 < (unsigned)W;
    bool vx1 = (unsigned)(ix0 + 1) < (unsigned)W;
    float w00 = (vy0 && vx0) ? mm * wy0 * wx0 : 0.f;
    float w01 = (vy0 && vx1) ? mm * wy0 * wx1 : 0.f;
    float w10 = (vy1 && vx0) ? mm * wy1 * wx0 : 0.f;
    float w11 = (vy1 && vx1) ? mm * wy1 * wx1 : 0.f;
    int iy0c = min(max(iy0, 0), H - 1);
    int iy1c = min(max(iy0 + 1, 0), H - 1);
    int ix0c = min(max(ix0, 0), W - 1);
    int ix1c = min(max(ix0 + 1, 0), W - 1);
    mw2[buf][slot] = make_float4(w00, w01, w10, w11);
    mi2[buf][slot] = (iy0c * W + ix0c) | ((ix1c - ix0c) << 20) | ((iy1c - iy0c) << 21);
  };

  floatx4 acc[4][2];
#pragma unroll
  for (int m = 0; m < 4; ++m)
#pragma unroll
    for (int nt = 0; nt < 2; ++nt) acc[m][nt] = (floatx4)0.f;

  ushort4 gl[8][4];
  auto gatherLoad = [&](int t) {
    int bufI = t & 1;
#pragma unroll
    for (int g = 0; g < 8; ++g) {
      int mv = mi2[bufI][g * 64 + px];
      int idx = mv & 0x3FFFF;
      int dxs = (mv >> 20) & 1;
      int dyW = ((mv >> 21) & 1) * W;
      const bf16* up = UPn + (size_t)idx * 256 + g * 32 + l4 * 4;
      gl[g][0] = *(const ushort4*)(up);
      gl[g][1] = *(const ushort4*)(up + dxs * 256);
      gl[g][2] = *(const ushort4*)(up + dyW * 256);
      gl[g][3] = *(const ushort4*)(up + (dyW + dxs) * 256);
    }
  };
  auto gatherStore = [&](int t) {
    bf16* sv = &sval[t & 1][0];
    int bufI = t & 1;
#pragma unroll
    for (int g = 0; g < 8; ++g) {
      float4 wv = mw2[bufI][g * 64 + px];
      ushort4 u00 = gl[g][0], u01 = gl[g][1], u10 = gl[g][2], u11 = gl[g][3];
      ushort4 o4;
      o4.x = f2us(wv.x * us2f(u00.x) + wv.y * us2f(u01.x)
                + wv.z * us2f(u10.x) + wv.w * us2f(u11.x));
      o4.y = f2us(wv.x * us2f(u00.y) + wv.y * us2f(u01.y)
                + wv.z * us2f(u10.y) + wv.w * us2f(u11.y));
      o4.z = f2us(wv.x * us2f(u00.z) + wv.y * us2f(u01.z)
                + wv.z * us2f(u10.z) + wv.w * us2f(u11.z));
      o4.w = f2us(wv.x * us2f(u00.w) + wv.y * us2f(u01.w)
                + wv.z * us2f(u10.w) + wv.w * us2f(u11.w));
      *(ushort4*)&sv[(g * 4 + rowb) * 520 + woff] = o4;
    }
  };

  metaCompute(0, 0);
  metaCompute(1, 1);
  __syncthreads();
  gatherLoad(0);
  gatherStore(0);

  for (int t = 0; t < 9; ++t) {
    __syncthreads();
    if (t < 8) gatherLoad(t + 1);
    if (t < 7) metaCompute(t + 2, t & 1);
    const bf16* sv = &sval[t & 1][0];
    const bf16* bpt = BP + ((size_t)(t * 32) * 256 + wave * 32) * 8;
#pragma unroll
    for (int kc = 0; kc < 8; ++kc) {
      int R = kc * 4 + q;
      const bf16* bp = bpt + (size_t)R * 2048;   // R*256*8
      bf16x8 b0 = *(const bf16x8*)&bp[n * 8];
      bf16x8 b1 = *(const bf16x8*)&bp[(16 + n) * 8];
#pragma unroll
      for (int m = 0; m < 4; ++m) {
        bf16x8 a = *(const bf16x8*)&sv[R * 520 + (m * 16 + n) * 8];
        acc[m][0] = __builtin_amdgcn_mfma_f32_16x16x32_bf16(a, b0, acc[m][0], 0, 0, 0);
        acc[m][1] = __builtin_amdgcn_mfma_f32_16x16x32_bf16(a, b1, acc[m][1], 0, 0, 0);
      }
    }
    if (t < 8) gatherStore(t + 1);
  }

#pragma unroll
  for (int m = 0; m < 4; ++m) {
#pragma unroll
    for (int nt = 0; nt < 2; ++nt) {
      int o = wave * 32 + nt * 16 + n;
      float bv = dcn_b[o];
#pragma unroll
      for (int r = 0; r < 4; ++r) {
        int p = pb + m * 16 + q * 4 + r;
        float v = fmaxf(acc[m][nt][r] + bv, 0.f) + b2f(ARM[(size_t)p * 256 + o]);
        F[(size_t)p * 256 + o] = f2b(v);
      }
    }
  }
}

extern "C" void kernel_launch(void* const* d_in, const int* in_sizes, int n_in,
                              void* d_out, int out_size, void* d_ws, size_t ws_size,
                              hipStream_t stream) {
  // Inputs fp32, outputs fp32 (established rounds 3-5). Interior: bf16 NHWC.
  const float* c2 = (const float*)d_in[0];
  const float* c3 = (const float*)d_in[1];
  const float* c4 = (const float*)d_in[2];
  const float* c5 = (const float*)d_in[3];
  const float* lat_w = (const float*)d_in[31];
  const float* lat_b = (const float*)d_in[32];
  float* out = (float*)d_out;
  (void)ws_size; (void)in_sizes; (void)n_in; (void)out_size;

  const size_t p2_off = 0;
  const size_t p3_off = 4194304;
  const size_t p4_off = p3_off + 1048576;
  const size_t p5_off = p4_off + 262144;

  // ---- ws layout (~27.3MB; ws_size >= 28MB proven round 3) ----
  char* ws = (char*)d_ws;
  bf16* UPn = (bf16*)(ws);                    // 8MB NHWC
  bf16* ARM = (bf16*)(ws + 8388608);          // 8MB NHWC
  bf16* FB  = (bf16*)(ws + 16777216);         // 8MB NHWC (off_feat & F alias)
  bf16* P5N = (bf16*)(ws + 25165824);         // 128KB NHWC p5 copy
  bf16* BPout = (bf16*)(ws + 25296896);       // 1.125MB (also hosts p5 lat pack)
  bf16* BPfsm = (bf16*)(ws + 26476544);       // 512KB
  bf16* BPoff = (bf16*)(ws + 27000832);       // 256KB
  float* GAP = (float*)(ws + 27262976);
  float* SC  = (float*)(ws + 27271168);
  // p2 output region scratch: OM at +0 (6.75MB max), BPom at +10MiB,
  // BPdcn at +10MiB+1.125MB. All consumed before the final conv writes p2.
  // L0 conv1x1 K-split partials (<=4MB) also borrow p2+0 (consumed by
  // reduce_nhwc before OM is written at step 4).
  bf16* OM = (bf16*)(out + p2_off);
  bf16* BPom = (bf16*)((char*)(out + p2_off) + 10485760);
  bf16* BPdcn = (bf16*)((char*)(out + p2_off) + 11665408);
  float* PARTL = (float*)(out + p2_off);
  // p5 K-split partials (2MB) borrow the UPn region.
  float* PART = (float*)ws;

  // ---- p5 = conv1x1(c5, lat_w, lat_b), K-split x8 + reduce --------------
  packw1_kernel<<<2048, 256, 0, stream>>>(lat_w, BPout, 2048);
  conv1x1_split_kernel<true, float><<<dim3(8, 2, 8), 256, 0, stream>>>(
      c5, nullptr, nullptr, 0.f, 2048, 256, BPout, PART, 8);
  reduce_p5_kernel<<<256, 256, 0, stream>>>(PART, lat_b, out + p5_off, P5N, 256, 8);

  struct Lv {
    const float* featl; int Ci; int H; int W; int wshift;
    float* pdst; int wbase;
  };
  Lv levels[3] = {
      {c4, 1024, 32, 32, 5, out + p4_off, 4},
      {c3, 512, 64, 64, 6, out + p3_off, 13},
      {c2, 256, 128, 128, 7, out + p2_off, 22},
  };

  for (int li = 0; li < 3; ++li) {
    const Lv& L = levels[li];
    const float* att_w = (const float*)d_in[L.wbase + 0];
    const float* fsm_w = (const float*)d_in[L.wbase + 1];
    const float* off_w = (const float*)d_in[L.wbase + 2];
    const float* om_w  = (const float*)d_in[L.wbase + 3];
    const float* om_b  = (const float*)d_in[L.wbase + 4];
    const float* dcn_w = (const float*)d_in[L.wbase + 5];
    const float* dcn_b = (const float*)d_in[L.wbase + 6];
    const float* out_w = (const float*)d_in[L.wbase + 7];
    const float* out_b = (const float*)d_in[L.wbase + 8];
    int HW = L.H * L.W;

    // 0) fused pack of all 5 weight tensors for this level (1 launch)
    pack_level_kernel<<<L.Ci + 512 + 3 * 2304, 256, 0, stream>>>(
        fsm_w, L.Ci, off_w, om_w, dcn_w, out_w,
        BPfsm, BPoff, BPom, BPdcn, BPout);
    // 1) feat_up = bilinear 2x (NHWC -> NHWC): src = P5N or previous F(FB)
    upsample2x_nhwc_kernel<<<HW, 256, 0, stream>>>(
        (li == 0) ? P5N : FB, UPn, L.H / 2, L.W / 2);
    // 2) FSM: gap -> atten -> scaled 1x1 GEMM -> ARM (NHWC)
    gap_kernel<<<L.Ci, 256, 0, stream>>>(L.featl, GAP, HW, 1.f / (float)HW);
    atten_kernel<<<L.Ci / 4, 256, 0, stream>>>(att_w, GAP, SC, L.Ci);
    if (li == 0) {
      // HW=1024: K-split x4 for parallelism (64 -> 256 blocks)
      conv1x1_split_kernel<true, float><<<dim3(HW / 32, 2, 4), 256, 0, stream>>>(
          L.featl, SC, nullptr, 0.f, L.Ci, HW, BPfsm, PARTL, 8);
      reduce_nhwc_kernel<<<256, 256, 0, stream>>>(PARTL, ARM, HW, 4, 256);
    } else {
      conv1x1_mfma_kernel<true, float><<<dim3(HW / 32, 2), 256, 0, stream>>>(
          L.featl, SC, nullptr, 0.f, L.Ci, 0, HW, BPfsm, nullptr,
          nullptr, ARM, 256);
    }
    // 3) off_feat = conv1x1(concat(ARM, 2*UPn)) -> FB (NHWC)
    if (li == 0) {
      conv1x1_split_kernel<false, bf16><<<dim3(HW / 32, 2, 2), 256, 0, stream>>>(
          ARM, nullptr, UPn, 2.f, 256, HW, BPoff, PARTL, 8);
      reduce_nhwc_kernel<<<256, 256, 0, stream>>>(PARTL, FB, HW, 2, 256);
    } else {
      conv1x1_mfma_kernel<false, bf16><<<dim3(HW / 32, 2), 256, 0, stream>>>(
          ARM, nullptr, UPn, 2.f, 256, 256, HW, BPoff, nullptr,
          nullptr, FB, 256);
    }
    // 4) om = conv3x3(FB) + om_b -> OM (NHWC stride 216, in p2 region)
    if (li == 2)
      conv3x3v2_kernel<2><<<dim3(HW / 64, 4), 256, 0, stream>>>(
          FB, BPom, om_b, L.H, L.W, 216, nullptr, OM, 216);
    else
      conv3x3v2_kernel<1><<<dim3(HW / 32, 4), 256, 0, stream>>>(
          FB, BPom, om_b, L.H, L.W, 216, nullptr, OM, 216);
    // 5) F = relu(mdcn(UPn, OM) + dcn_b) + ARM -> FB (NHWC)
    if (li == 2)
      mdcn64_mfma_kernel<<<HW / 64, 512, 0, stream>>>(
          UPn, OM, BPdcn, dcn_b, ARM, FB, L.H, L.W, L.wshift);
    else
      mdcn_mfma_kernel<<<HW / 32, 512, 0, stream>>>(
          UPn, OM, BPdcn, dcn_b, ARM, FB, L.H, L.W, L.wshift);
    // 6) p = conv3x3(F) + out_b -> fp32 NCHW output
    if (li == 2)
      conv3x3v2_kernel<2><<<dim3(HW / 64, 4), 256, 0, stream>>>(
          FB, BPout, out_b, L.H, L.W, 256, L.pdst, nullptr, 256);
    else
      conv3x3v2_kernel<1><<<dim3(HW / 32, 4), 256, 0, stream>>>(
          FB, BPout, out_b, L.H, L.W, 256, L.pdst, nullptr, 256);
  }
}